// Round 3
// baseline (4882.577 us; speedup 1.0000x reference)
//
#include <hip/hip_runtime.h>
#include <math.h>

// ---------------- workspace layout (floats), total ~5.76M floats = 22 MB ----------------
constexpr size_t OFF_HINT = 0;                              // 64*160
constexpr size_t OFF_HGRD = OFF_HINT + (size_t)64*160;      // 64*160
constexpr size_t OFF_F    = OFF_HGRD + (size_t)64*160;      // 64*4096
constexpr size_t OFF_H1   = OFF_F    + (size_t)64*4096;     // 64*256
constexpr size_t OFF_P5   = OFF_H1   + (size_t)64*256;      // 64*256*2*2
constexpr size_t OFF_R2   = OFF_P5   + (size_t)64*1024;     // region2: x0 / p1 / p2 / a4
constexpr size_t SZ_R2    = (size_t)64*3*112*112;           // 2,408,448 (max of x0,p1,p2,a4)
constexpr size_t OFF_R1   = OFF_R2 + SZ_R2;                 // region1: a1 / a2 / a3 / a5
constexpr size_t SZ_R1    = (size_t)64*64*27*27;            // 2,985,984 (max of a1,a2,a3,a5)
constexpr size_t WS_FLOATS = OFF_R1 + SZ_R1;                // 5,758,976

__device__ __forceinline__ float grayAt(const float* __restrict__ ib, int r, int c) {
  const size_t o = (size_t)r * 448 + c;
  return 0.299f * ib[o]
       + 0.587f * (0.5f * (ib[200704 + o] + ib[2 * 200704 + o]))
       + 0.114f * ib[3 * 200704 + o];
}

// ---------------- area resize 448->112 (unpadded output) ----------------
__global__ __launch_bounds__(256) void k_resize(const float* __restrict__ img,
                                                float* __restrict__ x0) {
  const int idx = blockIdx.x * 256 + threadIdx.x;
  if (idx >= 64 * 3 * 112 * 112) return;
  const int cc = idx % 112;
  int t = idx / 112;
  const int rr = t % 112; t /= 112;
  const int ch = t % 3;
  const int b = t / 3;
  const float* ib = img + (size_t)b * 4 * 200704;
  float s = 0.f;
  for (int i = 0; i < 4; ++i)
    for (int j = 0; j < 4; ++j) {
      const int r = rr * 4 + i, c = cc * 4 + j;
      float v;
      if (ch == 0)      v = ib[(size_t)r * 448 + c];
      else if (ch == 1) v = 0.5f * (ib[200704 + (size_t)r * 448 + c] + ib[2 * 200704 + (size_t)r * 448 + c]);
      else              v = ib[3 * 200704 + (size_t)r * 448 + c];
      s += v;
    }
  x0[idx] = s * (1.f / 16.f);
}

// ---------------- intensity histogram (gray recomputed inline) ----------------
__global__ __launch_bounds__(256) void k_hist(const float* __restrict__ img,
                                              float* __restrict__ hist) {
  const int b = blockIdx.x, s = blockIdx.y;   // 28 slices of 16 rows
  __shared__ float lh[160];
  const int tid = threadIdx.x;
  for (int i = tid; i < 160; i += 256) lh[i] = 0.f;
  __syncthreads();
  const float* ib = img + (size_t)b * 4 * 200704;
  for (int p = tid; p < 16 * 448; p += 256) {
    const int r = s * 16 + p / 448, c = p % 448;
    const float g = grayAt(ib, r, c);
    int bin = (int)(g * 32.f); bin = bin > 31 ? 31 : (bin < 0 ? 0 : bin);
    atomicAdd(&lh[bin], 1.f);
    const int quad = ((r >= 224) ? 2 : 0) + ((c >= 224) ? 1 : 0);
    atomicAdd(&lh[32 + quad * 32 + bin], 1.f);
  }
  __syncthreads();
  if (tid < 160) atomicAdd(&hist[(size_t)b * 160 + tid], lh[tid]);
}

// ---------------- sobel magnitude histogram (gray staged in LDS) ----------------
__global__ __launch_bounds__(256) void k_sobelhist(const float* __restrict__ img,
                                                   float* __restrict__ hist) {
  const int b = blockIdx.x, s = blockIdx.y;   // 28 slices of 16 rows
  const int r0 = s * 16;
  __shared__ float gs[18][448];
  __shared__ float lh[160];
  const int tid = threadIdx.x;
  for (int i = tid; i < 160; i += 256) lh[i] = 0.f;
  const float* ib = img + (size_t)b * 4 * 200704;
  for (int p = tid; p < 18 * 448; p += 256) {
    const int rr = p / 448, c = p % 448;
    int r = r0 + rr - 1; r = r < 0 ? 0 : (r > 447 ? 447 : r);
    gs[rr][c] = grayAt(ib, r, c);
  }
  __syncthreads();
  for (int p = tid; p < 16 * 448; p += 256) {
    const int dr = p / 448, c = p % 448;
    const int cm = c > 0 ? c - 1 : 0, cp = c < 447 ? c + 1 : 447;
    const float a00 = gs[dr][cm],     a01 = gs[dr][c],     a02 = gs[dr][cp];
    const float a10 = gs[dr + 1][cm],                      a12 = gs[dr + 1][cp];
    const float a20 = gs[dr + 2][cm], a21 = gs[dr + 2][c], a22 = gs[dr + 2][cp];
    const float gx = (-a00 + a02 - 2.f * a10 + 2.f * a12 - a20 + a22) * 0.125f;
    const float gy = (-a00 - 2.f * a01 - a02 + a20 + 2.f * a21 + a22) * 0.125f;
    const float mag = sqrtf(gx * gx + gy * gy + 1e-6f);
    int bin = (int)(mag * 32.f); bin = bin > 31 ? 31 : (bin < 0 ? 0 : bin);
    atomicAdd(&lh[bin], 1.f);
    const int r = r0 + dr;
    const int quad = ((r >= 224) ? 2 : 0) + ((c >= 224) ? 1 : 0);
    atomicAdd(&lh[32 + quad * 32 + bin], 1.f);
  }
  __syncthreads();
  if (tid < 160) atomicAdd(&hist[(size_t)b * 160 + tid], lh[tid]);
}

// ---------------- direct conv, logical zero-pad via bounds check, relu ----------------
// in: [64][CIN][HI][WI] unpadded; w: [M][CIN][KH][KW]; out: [64][M][OH][OW] unpadded
template<int CIN, int HI, int WI, int KH, int KW, int STRIDE, int IPAD, int OH, int OW, int M>
__global__ __launch_bounds__(256) void k_convd(const float* __restrict__ in,
                                               const float* __restrict__ w,
                                               const float* __restrict__ bias,
                                               float* __restrict__ out) {
  const int idx = blockIdx.x * 256 + threadIdx.x;
  constexpr int TOT = 64 * M * OH * OW;
  if (idx >= TOT) return;
  const int ox = idx % OW;
  int t = idx / OW;
  const int oy = t % OH; t /= OH;
  const int oc = t % M;
  const int b = t / M;
  const float* ip = in + (size_t)b * CIN * HI * WI;
  const float* wp = w + (size_t)oc * CIN * KH * KW;
  float s = bias[oc];
  for (int c = 0; c < CIN; ++c) {
    #pragma unroll
    for (int ky = 0; ky < KH; ++ky) {
      const int r = oy * STRIDE - IPAD + ky;
      if (r < 0 || r >= HI) continue;
      #pragma unroll
      for (int kx = 0; kx < KW; ++kx) {
        const int cc = ox * STRIDE - IPAD + kx;
        if (cc < 0 || cc >= WI) continue;
        s += ip[((size_t)c * HI + r) * WI + cc] * wp[(c * KH + ky) * KW + kx];
      }
    }
  }
  out[idx] = fmaxf(s, 0.f);
}

// ---------------- maxpool 3x3 stride 2, unpadded in/out ----------------
template<int C, int HI, int HO>
__global__ __launch_bounds__(256) void k_pool(const float* __restrict__ in,
                                              float* __restrict__ out) {
  const int idx = blockIdx.x * 256 + threadIdx.x;
  constexpr int TOT = 64 * C * HO * HO;
  if (idx >= TOT) return;
  const int x = idx % HO;
  const int y = (idx / HO) % HO;
  const int c = (idx / (HO * HO)) % C;
  const int b = idx / (HO * HO * C);
  const float* ib = in + (size_t)(b * C + c) * HI * HI + (size_t)(y * 2) * HI + x * 2;
  float v = -INFINITY;
  #pragma unroll
  for (int i = 0; i < 3; ++i)
    #pragma unroll
    for (int j = 0; j < 3; ++j)
      v = fmaxf(v, ib[i * HI + j]);
  out[idx] = v;
}

// ---------------- serial per-batch feature assembly ----------------
__global__ void k_feat_simple(const float* __restrict__ p5,
                              const float* __restrict__ hint,
                              const float* __restrict__ hgrad,
                              float* __restrict__ f) {
  const int b = blockIdx.x;
  if (threadIdx.x != 0) return;
  const float* ps = p5 + (size_t)b * 1024;
  float* fb = f + (size_t)b * 4096;
  float ss = 0.f;
  for (int i = 0; i < 1024; ++i) ss += ps[i] * ps[i];
  const float inv = 1.f / (sqrtf(ss) + 1e-7f);
  for (int i = 0; i < 1024; ++i) fb[i] = fmaxf(ps[i] * inv, 0.f);
  for (int ft = 0; ft < 2; ++ft) {
    const float* hb = (ft ? hgrad : hint) + (size_t)b * 160;
    float vals[160];
    for (int i = 0; i < 160; ++i)
      vals[i] = hb[i] * (i < 32 ? (1.f / 200704.f) : (1.f / 50176.f));
    float t2 = 0.f;
    for (int i = 0; i < 160; ++i) t2 += (i < 32 ? 16.f : 4.f) * vals[i] * vals[i];
    const float inv2 = 1.f / (sqrtf(t2) + 1e-7f);
    float* fo = fb + 1024 + ft * 1536;
    for (int ch = 0; ch < 96; ++ch)
      for (int i2 = 0; i2 < 4; ++i2)
        for (int j = 0; j < 4; ++j) {
          float v;
          if (ch < 32)      v = vals[ch];
          else if (ch < 64) v = vals[32 + (((i2 >> 1) * 2) + (j >> 1)) * 32 + (ch - 32)];
          else              v = 0.f;
          fo[ch * 16 + i2 * 4 + j] = fmaxf(v * inv2, 0.f);
        }
  }
}

// ---------------- fc1 / fc2 ----------------
__global__ __launch_bounds__(256) void k_fc1_simple(const float* __restrict__ f,
                                                    const float* __restrict__ w,
                                                    const float* __restrict__ bias,
                                                    float* __restrict__ h1) {
  const int idx = blockIdx.x * 256 + threadIdx.x;
  if (idx >= 64 * 256) return;
  const int oc = idx % 256, b = idx / 256;
  const float* fb = f + (size_t)b * 4096;
  const float* wr = w + (size_t)oc * 4096;
  float s = bias[oc];
  for (int k = 0; k < 4096; ++k) s += fb[k] * wr[k];
  h1[(size_t)b * 256 + oc] = fmaxf(s, 0.f);
}

__global__ __launch_bounds__(256) void k_fc2_simple(const float* __restrict__ h1,
                                                    const float* __restrict__ w,
                                                    const float* __restrict__ bias,
                                                    float* __restrict__ out) {
  const int idx = blockIdx.x * 256 + threadIdx.x;
  if (idx >= 64 * 12) return;
  const int oc = idx % 12, b = idx / 12;
  const float* hb = h1 + (size_t)b * 256;
  const float* wr = w + (size_t)oc * 256;
  float s = bias[oc];
  for (int k = 0; k < 256; ++k) s += hb[k] * wr[k];
  out[b * 12 + oc] = s;
}

// ---------------- launch ----------------
extern "C" void kernel_launch(void* const* d_in, const int* in_sizes, int n_in,
                              void* d_out, int out_size, void* d_ws, size_t ws_size,
                              hipStream_t stream) {
  const float* img  = (const float*)d_in[0];
  const float* w1 = (const float*)d_in[1];  const float* b1 = (const float*)d_in[2];
  const float* w2 = (const float*)d_in[3];  const float* b2 = (const float*)d_in[4];
  const float* w3 = (const float*)d_in[5];  const float* b3 = (const float*)d_in[6];
  const float* w4 = (const float*)d_in[7];  const float* b4 = (const float*)d_in[8];
  const float* w5 = (const float*)d_in[9];  const float* b5 = (const float*)d_in[10];
  const float* fc1w = (const float*)d_in[11]; const float* fc1b = (const float*)d_in[12];
  const float* fc2w = (const float*)d_in[13]; const float* fc2b = (const float*)d_in[14];
  float* out = (float*)d_out;
  float* ws  = (float*)d_ws;

  float* hint = ws + OFF_HINT;
  float* hgrd = ws + OFF_HGRD;
  float* f    = ws + OFF_F;
  float* h1   = ws + OFF_H1;
  float* p5   = ws + OFF_P5;
  float* r2   = ws + OFF_R2;   // x0, p1, p2, a4 (time-multiplexed)
  float* r1   = ws + OFF_R1;   // a1, a2, a3, a5 (time-multiplexed)

  // only memset needed: histogram accumulators (re-run on every graph replay)
  hipMemsetAsync(hint, 0, (size_t)2 * 64 * 160 * sizeof(float), stream);

  k_hist     <<<dim3(64, 28), 256, 0, stream>>>(img, hint);
  k_sobelhist<<<dim3(64, 28), 256, 0, stream>>>(img, hgrd);
  k_resize   <<<(64*3*112*112 + 255)/256, 256, 0, stream>>>(img, r2);      // x0 in r2

  // conv1: 3x112x112 (pad2, s4) -> 64x27x27
  k_convd<3,112,112,11,11,4,2,27,27,64>
      <<<(64*64*27*27 + 255)/256, 256, 0, stream>>>(r2, w1, b1, r1);       // a1 in r1
  k_pool<64,27,13><<<(64*64*13*13 + 255)/256, 256, 0, stream>>>(r1, r2);   // p1 in r2
  // conv2: 64x13x13 (pad2) -> 192x13x13
  k_convd<64,13,13,5,5,1,2,13,13,192>
      <<<(64*192*13*13 + 255)/256, 256, 0, stream>>>(r2, w2, b2, r1);      // a2 in r1
  k_pool<192,13,6><<<(64*192*6*6 + 255)/256, 256, 0, stream>>>(r1, r2);    // p2 in r2
  // conv3: 192x6x6 (pad1) -> 384x6x6
  k_convd<192,6,6,3,3,1,1,6,6,384>
      <<<(64*384*6*6 + 255)/256, 256, 0, stream>>>(r2, w3, b3, r1);        // a3 in r1
  // conv4: 384x6x6 (pad1) -> 256x6x6
  k_convd<384,6,6,3,3,1,1,6,6,256>
      <<<(64*256*6*6 + 255)/256, 256, 0, stream>>>(r1, w4, b4, r2);        // a4 in r2
  // conv5: 256x6x6 (pad1) -> 256x6x6
  k_convd<256,6,6,3,3,1,1,6,6,256>
      <<<(64*256*6*6 + 255)/256, 256, 0, stream>>>(r2, w5, b5, r1);        // a5 in r1
  k_pool<256,6,2><<<(64*256*2*2 + 255)/256, 256, 0, stream>>>(r1, p5);

  k_feat_simple<<<64, 64, 0, stream>>>(p5, hint, hgrd, f);
  k_fc1_simple<<<(64*256 + 255)/256, 256, 0, stream>>>(f, fc1w, fc1b, h1);
  k_fc2_simple<<<(64*12 + 255)/256, 256, 0, stream>>>(h1, fc2w, fc2b, out);
}

// Round 4
// 1450.623 us; speedup vs baseline: 3.3658x; 3.3658x over previous
//
#include <hip/hip_runtime.h>
#include <math.h>

// ---------------- workspace layout (floats), ~5.76M floats = 22 MB ----------------
constexpr size_t OFF_HINT = 0;                              // 64*160
constexpr size_t OFF_HGRD = OFF_HINT + (size_t)64*160;      // 64*160
constexpr size_t OFF_F    = OFF_HGRD + (size_t)64*160;      // 64*4096
constexpr size_t OFF_H1   = OFF_F    + (size_t)64*4096;     // 64*256
constexpr size_t OFF_P5   = OFF_H1   + (size_t)64*256;      // 64*256*2*2
constexpr size_t OFF_R2   = OFF_P5   + (size_t)64*1024;     // region2: x0 / p1 / p2 / a4
constexpr size_t SZ_R2    = (size_t)64*3*112*112;           // max of x0,p1,p2,a4
constexpr size_t OFF_R1   = OFF_R2 + SZ_R2;                 // region1: a1 / a2 / a3 / a5
constexpr size_t SZ_R1    = (size_t)64*64*27*27;            // max of a1,a2,a3,a5
constexpr size_t WS_FLOATS = OFF_R1 + SZ_R1;                // 5,758,976

__device__ __forceinline__ float grayAt(const float* __restrict__ ib, int r, int c) {
  const size_t o = (size_t)r * 448 + c;
  return 0.299f * ib[o]
       + 0.587f * (0.5f * (ib[200704 + o] + ib[2 * 200704 + o]))
       + 0.114f * ib[3 * 200704 + o];
}

// ---------------- fused: gray-strip -> intensity hist + sobel hist (one img read) ----------------
__global__ __launch_bounds__(256) void k_preproc(const float* __restrict__ img,
                                                 float* __restrict__ hint,
                                                 float* __restrict__ hgrd) {
  const int b = blockIdx.x, s = blockIdx.y;   // 28 strips of 16 rows
  const int r0 = s * 16;
  __shared__ float gs[18][448];
  __shared__ float lhi[160], lhs[160];
  const int tid = threadIdx.x;
  for (int i = tid; i < 160; i += 256) { lhi[i] = 0.f; lhs[i] = 0.f; }
  const float* ib = img + (size_t)b * 4 * 200704;
  for (int p = tid; p < 18 * 448; p += 256) {
    const int rr = p / 448, c = p % 448;
    int r = r0 + rr - 1; r = r < 0 ? 0 : (r > 447 ? 447 : r);
    gs[rr][c] = grayAt(ib, r, c);
  }
  __syncthreads();
  for (int p = tid; p < 16 * 448; p += 256) {
    const int dr = p / 448, c = p % 448;
    const int r = r0 + dr;
    const int quad = ((r >= 224) ? 2 : 0) + ((c >= 224) ? 1 : 0);
    // intensity (gray value at row r is gs[dr+1])
    const float g = gs[dr + 1][c];
    int bin = (int)(g * 32.f); bin = bin > 31 ? 31 : (bin < 0 ? 0 : bin);
    atomicAdd(&lhi[bin], 1.f);
    atomicAdd(&lhi[32 + quad * 32 + bin], 1.f);
    // sobel
    const int cm = c > 0 ? c - 1 : 0, cp = c < 447 ? c + 1 : 447;
    const float a00 = gs[dr][cm],     a01 = gs[dr][c],     a02 = gs[dr][cp];
    const float a10 = gs[dr + 1][cm],                      a12 = gs[dr + 1][cp];
    const float a20 = gs[dr + 2][cm], a21 = gs[dr + 2][c], a22 = gs[dr + 2][cp];
    const float gx = (-a00 + a02 - 2.f * a10 + 2.f * a12 - a20 + a22) * 0.125f;
    const float gy = (-a00 - 2.f * a01 - a02 + a20 + 2.f * a21 + a22) * 0.125f;
    const float mag = sqrtf(gx * gx + gy * gy + 1e-6f);
    int sb = (int)(mag * 32.f); sb = sb > 31 ? 31 : (sb < 0 ? 0 : sb);
    atomicAdd(&lhs[sb], 1.f);
    atomicAdd(&lhs[32 + quad * 32 + sb], 1.f);
  }
  __syncthreads();
  if (tid < 160) {
    atomicAdd(&hint[(size_t)b * 160 + tid], lhi[tid]);
    atomicAdd(&hgrd[(size_t)b * 160 + tid], lhs[tid]);
  }
}

// ---------------- area resize 448->112 (verbatim from passing r3) ----------------
__global__ __launch_bounds__(256) void k_resize(const float* __restrict__ img,
                                                float* __restrict__ x0) {
  const int idx = blockIdx.x * 256 + threadIdx.x;
  if (idx >= 64 * 3 * 112 * 112) return;
  const int cc = idx % 112;
  int t = idx / 112;
  const int rr = t % 112; t /= 112;
  const int ch = t % 3;
  const int b = t / 3;
  const float* ib = img + (size_t)b * 4 * 200704;
  float s = 0.f;
  for (int i = 0; i < 4; ++i)
    for (int j = 0; j < 4; ++j) {
      const int r = rr * 4 + i, c = cc * 4 + j;
      float v;
      if (ch == 0)      v = ib[(size_t)r * 448 + c];
      else if (ch == 1) v = 0.5f * (ib[200704 + (size_t)r * 448 + c] + ib[2 * 200704 + (size_t)r * 448 + c]);
      else              v = ib[3 * 200704 + (size_t)r * 448 + c];
      s += v;
    }
  x0[idx] = s * (1.f / 16.f);
}

// ---------------- conv as tiled GEMM (fp32, logical zero-pad, bias+relu fused) ----------------
// C[m][n] = sum_k W[m][k] * B[k][n];  m = out-channel, n = (b,oy,ox), k = (c,ky,kx)
// Identical index math to the verified direct conv; 64x64 tile, BK=16, 4x4 acc/thread.
template<int CIN, int HI, int WI, int KH, int KW, int STRIDE, int IPAD, int OH, int OW, int M>
__global__ __launch_bounds__(256) void k_conv_gemm(const float* __restrict__ in,
                                                   const float* __restrict__ w,
                                                   const float* __restrict__ bias,
                                                   float* __restrict__ out) {
  constexpr int K   = CIN * KH * KW;
  constexpr int KHW = KH * KW;
  constexpr int NPB = OH * OW;
  __shared__ float As[16][64];
  __shared__ float Bs[16][64];
  const int tid = threadIdx.x;
  const int n0 = blockIdx.x * 64, m0 = blockIdx.y * 64;
  // per-thread B column (fixed across K loop)
  const int nb = n0 + (tid & 63);
  const int kq = tid >> 6;                  // 0..3
  const int bB  = nb / NPB;
  const int rB  = nb % NPB;
  const int oyB = rB / OW, oxB = rB % OW;
  const int rowb = oyB * STRIDE - IPAD;
  const int colb = oxB * STRIDE - IPAD;
  const float* inb = in + (size_t)bB * CIN * HI * WI;
  // per-thread A element coords
  const int mA = tid >> 2, kqA = tid & 3;
  const float* wA = w + (size_t)(m0 + mA) * K;
  float acc[4][4] = {};
  const int tm = tid >> 4, tn = tid & 15;
  for (int k0 = 0; k0 < K; k0 += 16) {
    #pragma unroll
    for (int i = 0; i < 4; ++i) {
      const int k = k0 + kqA * 4 + i;
      As[kqA * 4 + i][mA] = (k < K) ? wA[k] : 0.f;
    }
    #pragma unroll
    for (int i = 0; i < 4; ++i) {
      const int k = k0 + kq * 4 + i;
      float v = 0.f;
      if (k < K) {
        const int c  = k / KHW;
        const int kr = k - c * KHW;
        const int ky = kr / KW, kx = kr - (kr / KW) * KW;
        const int r  = rowb + ky, cc = colb + kx;
        if (r >= 0 && r < HI && cc >= 0 && cc < WI)
          v = inb[((size_t)c * HI + r) * WI + cc];
      }
      Bs[kq * 4 + i][tid & 63] = v;
    }
    __syncthreads();
    #pragma unroll
    for (int kk = 0; kk < 16; ++kk) {
      const float4 a  = *(const float4*)&As[kk][tm * 4];
      const float4 bv = *(const float4*)&Bs[kk][tn * 4];
      const float av[4]  = {a.x, a.y, a.z, a.w};
      const float bvv[4] = {bv.x, bv.y, bv.z, bv.w};
      #pragma unroll
      for (int i = 0; i < 4; ++i)
        #pragma unroll
        for (int j = 0; j < 4; ++j)
          acc[i][j] += av[i] * bvv[j];
    }
    __syncthreads();
  }
  #pragma unroll
  for (int i = 0; i < 4; ++i) {
    const int m = m0 + tm * 4 + i;
    const float bi = bias[m];
    #pragma unroll
    for (int j = 0; j < 4; ++j) {
      const int n = n0 + tn * 4 + j;
      const int b = n / NPB;
      const int r = n % NPB;   // oy*OW + ox
      out[((size_t)b * M + m) * NPB + r] = fmaxf(acc[i][j] + bi, 0.f);
    }
  }
}

// ---------------- maxpool 3x3 stride 2, unpadded (verbatim r3) ----------------
template<int C, int HI, int HO>
__global__ __launch_bounds__(256) void k_pool(const float* __restrict__ in,
                                              float* __restrict__ out) {
  const int idx = blockIdx.x * 256 + threadIdx.x;
  constexpr int TOT = 64 * C * HO * HO;
  if (idx >= TOT) return;
  const int x = idx % HO;
  const int y = (idx / HO) % HO;
  const int c = (idx / (HO * HO)) % C;
  const int b = idx / (HO * HO * C);
  const float* ib = in + (size_t)(b * C + c) * HI * HI + (size_t)(y * 2) * HI + x * 2;
  float v = -INFINITY;
  #pragma unroll
  for (int i = 0; i < 3; ++i)
    #pragma unroll
    for (int j = 0; j < 3; ++j)
      v = fmaxf(v, ib[i * HI + j]);
  out[idx] = v;
}

// ---------------- parallel feature assembly (same math as verified serial) ----------------
__global__ __launch_bounds__(256) void k_feat(const float* __restrict__ p5,
                                              const float* __restrict__ hint,
                                              const float* __restrict__ hgrad,
                                              float* __restrict__ f) {
  const int b = blockIdx.x, tid = threadIdx.x;
  __shared__ float tmp4[4];
  __shared__ float vals[160];
  const float* ps = p5 + (size_t)b * 1024;
  float* fb = f + (size_t)b * 4096;
  float mv[4]; float ss = 0.f;
  #pragma unroll
  for (int i = 0; i < 4; ++i) { mv[i] = ps[tid + i * 256]; ss += mv[i] * mv[i]; }
  #pragma unroll
  for (int o = 32; o > 0; o >>= 1) ss += __shfl_down(ss, o, 64);
  if ((tid & 63) == 0) tmp4[tid >> 6] = ss;
  __syncthreads();
  const float inv = 1.f / (sqrtf(tmp4[0] + tmp4[1] + tmp4[2] + tmp4[3]) + 1e-7f);
  #pragma unroll
  for (int i = 0; i < 4; ++i) fb[tid + i * 256] = fmaxf(mv[i] * inv, 0.f);
  for (int ft = 0; ft < 2; ++ft) {
    const float* hb = (ft ? hgrad : hint) + (size_t)b * 160;
    __syncthreads();
    if (tid < 160) vals[tid] = hb[tid] * (tid < 32 ? (1.f / 200704.f) : (1.f / 50176.f));
    __syncthreads();
    float s2 = 0.f;
    if (tid < 160) s2 = (tid < 32 ? 16.f : 4.f) * vals[tid] * vals[tid];
    #pragma unroll
    for (int o = 32; o > 0; o >>= 1) s2 += __shfl_down(s2, o, 64);
    __syncthreads();
    if ((tid & 63) == 0) tmp4[tid >> 6] = s2;
    __syncthreads();
    const float inv2 = 1.f / (sqrtf(tmp4[0] + tmp4[1] + tmp4[2] + tmp4[3]) + 1e-7f);
    float* fo = fb + 1024 + ft * 1536;
    for (int idx = tid; idx < 1536; idx += 256) {
      const int ch = idx >> 4, i2 = (idx >> 2) & 3, j = idx & 3;
      float v;
      if (ch < 32)      v = vals[ch];
      else if (ch < 64) v = vals[32 + (((i2 >> 1) * 2) + (j >> 1)) * 32 + (ch - 32)];
      else              v = 0.f;
      fo[idx] = fmaxf(v * inv2, 0.f);
    }
  }
}

// ---------------- fc1: one wave per (b,oc) ----------------
__global__ __launch_bounds__(256) void k_fc1(const float* __restrict__ f,
                                             const float* __restrict__ w,
                                             const float* __restrict__ bias,
                                             float* __restrict__ h1) {
  const int gid = blockIdx.x * 4 + (threadIdx.x >> 6);
  const int lane = threadIdx.x & 63;
  if (gid >= 64 * 256) return;
  const int oc = gid & 255, b = gid >> 8;
  const float* fb = f + (size_t)b * 4096;
  const float* wr = w + (size_t)oc * 4096;
  float s = 0.f;
  for (int k = lane; k < 4096; k += 64) s += fb[k] * wr[k];
  #pragma unroll
  for (int o = 32; o > 0; o >>= 1) s += __shfl_down(s, o, 64);
  if (lane == 0) h1[(size_t)b * 256 + oc] = fmaxf(s + bias[oc], 0.f);
}

// ---------------- fc2 (verbatim r3) ----------------
__global__ __launch_bounds__(256) void k_fc2_simple(const float* __restrict__ h1,
                                                    const float* __restrict__ w,
                                                    const float* __restrict__ bias,
                                                    float* __restrict__ out) {
  const int idx = blockIdx.x * 256 + threadIdx.x;
  if (idx >= 64 * 12) return;
  const int oc = idx % 12, b = idx / 12;
  const float* hb = h1 + (size_t)b * 256;
  const float* wr = w + (size_t)oc * 256;
  float s = bias[oc];
  for (int k = 0; k < 256; ++k) s += hb[k] * wr[k];
  out[b * 12 + oc] = s;
}

// ---------------- launch ----------------
extern "C" void kernel_launch(void* const* d_in, const int* in_sizes, int n_in,
                              void* d_out, int out_size, void* d_ws, size_t ws_size,
                              hipStream_t stream) {
  const float* img  = (const float*)d_in[0];
  const float* w1 = (const float*)d_in[1];  const float* b1 = (const float*)d_in[2];
  const float* w2 = (const float*)d_in[3];  const float* b2 = (const float*)d_in[4];
  const float* w3 = (const float*)d_in[5];  const float* b3 = (const float*)d_in[6];
  const float* w4 = (const float*)d_in[7];  const float* b4 = (const float*)d_in[8];
  const float* w5 = (const float*)d_in[9];  const float* b5 = (const float*)d_in[10];
  const float* fc1w = (const float*)d_in[11]; const float* fc1b = (const float*)d_in[12];
  const float* fc2w = (const float*)d_in[13]; const float* fc2b = (const float*)d_in[14];
  float* out = (float*)d_out;
  float* ws  = (float*)d_ws;

  float* hint = ws + OFF_HINT;
  float* hgrd = ws + OFF_HGRD;
  float* f    = ws + OFF_F;
  float* h1   = ws + OFF_H1;
  float* p5   = ws + OFF_P5;
  float* r2   = ws + OFF_R2;   // x0, p1, p2, a4 (time-multiplexed)
  float* r1   = ws + OFF_R1;   // a1, a2, a3, a5 (time-multiplexed)

  hipMemsetAsync(hint, 0, (size_t)2 * 64 * 160 * sizeof(float), stream);

  k_preproc<<<dim3(64, 28), 256, 0, stream>>>(img, hint, hgrd);
  k_resize <<<(64*3*112*112 + 255)/256, 256, 0, stream>>>(img, r2);        // x0 in r2

  // conv1: 3x112x112 (pad2, s4) -> 64x27x27 ; N=64*729, M=64, K=363
  k_conv_gemm<3,112,112,11,11,4,2,27,27,64>
      <<<dim3(729, 1), 256, 0, stream>>>(r2, w1, b1, r1);                  // a1 in r1
  k_pool<64,27,13><<<(64*64*13*13 + 255)/256, 256, 0, stream>>>(r1, r2);   // p1 in r2
  // conv2: 64x13x13 (pad2) -> 192x13x13 ; N=64*169, M=192, K=1600
  k_conv_gemm<64,13,13,5,5,1,2,13,13,192>
      <<<dim3(169, 3), 256, 0, stream>>>(r2, w2, b2, r1);                  // a2 in r1
  k_pool<192,13,6><<<(64*192*6*6 + 255)/256, 256, 0, stream>>>(r1, r2);    // p2 in r2
  // conv3: 192x6x6 (pad1) -> 384x6x6 ; N=64*36, M=384, K=1728
  k_conv_gemm<192,6,6,3,3,1,1,6,6,384>
      <<<dim3(36, 6), 256, 0, stream>>>(r2, w3, b3, r1);                   // a3 in r1
  // conv4: 384x6x6 (pad1) -> 256x6x6 ; K=3456
  k_conv_gemm<384,6,6,3,3,1,1,6,6,256>
      <<<dim3(36, 4), 256, 0, stream>>>(r1, w4, b4, r2);                   // a4 in r2
  // conv5: 256x6x6 (pad1) -> 256x6x6 ; K=2304
  k_conv_gemm<256,6,6,3,3,1,1,6,6,256>
      <<<dim3(36, 4), 256, 0, stream>>>(r2, w5, b5, r1);                   // a5 in r1
  k_pool<256,6,2><<<(64*256*2*2 + 255)/256, 256, 0, stream>>>(r1, p5);

  k_feat<<<64, 256, 0, stream>>>(p5, hint, hgrd, f);
  k_fc1<<<(64*256)/4, 256, 0, stream>>>(f, fc1w, fc1b, h1);
  k_fc2_simple<<<(64*12 + 255)/256, 256, 0, stream>>>(h1, fc2w, fc2b, out);
}

// Round 5
// 867.631 us; speedup vs baseline: 5.6275x; 1.6719x over previous
//
#include <hip/hip_runtime.h>
#include <math.h>

typedef __attribute__((ext_vector_type(8))) short short8;
typedef __attribute__((ext_vector_type(8))) unsigned short u16x8;
typedef __attribute__((ext_vector_type(4))) float f32x4;

// ---------------- workspace layout (floats), ~5.76M floats = 22 MB ----------------
constexpr size_t OFF_HINT = 0;                              // 64*160
constexpr size_t OFF_HGRD = OFF_HINT + (size_t)64*160;      // 64*160
constexpr size_t OFF_F    = OFF_HGRD + (size_t)64*160;      // 64*4096
constexpr size_t OFF_H1   = OFF_F    + (size_t)64*4096;     // 64*256
constexpr size_t OFF_P5   = OFF_H1   + (size_t)64*256;      // 64*256*2*2
constexpr size_t OFF_R2   = OFF_P5   + (size_t)64*1024;     // region2: x0 / p1 / p2 / a4
constexpr size_t SZ_R2    = (size_t)64*3*112*112;           // max of x0,p1,p2,a4
constexpr size_t OFF_R1   = OFF_R2 + SZ_R2;                 // region1: a1 / a2 / a3 / a5
constexpr size_t SZ_R1    = (size_t)64*64*27*27;            // max of a1,a2,a3,a5
constexpr size_t WS_FLOATS = OFF_R1 + SZ_R1;                // 5,758,976

__device__ __forceinline__ float grayAt(const float* __restrict__ ib, int r, int c) {
  const size_t o = (size_t)r * 448 + c;
  return 0.299f * ib[o]
       + 0.587f * (0.5f * (ib[200704 + o] + ib[2 * 200704 + o]))
       + 0.114f * ib[3 * 200704 + o];
}

// bf16 hi/lo split (RNE), branchless
__device__ __forceinline__ void bf16split(float v, unsigned short& hi, unsigned short& lo) {
  union { float f; unsigned u; } a; a.f = v;
  unsigned uh = (a.u + 0x7FFFu + ((a.u >> 16) & 1u)) >> 16;
  hi = (unsigned short)uh;
  union { unsigned u; float f; } b; b.u = uh << 16;
  float rem = v - b.f;
  union { float f; unsigned u; } c; c.f = rem;
  lo = (unsigned short)((c.u + 0x7FFFu + ((c.u >> 16) & 1u)) >> 16);
}

// ---------------- fused: gray-strip -> intensity hist + sobel hist ----------------
__global__ __launch_bounds__(256) void k_preproc(const float* __restrict__ img,
                                                 float* __restrict__ hint,
                                                 float* __restrict__ hgrd) {
  const int b = blockIdx.x, s = blockIdx.y;   // 28 strips of 16 rows
  const int r0 = s * 16;
  __shared__ float gs[18][448];
  __shared__ float lhi[160], lhs[160];
  const int tid = threadIdx.x;
  for (int i = tid; i < 160; i += 256) { lhi[i] = 0.f; lhs[i] = 0.f; }
  const float* ib = img + (size_t)b * 4 * 200704;
  for (int p = tid; p < 18 * 448; p += 256) {
    const int rr = p / 448, c = p % 448;
    int r = r0 + rr - 1; r = r < 0 ? 0 : (r > 447 ? 447 : r);
    gs[rr][c] = grayAt(ib, r, c);
  }
  __syncthreads();
  for (int p = tid; p < 16 * 448; p += 256) {
    const int dr = p / 448, c = p % 448;
    const int r = r0 + dr;
    const int quad = ((r >= 224) ? 2 : 0) + ((c >= 224) ? 1 : 0);
    const float g = gs[dr + 1][c];
    int bin = (int)(g * 32.f); bin = bin > 31 ? 31 : (bin < 0 ? 0 : bin);
    atomicAdd(&lhi[bin], 1.f);
    atomicAdd(&lhi[32 + quad * 32 + bin], 1.f);
    const int cm = c > 0 ? c - 1 : 0, cp = c < 447 ? c + 1 : 447;
    const float a00 = gs[dr][cm],     a01 = gs[dr][c],     a02 = gs[dr][cp];
    const float a10 = gs[dr + 1][cm],                      a12 = gs[dr + 1][cp];
    const float a20 = gs[dr + 2][cm], a21 = gs[dr + 2][c], a22 = gs[dr + 2][cp];
    const float gx = (-a00 + a02 - 2.f * a10 + 2.f * a12 - a20 + a22) * 0.125f;
    const float gy = (-a00 - 2.f * a01 - a02 + a20 + 2.f * a21 + a22) * 0.125f;
    const float mag = sqrtf(gx * gx + gy * gy + 1e-6f);
    int sb = (int)(mag * 32.f); sb = sb > 31 ? 31 : (sb < 0 ? 0 : sb);
    atomicAdd(&lhs[sb], 1.f);
    atomicAdd(&lhs[32 + quad * 32 + sb], 1.f);
  }
  __syncthreads();
  if (tid < 160) {
    atomicAdd(&hint[(size_t)b * 160 + tid], lhi[tid]);
    atomicAdd(&hgrd[(size_t)b * 160 + tid], lhs[tid]);
  }
}

// ---------------- area resize 448->112 ----------------
__global__ __launch_bounds__(256) void k_resize(const float* __restrict__ img,
                                                float* __restrict__ x0) {
  const int idx = blockIdx.x * 256 + threadIdx.x;
  if (idx >= 64 * 3 * 112 * 112) return;
  const int cc = idx % 112;
  int t = idx / 112;
  const int rr = t % 112; t /= 112;
  const int ch = t % 3;
  const int b = t / 3;
  const float* ib = img + (size_t)b * 4 * 200704;
  float s = 0.f;
  for (int i = 0; i < 4; ++i)
    for (int j = 0; j < 4; ++j) {
      const int r = rr * 4 + i, c = cc * 4 + j;
      float v;
      if (ch == 0)      v = ib[(size_t)r * 448 + c];
      else if (ch == 1) v = 0.5f * (ib[200704 + (size_t)r * 448 + c] + ib[2 * 200704 + (size_t)r * 448 + c]);
      else              v = ib[3 * 200704 + (size_t)r * 448 + c];
      s += v;
    }
  x0[idx] = s * (1.f / 16.f);
}

// ---------------- conv as MFMA GEMM (bf16 hi/lo split, fp32-grade accuracy) ----------------
// C[m][n] = sum_k W[m][k]*B[k][n]; m=oc, n=(b,oy,ox), k=(c,ky,kx). 64x64 tile, BK=64.
// LDS tiles [64 rows][64 k] bf16, 128B rows, chunk^=(row&7) XOR swizzle (16B chunks).
template<int CIN, int HI, int WI, int KH, int KW, int STRIDE, int IPAD, int OH, int OW, int M>
__global__ __launch_bounds__(256) void k_conv_mfma(const float* __restrict__ in,
                                                   const float* __restrict__ w,
                                                   const float* __restrict__ bias,
                                                   float* __restrict__ out) {
  constexpr int K_TOT = CIN * KH * KW;
  constexpr int KHW   = KH * KW;
  constexpr int NPB   = OH * OW;
  constexpr int KSTEPS = (K_TOT + 63) / 64;
  __shared__ unsigned short Ahi[64 * 64], Alo[64 * 64];
  __shared__ unsigned short Bhi[64 * 64], Blo[64 * 64];
  const int tid  = threadIdx.x;
  const int lane = tid & 63, wv = tid >> 6;
  const int n0 = blockIdx.x * 64, m0 = blockIdx.y * 64;
  // staging coords: each thread owns (row_s, 16 k's)
  const int row_s = tid & 63, kc2 = tid >> 6;       // kc2: which 16-k chunk pair
  const float* gA = w + (size_t)(m0 + row_s) * K_TOT;
  const int nb  = n0 + row_s;
  const int bB  = nb / NPB;
  const int rB  = nb % NPB;
  const int oyB = rB / OW, oxB = rB % OW;
  const int rowb = oyB * STRIDE - IPAD;
  const int colb = oxB * STRIDE - IPAD;
  const float* inb = in + (size_t)bB * CIN * HI * WI;
  f32x4 acc[4] = {};
  // compute-side coords
  const int rA = wv * 16 + (lane & 15);             // A row (m_local)
  const int kg = lane >> 4;                          // k-group 0..3

  for (int step = 0; step < KSTEPS; ++step) {
    const int kbase = step * 64 + kc2 * 16;
    // ---- stage A (weights): 16 contiguous fp32 ----
    float va[16];
    if constexpr (K_TOT % 64 == 0) {
      const float4 v0 = *(const float4*)&gA[kbase + 0];
      const float4 v1 = *(const float4*)&gA[kbase + 4];
      const float4 v2 = *(const float4*)&gA[kbase + 8];
      const float4 v3 = *(const float4*)&gA[kbase + 12];
      va[0]=v0.x; va[1]=v0.y; va[2]=v0.z; va[3]=v0.w;
      va[4]=v1.x; va[5]=v1.y; va[6]=v1.z; va[7]=v1.w;
      va[8]=v2.x; va[9]=v2.y; va[10]=v2.z; va[11]=v2.w;
      va[12]=v3.x; va[13]=v3.y; va[14]=v3.z; va[15]=v3.w;
    } else {
      #pragma unroll
      for (int j = 0; j < 16; ++j) {
        const int k = kbase + j;
        va[j] = (k < K_TOT) ? gA[k] : 0.f;
      }
    }
    u16x8 ah0, al0, ah1, al1;
    #pragma unroll
    for (int j = 0; j < 8; ++j) {
      unsigned short h, l;
      bf16split(va[j], h, l);     ah0[j] = h; al0[j] = l;
      bf16split(va[8 + j], h, l); ah1[j] = h; al1[j] = l;
    }
    {
      const int c0 = kc2 * 2, c1 = c0 + 1, r = row_s;
      *(u16x8*)&Ahi[r * 64 + ((c0 ^ (r & 7)) * 8)] = ah0;
      *(u16x8*)&Ahi[r * 64 + ((c1 ^ (r & 7)) * 8)] = ah1;
      *(u16x8*)&Alo[r * 64 + ((c0 ^ (r & 7)) * 8)] = al0;
      *(u16x8*)&Alo[r * 64 + ((c1 ^ (r & 7)) * 8)] = al1;
    }
    // ---- stage B (implicit im2col): 16 guarded fp32 ----
    float vb[16];
    #pragma unroll
    for (int j = 0; j < 16; ++j) {
      const int k = kbase + j;
      float v = 0.f;
      if (k < K_TOT) {
        const int c  = k / KHW;
        const int kr = k - c * KHW;
        const int ky = kr / KW, kx = kr - (kr / KW) * KW;
        const int r  = rowb + ky, cc = colb + kx;
        if (r >= 0 && r < HI && cc >= 0 && cc < WI)
          v = inb[((size_t)c * HI + r) * WI + cc];
      }
      vb[j] = v;
    }
    u16x8 bh0, bl0, bh1, bl1;
    #pragma unroll
    for (int j = 0; j < 8; ++j) {
      unsigned short h, l;
      bf16split(vb[j], h, l);     bh0[j] = h; bl0[j] = l;
      bf16split(vb[8 + j], h, l); bh1[j] = h; bl1[j] = l;
    }
    {
      const int c0 = kc2 * 2, c1 = c0 + 1, r = row_s;  // r = col for B
      *(u16x8*)&Bhi[r * 64 + ((c0 ^ (r & 7)) * 8)] = bh0;
      *(u16x8*)&Bhi[r * 64 + ((c1 ^ (r & 7)) * 8)] = bh1;
      *(u16x8*)&Blo[r * 64 + ((c0 ^ (r & 7)) * 8)] = bl0;
      *(u16x8*)&Blo[r * 64 + ((c1 ^ (r & 7)) * 8)] = bl1;
    }
    __syncthreads();
    // ---- compute: 2 sub-steps of K=32, 4 n-tiles, 3 MFMAs each (hi/lo) ----
    #pragma unroll
    for (int s = 0; s < 2; ++s) {
      const int cA = s * 4 + kg;
      const short8 a_h = *(const short8*)&Ahi[rA * 64 + ((cA ^ (rA & 7)) * 8)];
      const short8 a_l = *(const short8*)&Alo[rA * 64 + ((cA ^ (rA & 7)) * 8)];
      #pragma unroll
      for (int t = 0; t < 4; ++t) {
        const int col = t * 16 + (lane & 15);
        const short8 b_h = *(const short8*)&Bhi[col * 64 + ((cA ^ (col & 7)) * 8)];
        const short8 b_l = *(const short8*)&Blo[col * 64 + ((cA ^ (col & 7)) * 8)];
        acc[t] = __builtin_amdgcn_mfma_f32_16x16x32_bf16(a_h, b_h, acc[t], 0, 0, 0);
        acc[t] = __builtin_amdgcn_mfma_f32_16x16x32_bf16(a_h, b_l, acc[t], 0, 0, 0);
        acc[t] = __builtin_amdgcn_mfma_f32_16x16x32_bf16(a_l, b_h, acc[t], 0, 0, 0);
      }
    }
    __syncthreads();
  }
  // ---- epilogue: D col=lane&15, row=(lane>>4)*4+q ----
  #pragma unroll
  for (int q = 0; q < 4; ++q) {
    const int m = m0 + wv * 16 + (lane >> 4) * 4 + q;
    const float bi = bias[m];
    #pragma unroll
    for (int t = 0; t < 4; ++t) {
      const int n = n0 + t * 16 + (lane & 15);
      const int b = n / NPB;
      const int r = n % NPB;
      out[((size_t)b * M + m) * NPB + r] = fmaxf(acc[t][q] + bi, 0.f);
    }
  }
}

// ---------------- maxpool 3x3 stride 2, unpadded ----------------
template<int C, int HI, int HO>
__global__ __launch_bounds__(256) void k_pool(const float* __restrict__ in,
                                              float* __restrict__ out) {
  const int idx = blockIdx.x * 256 + threadIdx.x;
  constexpr int TOT = 64 * C * HO * HO;
  if (idx >= TOT) return;
  const int x = idx % HO;
  const int y = (idx / HO) % HO;
  const int c = (idx / (HO * HO)) % C;
  const int b = idx / (HO * HO * C);
  const float* ib = in + (size_t)(b * C + c) * HI * HI + (size_t)(y * 2) * HI + x * 2;
  float v = -INFINITY;
  #pragma unroll
  for (int i = 0; i < 3; ++i)
    #pragma unroll
    for (int j = 0; j < 3; ++j)
      v = fmaxf(v, ib[i * HI + j]);
  out[idx] = v;
}

// ---------------- parallel feature assembly ----------------
__global__ __launch_bounds__(256) void k_feat(const float* __restrict__ p5,
                                              const float* __restrict__ hint,
                                              const float* __restrict__ hgrad,
                                              float* __restrict__ f) {
  const int b = blockIdx.x, tid = threadIdx.x;
  __shared__ float tmp4[4];
  __shared__ float vals[160];
  const float* ps = p5 + (size_t)b * 1024;
  float* fb = f + (size_t)b * 4096;
  float mv[4]; float ss = 0.f;
  #pragma unroll
  for (int i = 0; i < 4; ++i) { mv[i] = ps[tid + i * 256]; ss += mv[i] * mv[i]; }
  #pragma unroll
  for (int o = 32; o > 0; o >>= 1) ss += __shfl_down(ss, o, 64);
  if ((tid & 63) == 0) tmp4[tid >> 6] = ss;
  __syncthreads();
  const float inv = 1.f / (sqrtf(tmp4[0] + tmp4[1] + tmp4[2] + tmp4[3]) + 1e-7f);
  #pragma unroll
  for (int i = 0; i < 4; ++i) fb[tid + i * 256] = fmaxf(mv[i] * inv, 0.f);
  for (int ft = 0; ft < 2; ++ft) {
    const float* hb = (ft ? hgrad : hint) + (size_t)b * 160;
    __syncthreads();
    if (tid < 160) vals[tid] = hb[tid] * (tid < 32 ? (1.f / 200704.f) : (1.f / 50176.f));
    __syncthreads();
    float s2 = 0.f;
    if (tid < 160) s2 = (tid < 32 ? 16.f : 4.f) * vals[tid] * vals[tid];
    #pragma unroll
    for (int o = 32; o > 0; o >>= 1) s2 += __shfl_down(s2, o, 64);
    __syncthreads();
    if ((tid & 63) == 0) tmp4[tid >> 6] = s2;
    __syncthreads();
    const float inv2 = 1.f / (sqrtf(tmp4[0] + tmp4[1] + tmp4[2] + tmp4[3]) + 1e-7f);
    float* fo = fb + 1024 + ft * 1536;
    for (int idx = tid; idx < 1536; idx += 256) {
      const int ch = idx >> 4, i2 = (idx >> 2) & 3, j = idx & 3;
      float v;
      if (ch < 32)      v = vals[ch];
      else if (ch < 64) v = vals[32 + (((i2 >> 1) * 2) + (j >> 1)) * 32 + (ch - 32)];
      else              v = 0.f;
      fo[idx] = fmaxf(v * inv2, 0.f);
    }
  }
}

// ---------------- fc1: one wave per (b,oc) ----------------
__global__ __launch_bounds__(256) void k_fc1(const float* __restrict__ f,
                                             const float* __restrict__ w,
                                             const float* __restrict__ bias,
                                             float* __restrict__ h1) {
  const int gid = blockIdx.x * 4 + (threadIdx.x >> 6);
  const int lane = threadIdx.x & 63;
  if (gid >= 64 * 256) return;
  const int oc = gid & 255, b = gid >> 8;
  const float* fb = f + (size_t)b * 4096;
  const float* wr = w + (size_t)oc * 4096;
  float s = 0.f;
  for (int k = lane; k < 4096; k += 64) s += fb[k] * wr[k];
  #pragma unroll
  for (int o = 32; o > 0; o >>= 1) s += __shfl_down(s, o, 64);
  if (lane == 0) h1[(size_t)b * 256 + oc] = fmaxf(s + bias[oc], 0.f);
}

// ---------------- fc2 ----------------
__global__ __launch_bounds__(256) void k_fc2_simple(const float* __restrict__ h1,
                                                    const float* __restrict__ w,
                                                    const float* __restrict__ bias,
                                                    float* __restrict__ out) {
  const int idx = blockIdx.x * 256 + threadIdx.x;
  if (idx >= 64 * 12) return;
  const int oc = idx % 12, b = idx / 12;
  const float* hb = h1 + (size_t)b * 256;
  const float* wr = w + (size_t)oc * 256;
  float s = bias[oc];
  for (int k = 0; k < 256; ++k) s += hb[k] * wr[k];
  out[b * 12 + oc] = s;
}

// ---------------- launch ----------------
extern "C" void kernel_launch(void* const* d_in, const int* in_sizes, int n_in,
                              void* d_out, int out_size, void* d_ws, size_t ws_size,
                              hipStream_t stream) {
  const float* img  = (const float*)d_in[0];
  const float* w1 = (const float*)d_in[1];  const float* b1 = (const float*)d_in[2];
  const float* w2 = (const float*)d_in[3];  const float* b2 = (const float*)d_in[4];
  const float* w3 = (const float*)d_in[5];  const float* b3 = (const float*)d_in[6];
  const float* w4 = (const float*)d_in[7];  const float* b4 = (const float*)d_in[8];
  const float* w5 = (const float*)d_in[9];  const float* b5 = (const float*)d_in[10];
  const float* fc1w = (const float*)d_in[11]; const float* fc1b = (const float*)d_in[12];
  const float* fc2w = (const float*)d_in[13]; const float* fc2b = (const float*)d_in[14];
  float* out = (float*)d_out;
  float* ws  = (float*)d_ws;

  float* hint = ws + OFF_HINT;
  float* hgrd = ws + OFF_HGRD;
  float* f    = ws + OFF_F;
  float* h1   = ws + OFF_H1;
  float* p5   = ws + OFF_P5;
  float* r2   = ws + OFF_R2;   // x0, p1, p2, a4 (time-multiplexed)
  float* r1   = ws + OFF_R1;   // a1, a2, a3, a5 (time-multiplexed)

  hipMemsetAsync(hint, 0, (size_t)2 * 64 * 160 * sizeof(float), stream);

  k_preproc<<<dim3(64, 28), 256, 0, stream>>>(img, hint, hgrd);
  k_resize <<<(64*3*112*112 + 255)/256, 256, 0, stream>>>(img, r2);        // x0 in r2

  // conv1: 3x112x112 (pad2, s4) -> 64x27x27 ; N=46656, M=64, K=363
  k_conv_mfma<3,112,112,11,11,4,2,27,27,64>
      <<<dim3(729, 1), 256, 0, stream>>>(r2, w1, b1, r1);                  // a1 in r1
  k_pool<64,27,13><<<(64*64*13*13 + 255)/256, 256, 0, stream>>>(r1, r2);   // p1 in r2
  // conv2: 64x13x13 (pad2) -> 192x13x13 ; N=10816, M=192, K=1600
  k_conv_mfma<64,13,13,5,5,1,2,13,13,192>
      <<<dim3(169, 3), 256, 0, stream>>>(r2, w2, b2, r1);                  // a2 in r1
  k_pool<192,13,6><<<(64*192*6*6 + 255)/256, 256, 0, stream>>>(r1, r2);    // p2 in r2
  // conv3: 192x6x6 (pad1) -> 384x6x6 ; N=2304, M=384, K=1728
  k_conv_mfma<192,6,6,3,3,1,1,6,6,384>
      <<<dim3(36, 6), 256, 0, stream>>>(r2, w3, b3, r1);                   // a3 in r1
  // conv4: 384x6x6 (pad1) -> 256x6x6 ; K=3456
  k_conv_mfma<384,6,6,3,3,1,1,6,6,256>
      <<<dim3(36, 4), 256, 0, stream>>>(r1, w4, b4, r2);                   // a4 in r2
  // conv5: 256x6x6 (pad1) -> 256x6x6 ; K=2304
  k_conv_mfma<256,6,6,3,3,1,1,6,6,256>
      <<<dim3(36, 4), 256, 0, stream>>>(r2, w5, b5, r1);                   // a5 in r1
  k_pool<256,6,2><<<(64*256*2*2 + 255)/256, 256, 0, stream>>>(r1, p5);

  k_feat<<<64, 256, 0, stream>>>(p5, hint, hgrd, f);
  k_fc1<<<(64*256)/4, 256, 0, stream>>>(f, fc1w, fc1b, h1);
  k_fc2_simple<<<(64*12 + 255)/256, 256, 0, stream>>>(h1, fc2w, fc2b, out);
}

// Round 6
// 729.876 us; speedup vs baseline: 6.6896x; 1.1887x over previous
//
#include <hip/hip_runtime.h>
#include <math.h>

typedef __attribute__((ext_vector_type(8))) short short8;
typedef __attribute__((ext_vector_type(8))) unsigned short u16x8;
typedef __attribute__((ext_vector_type(4))) float f32x4;

// ---------------- workspace layout (floats), ~5.76M floats = 22 MB ----------------
constexpr size_t OFF_HINT = 0;                              // 64*160
constexpr size_t OFF_HGRD = OFF_HINT + (size_t)64*160;      // 64*160
constexpr size_t OFF_F    = OFF_HGRD + (size_t)64*160;      // 64*4096
constexpr size_t OFF_H1   = OFF_F    + (size_t)64*4096;     // 64*256
constexpr size_t OFF_P5   = OFF_H1   + (size_t)64*256;      // 64*256*2*2
constexpr size_t OFF_R2   = OFF_P5   + (size_t)64*1024;     // region2: x0 / p1 / p2 / a4
constexpr size_t SZ_R2    = (size_t)64*3*112*112;           // max of x0,p1,p2,a4
constexpr size_t OFF_R1   = OFF_R2 + SZ_R2;                 // region1: a1 / a2 / a3 / a5
constexpr size_t SZ_R1    = (size_t)64*64*27*27;            // max of a1,a2,a3,a5
constexpr size_t WS_FLOATS = OFF_R1 + SZ_R1;                // 5,758,976

// bf16 hi/lo split (RNE), branchless
__device__ __forceinline__ void bf16split(float v, unsigned short& hi, unsigned short& lo) {
  union { float f; unsigned u; } a; a.f = v;
  unsigned uh = (a.u + 0x7FFFu + ((a.u >> 16) & 1u)) >> 16;
  hi = (unsigned short)uh;
  union { unsigned u; float f; } b; b.u = uh << 16;
  float rem = v - b.f;
  union { float f; unsigned u; } c; c.f = rem;
  lo = (unsigned short)((c.u + 0x7FFFu + ((c.u >> 16) & 1u)) >> 16);
}

// ---------------- fused preproc: gray strip -> intensity + sobel QUADRANT hists ----------------
// Whole-image hist = sum of quadrant hists (exact integer identity) -> reconstructed in k_feat.
__global__ __launch_bounds__(256) void k_preproc(const float* __restrict__ img,
                                                 float* __restrict__ hint,
                                                 float* __restrict__ hgrd) {
  const int b = blockIdx.x, s = blockIdx.y;   // 28 strips of 16 rows
  const int r0 = s * 16;
  __shared__ float gs[18][448];
  __shared__ float lhi_w[4][128], lhs_w[4][128];   // per-wave quad*32+bin
  const int tid = threadIdx.x, wv = tid >> 6;
  for (int i = tid; i < 4 * 128; i += 256) { ((float*)lhi_w)[i] = 0.f; ((float*)lhs_w)[i] = 0.f; }
  const float* ib = img + (size_t)b * 4 * 200704;
  // stage gray: float4 per channel, 4 pixels/thread-iter
  for (int i = tid; i < 18 * 112; i += 256) {
    const int rr = i / 112, c4 = (i % 112) * 4;
    int r = r0 + rr - 1; r = r < 0 ? 0 : (r > 447 ? 447 : r);
    const size_t o = (size_t)r * 448 + c4;
    const float4 vr = *(const float4*)&ib[o];
    const float4 g1 = *(const float4*)&ib[200704 + o];
    const float4 g2 = *(const float4*)&ib[2 * 200704 + o];
    const float4 vb = *(const float4*)&ib[3 * 200704 + o];
    float4 g;
    g.x = 0.299f * vr.x + 0.587f * (0.5f * (g1.x + g2.x)) + 0.114f * vb.x;
    g.y = 0.299f * vr.y + 0.587f * (0.5f * (g1.y + g2.y)) + 0.114f * vb.y;
    g.z = 0.299f * vr.z + 0.587f * (0.5f * (g1.z + g2.z)) + 0.114f * vb.z;
    g.w = 0.299f * vr.w + 0.587f * (0.5f * (g1.w + g2.w)) + 0.114f * vb.w;
    *(float4*)&gs[rr][c4] = g;
  }
  __syncthreads();
  // process 4 pixels/thread-iter
  for (int i = tid; i < 16 * 112; i += 256) {
    const int dr = i / 112, c4 = (i % 112) * 4;
    const int r = r0 + dr;
    const int quad = ((r >= 224) ? 2 : 0) + ((c4 >= 224) ? 1 : 0);
    const int cl = c4 > 0 ? c4 - 1 : 0;
    const int cr = c4 < 444 ? c4 + 4 : 447;
    const float4 m0 = *(const float4*)&gs[dr][c4];
    const float4 m1 = *(const float4*)&gs[dr + 1][c4];
    const float4 m2 = *(const float4*)&gs[dr + 2][c4];
    const float r0v[6] = {gs[dr][cl],     m0.x, m0.y, m0.z, m0.w, gs[dr][cr]};
    const float r1v[6] = {gs[dr + 1][cl], m1.x, m1.y, m1.z, m1.w, gs[dr + 1][cr]};
    const float r2v[6] = {gs[dr + 2][cl], m2.x, m2.y, m2.z, m2.w, gs[dr + 2][cr]};
    float* hi = lhi_w[wv];
    float* hs = lhs_w[wv];
    #pragma unroll
    for (int j = 0; j < 4; ++j) {
      const float g = r1v[j + 1];
      int bin = (int)(g * 32.f); bin = bin > 31 ? 31 : (bin < 0 ? 0 : bin);
      atomicAdd(&hi[quad * 32 + bin], 1.f);
      const float gx = (-r0v[j] + r0v[j + 2] - 2.f * r1v[j] + 2.f * r1v[j + 2]
                        - r2v[j] + r2v[j + 2]) * 0.125f;
      const float gy = (-r0v[j] - 2.f * r0v[j + 1] - r0v[j + 2]
                        + r2v[j] + 2.f * r2v[j + 1] + r2v[j + 2]) * 0.125f;
      const float mag = sqrtf(gx * gx + gy * gy + 1e-6f);
      int sb = (int)(mag * 32.f); sb = sb > 31 ? 31 : (sb < 0 ? 0 : sb);
      atomicAdd(&hs[quad * 32 + sb], 1.f);
    }
  }
  __syncthreads();
  for (int idx = tid; idx < 128; idx += 256) {
    atomicAdd(&hint[(size_t)b * 160 + 32 + idx],
              lhi_w[0][idx] + lhi_w[1][idx] + lhi_w[2][idx] + lhi_w[3][idx]);
    atomicAdd(&hgrd[(size_t)b * 160 + 32 + idx],
              lhs_w[0][idx] + lhs_w[1][idx] + lhs_w[2][idx] + lhs_w[3][idx]);
  }
}

// ---------------- area resize 448->112, vectorized: 1 thread = 1 output pixel, 3 channels ----------------
__global__ __launch_bounds__(256) void k_resize(const float* __restrict__ img,
                                                float* __restrict__ x0) {
  const int idx = blockIdx.x * 256 + threadIdx.x;
  if (idx >= 64 * 112 * 112) return;
  const int cc = idx % 112;
  const int rr = (idx / 112) % 112;
  const int b  = idx / (112 * 112);
  const float* ib = img + (size_t)b * 4 * 200704;
  float sr = 0.f, sg = 0.f, sb = 0.f;
  #pragma unroll
  for (int i = 0; i < 4; ++i) {
    const size_t o = (size_t)(rr * 4 + i) * 448 + cc * 4;
    const float4 vr = *(const float4*)&ib[o];
    const float4 g1 = *(const float4*)&ib[200704 + o];
    const float4 g2 = *(const float4*)&ib[2 * 200704 + o];
    const float4 vb = *(const float4*)&ib[3 * 200704 + o];
    sr += vr.x + vr.y + vr.z + vr.w;
    sg += 0.5f * (g1.x + g2.x) + 0.5f * (g1.y + g2.y) + 0.5f * (g1.z + g2.z) + 0.5f * (g1.w + g2.w);
    sb += vb.x + vb.y + vb.z + vb.w;
  }
  float* xb = x0 + (size_t)b * 3 * 112 * 112 + (size_t)rr * 112 + cc;
  xb[0]              = sr * (1.f / 16.f);
  xb[112 * 112]      = sg * (1.f / 16.f);
  xb[2 * 112 * 112]  = sb * (1.f / 16.f);
}

// ---------------- conv as MFMA GEMM (bf16 hi/lo split) — verbatim r5 ----------------
template<int CIN, int HI, int WI, int KH, int KW, int STRIDE, int IPAD, int OH, int OW, int M>
__global__ __launch_bounds__(256) void k_conv_mfma(const float* __restrict__ in,
                                                   const float* __restrict__ w,
                                                   const float* __restrict__ bias,
                                                   float* __restrict__ out) {
  constexpr int K_TOT = CIN * KH * KW;
  constexpr int KHW   = KH * KW;
  constexpr int NPB   = OH * OW;
  constexpr int KSTEPS = (K_TOT + 63) / 64;
  __shared__ unsigned short Ahi[64 * 64], Alo[64 * 64];
  __shared__ unsigned short Bhi[64 * 64], Blo[64 * 64];
  const int tid  = threadIdx.x;
  const int lane = tid & 63, wv = tid >> 6;
  const int n0 = blockIdx.x * 64, m0 = blockIdx.y * 64;
  const int row_s = tid & 63, kc2 = tid >> 6;
  const float* gA = w + (size_t)(m0 + row_s) * K_TOT;
  const int nb  = n0 + row_s;
  const int bB  = nb / NPB;
  const int rB  = nb % NPB;
  const int oyB = rB / OW, oxB = rB % OW;
  const int rowb = oyB * STRIDE - IPAD;
  const int colb = oxB * STRIDE - IPAD;
  const float* inb = in + (size_t)bB * CIN * HI * WI;
  f32x4 acc[4] = {};
  const int rA = wv * 16 + (lane & 15);
  const int kg = lane >> 4;

  for (int step = 0; step < KSTEPS; ++step) {
    const int kbase = step * 64 + kc2 * 16;
    float va[16];
    if constexpr (K_TOT % 64 == 0) {
      const float4 v0 = *(const float4*)&gA[kbase + 0];
      const float4 v1 = *(const float4*)&gA[kbase + 4];
      const float4 v2 = *(const float4*)&gA[kbase + 8];
      const float4 v3 = *(const float4*)&gA[kbase + 12];
      va[0]=v0.x; va[1]=v0.y; va[2]=v0.z; va[3]=v0.w;
      va[4]=v1.x; va[5]=v1.y; va[6]=v1.z; va[7]=v1.w;
      va[8]=v2.x; va[9]=v2.y; va[10]=v2.z; va[11]=v2.w;
      va[12]=v3.x; va[13]=v3.y; va[14]=v3.z; va[15]=v3.w;
    } else {
      #pragma unroll
      for (int j = 0; j < 16; ++j) {
        const int k = kbase + j;
        va[j] = (k < K_TOT) ? gA[k] : 0.f;
      }
    }
    u16x8 ah0, al0, ah1, al1;
    #pragma unroll
    for (int j = 0; j < 8; ++j) {
      unsigned short h, l;
      bf16split(va[j], h, l);     ah0[j] = h; al0[j] = l;
      bf16split(va[8 + j], h, l); ah1[j] = h; al1[j] = l;
    }
    {
      const int c0 = kc2 * 2, c1 = c0 + 1, r = row_s;
      *(u16x8*)&Ahi[r * 64 + ((c0 ^ (r & 7)) * 8)] = ah0;
      *(u16x8*)&Ahi[r * 64 + ((c1 ^ (r & 7)) * 8)] = ah1;
      *(u16x8*)&Alo[r * 64 + ((c0 ^ (r & 7)) * 8)] = al0;
      *(u16x8*)&Alo[r * 64 + ((c1 ^ (r & 7)) * 8)] = al1;
    }
    float vb[16];
    #pragma unroll
    for (int j = 0; j < 16; ++j) {
      const int k = kbase + j;
      float v = 0.f;
      if (k < K_TOT) {
        const int c  = k / KHW;
        const int kr = k - c * KHW;
        const int ky = kr / KW, kx = kr - (kr / KW) * KW;
        const int r  = rowb + ky, cc = colb + kx;
        if (r >= 0 && r < HI && cc >= 0 && cc < WI)
          v = inb[((size_t)c * HI + r) * WI + cc];
      }
      vb[j] = v;
    }
    u16x8 bh0, bl0, bh1, bl1;
    #pragma unroll
    for (int j = 0; j < 8; ++j) {
      unsigned short h, l;
      bf16split(vb[j], h, l);     bh0[j] = h; bl0[j] = l;
      bf16split(vb[8 + j], h, l); bh1[j] = h; bl1[j] = l;
    }
    {
      const int c0 = kc2 * 2, c1 = c0 + 1, r = row_s;
      *(u16x8*)&Bhi[r * 64 + ((c0 ^ (r & 7)) * 8)] = bh0;
      *(u16x8*)&Bhi[r * 64 + ((c1 ^ (r & 7)) * 8)] = bh1;
      *(u16x8*)&Blo[r * 64 + ((c0 ^ (r & 7)) * 8)] = bl0;
      *(u16x8*)&Blo[r * 64 + ((c1 ^ (r & 7)) * 8)] = bl1;
    }
    __syncthreads();
    #pragma unroll
    for (int s = 0; s < 2; ++s) {
      const int cA = s * 4 + kg;
      const short8 a_h = *(const short8*)&Ahi[rA * 64 + ((cA ^ (rA & 7)) * 8)];
      const short8 a_l = *(const short8*)&Alo[rA * 64 + ((cA ^ (rA & 7)) * 8)];
      #pragma unroll
      for (int t = 0; t < 4; ++t) {
        const int col = t * 16 + (lane & 15);
        const short8 b_h = *(const short8*)&Bhi[col * 64 + ((cA ^ (col & 7)) * 8)];
        const short8 b_l = *(const short8*)&Blo[col * 64 + ((cA ^ (col & 7)) * 8)];
        acc[t] = __builtin_amdgcn_mfma_f32_16x16x32_bf16(a_h, b_h, acc[t], 0, 0, 0);
        acc[t] = __builtin_amdgcn_mfma_f32_16x16x32_bf16(a_h, b_l, acc[t], 0, 0, 0);
        acc[t] = __builtin_amdgcn_mfma_f32_16x16x32_bf16(a_l, b_h, acc[t], 0, 0, 0);
      }
    }
    __syncthreads();
  }
  #pragma unroll
  for (int q = 0; q < 4; ++q) {
    const int m = m0 + wv * 16 + (lane >> 4) * 4 + q;
    const float bi = bias[m];
    #pragma unroll
    for (int t = 0; t < 4; ++t) {
      const int n = n0 + t * 16 + (lane & 15);
      const int b = n / NPB;
      const int r = n % NPB;
      out[((size_t)b * M + m) * NPB + r] = fmaxf(acc[t][q] + bi, 0.f);
    }
  }
}

// ---------------- maxpool 3x3 stride 2, unpadded ----------------
template<int C, int HI, int HO>
__global__ __launch_bounds__(256) void k_pool(const float* __restrict__ in,
                                              float* __restrict__ out) {
  const int idx = blockIdx.x * 256 + threadIdx.x;
  constexpr int TOT = 64 * C * HO * HO;
  if (idx >= TOT) return;
  const int x = idx % HO;
  const int y = (idx / HO) % HO;
  const int c = (idx / (HO * HO)) % C;
  const int b = idx / (HO * HO * C);
  const float* ib = in + (size_t)(b * C + c) * HI * HI + (size_t)(y * 2) * HI + x * 2;
  float v = -INFINITY;
  #pragma unroll
  for (int i = 0; i < 3; ++i)
    #pragma unroll
    for (int j = 0; j < 3; ++j)
      v = fmaxf(v, ib[i * HI + j]);
  out[idx] = v;
}

// ---------------- feature assembly (h0 reconstructed from quadrant sums) ----------------
__global__ __launch_bounds__(256) void k_feat(const float* __restrict__ p5,
                                              const float* __restrict__ hint,
                                              const float* __restrict__ hgrad,
                                              float* __restrict__ f) {
  const int b = blockIdx.x, tid = threadIdx.x;
  __shared__ float tmp4[4];
  __shared__ float vals[160];
  const float* ps = p5 + (size_t)b * 1024;
  float* fb = f + (size_t)b * 4096;
  float mv[4]; float ss = 0.f;
  #pragma unroll
  for (int i = 0; i < 4; ++i) { mv[i] = ps[tid + i * 256]; ss += mv[i] * mv[i]; }
  #pragma unroll
  for (int o = 32; o > 0; o >>= 1) ss += __shfl_down(ss, o, 64);
  if ((tid & 63) == 0) tmp4[tid >> 6] = ss;
  __syncthreads();
  const float inv = 1.f / (sqrtf(tmp4[0] + tmp4[1] + tmp4[2] + tmp4[3]) + 1e-7f);
  #pragma unroll
  for (int i = 0; i < 4; ++i) fb[tid + i * 256] = fmaxf(mv[i] * inv, 0.f);
  for (int ft = 0; ft < 2; ++ft) {
    const float* hb = (ft ? hgrad : hint) + (size_t)b * 160;
    __syncthreads();
    if (tid < 160) {
      float cnt;
      if (tid < 32) cnt = hb[32 + tid] + hb[64 + tid] + hb[96 + tid] + hb[128 + tid];
      else          cnt = hb[tid];
      vals[tid] = cnt * (tid < 32 ? (1.f / 200704.f) : (1.f / 50176.f));
    }
    __syncthreads();
    float s2 = 0.f;
    if (tid < 160) s2 = (tid < 32 ? 16.f : 4.f) * vals[tid] * vals[tid];
    #pragma unroll
    for (int o = 32; o > 0; o >>= 1) s2 += __shfl_down(s2, o, 64);
    __syncthreads();
    if ((tid & 63) == 0) tmp4[tid >> 6] = s2;
    __syncthreads();
    const float inv2 = 1.f / (sqrtf(tmp4[0] + tmp4[1] + tmp4[2] + tmp4[3]) + 1e-7f);
    float* fo = fb + 1024 + ft * 1536;
    for (int idx = tid; idx < 1536; idx += 256) {
      const int ch = idx >> 4, i2 = (idx >> 2) & 3, j = idx & 3;
      float v;
      if (ch < 32)      v = vals[ch];
      else if (ch < 64) v = vals[32 + (((i2 >> 1) * 2) + (j >> 1)) * 32 + (ch - 32)];
      else              v = 0.f;
      fo[idx] = fmaxf(v * inv2, 0.f);
    }
  }
}

// ---------------- fc1: one wave per (b,oc) ----------------
__global__ __launch_bounds__(256) void k_fc1(const float* __restrict__ f,
                                             const float* __restrict__ w,
                                             const float* __restrict__ bias,
                                             float* __restrict__ h1) {
  const int gid = blockIdx.x * 4 + (threadIdx.x >> 6);
  const int lane = threadIdx.x & 63;
  if (gid >= 64 * 256) return;
  const int oc = gid & 255, b = gid >> 8;
  const float* fb = f + (size_t)b * 4096;
  const float* wr = w + (size_t)oc * 4096;
  float s = 0.f;
  for (int k = lane; k < 4096; k += 64) s += fb[k] * wr[k];
  #pragma unroll
  for (int o = 32; o > 0; o >>= 1) s += __shfl_down(s, o, 64);
  if (lane == 0) h1[(size_t)b * 256 + oc] = fmaxf(s + bias[oc], 0.f);
}

// ---------------- fc2 ----------------
__global__ __launch_bounds__(256) void k_fc2_simple(const float* __restrict__ h1,
                                                    const float* __restrict__ w,
                                                    const float* __restrict__ bias,
                                                    float* __restrict__ out) {
  const int idx = blockIdx.x * 256 + threadIdx.x;
  if (idx >= 64 * 12) return;
  const int oc = idx % 12, b = idx / 12;
  const float* hb = h1 + (size_t)b * 256;
  const float* wr = w + (size_t)oc * 256;
  float s = bias[oc];
  for (int k = 0; k < 256; ++k) s += hb[k] * wr[k];
  out[b * 12 + oc] = s;
}

// ---------------- launch ----------------
extern "C" void kernel_launch(void* const* d_in, const int* in_sizes, int n_in,
                              void* d_out, int out_size, void* d_ws, size_t ws_size,
                              hipStream_t stream) {
  const float* img  = (const float*)d_in[0];
  const float* w1 = (const float*)d_in[1];  const float* b1 = (const float*)d_in[2];
  const float* w2 = (const float*)d_in[3];  const float* b2 = (const float*)d_in[4];
  const float* w3 = (const float*)d_in[5];  const float* b3 = (const float*)d_in[6];
  const float* w4 = (const float*)d_in[7];  const float* b4 = (const float*)d_in[8];
  const float* w5 = (const float*)d_in[9];  const float* b5 = (const float*)d_in[10];
  const float* fc1w = (const float*)d_in[11]; const float* fc1b = (const float*)d_in[12];
  const float* fc2w = (const float*)d_in[13]; const float* fc2b = (const float*)d_in[14];
  float* out = (float*)d_out;
  float* ws  = (float*)d_ws;

  float* hint = ws + OFF_HINT;
  float* hgrd = ws + OFF_HGRD;
  float* f    = ws + OFF_F;
  float* h1   = ws + OFF_H1;
  float* p5   = ws + OFF_P5;
  float* r2   = ws + OFF_R2;   // x0, p1, p2, a4 (time-multiplexed)
  float* r1   = ws + OFF_R1;   // a1, a2, a3, a5 (time-multiplexed)

  hipMemsetAsync(hint, 0, (size_t)2 * 64 * 160 * sizeof(float), stream);

  k_preproc<<<dim3(64, 28), 256, 0, stream>>>(img, hint, hgrd);
  k_resize <<<(64*112*112 + 255)/256, 256, 0, stream>>>(img, r2);          // x0 in r2

  // conv1: 3x112x112 (pad2, s4) -> 64x27x27
  k_conv_mfma<3,112,112,11,11,4,2,27,27,64>
      <<<dim3(729, 1), 256, 0, stream>>>(r2, w1, b1, r1);                  // a1 in r1
  k_pool<64,27,13><<<(64*64*13*13 + 255)/256, 256, 0, stream>>>(r1, r2);   // p1 in r2
  // conv2: 64x13x13 (pad2) -> 192x13x13
  k_conv_mfma<64,13,13,5,5,1,2,13,13,192>
      <<<dim3(169, 3), 256, 0, stream>>>(r2, w2, b2, r1);                  // a2 in r1
  k_pool<192,13,6><<<(64*192*6*6 + 255)/256, 256, 0, stream>>>(r1, r2);    // p2 in r2
  // conv3: 192x6x6 (pad1) -> 384x6x6
  k_conv_mfma<192,6,6,3,3,1,1,6,6,384>
      <<<dim3(36, 6), 256, 0, stream>>>(r2, w3, b3, r1);                   // a3 in r1
  // conv4: 384x6x6 (pad1) -> 256x6x6
  k_conv_mfma<384,6,6,3,3,1,1,6,6,256>
      <<<dim3(36, 4), 256, 0, stream>>>(r1, w4, b4, r2);                   // a4 in r2
  // conv5: 256x6x6 (pad1) -> 256x6x6
  k_conv_mfma<256,6,6,3,3,1,1,6,6,256>
      <<<dim3(36, 4), 256, 0, stream>>>(r2, w5, b5, r1);                   // a5 in r1
  k_pool<256,6,2><<<(64*256*2*2 + 255)/256, 256, 0, stream>>>(r1, p5);

  k_feat<<<64, 256, 0, stream>>>(p5, hint, hgrd, f);
  k_fc1<<<(64*256)/4, 256, 0, stream>>>(f, fc1w, fc1b, h1);
  k_fc2_simple<<<(64*12 + 255)/256, 256, 0, stream>>>(h1, fc2w, fc2b, out);
}

// Round 7
// 633.515 us; speedup vs baseline: 7.7071x; 1.1521x over previous
//
#include <hip/hip_runtime.h>
#include <math.h>

typedef __attribute__((ext_vector_type(8))) short short8;
typedef __attribute__((ext_vector_type(8))) unsigned short u16x8;
typedef __attribute__((ext_vector_type(4))) float f32x4;

// ---------------- workspace layout (floats), ~5.76M floats = 22 MB ----------------
constexpr size_t OFF_HINT = 0;                              // 64*160
constexpr size_t OFF_HGRD = OFF_HINT + (size_t)64*160;      // 64*160
constexpr size_t OFF_F    = OFF_HGRD + (size_t)64*160;      // 64*4096
constexpr size_t OFF_H1   = OFF_F    + (size_t)64*4096;     // 64*256
constexpr size_t OFF_P5   = OFF_H1   + (size_t)64*256;      // 64*256*2*2
constexpr size_t OFF_R2   = OFF_P5   + (size_t)64*1024;     // region2: x0 / p1 / p2 / a4
constexpr size_t SZ_R2    = (size_t)64*3*112*112;           // max of x0,p1,p2,a4
constexpr size_t OFF_R1   = OFF_R2 + SZ_R2;                 // region1: a1 / a2 / a3 / a5
constexpr size_t SZ_R1    = (size_t)64*64*27*27;            // max of a1,a2,a3,a5
constexpr size_t WS_FLOATS = OFF_R1 + SZ_R1;                // 5,758,976

// bf16 hi/lo split (RNE), branchless
__device__ __forceinline__ void bf16split(float v, unsigned short& hi, unsigned short& lo) {
  union { float f; unsigned u; } a; a.f = v;
  unsigned uh = (a.u + 0x7FFFu + ((a.u >> 16) & 1u)) >> 16;
  hi = (unsigned short)uh;
  union { unsigned u; float f; } b; b.u = uh << 16;
  float rem = v - b.f;
  union { float f; unsigned u; } c; c.f = rem;
  lo = (unsigned short)((c.u + 0x7FFFu + ((c.u >> 16) & 1u)) >> 16);
}

// match-any histogram insert: 7-bit key, leader lane adds popcount(equal-key mask).
// Every LDS atomic instruction ends up with pairwise-distinct addresses -> no RMW serialization.
__device__ __forceinline__ void hist_insert(float* __restrict__ h, unsigned key) {
  unsigned long long m = __ballot(1);                       // active-lane mask (exact for partial waves)
  #pragma unroll
  for (int b = 0; b < 7; ++b) {
    const unsigned long long bal = __ballot((key >> b) & 1u);
    m &= ((key >> b) & 1u) ? bal : ~bal;
  }
  const unsigned lane = __builtin_amdgcn_mbcnt_hi(~0u, __builtin_amdgcn_mbcnt_lo(~0u, 0u));
  if ((m & ((1ull << lane) - 1ull)) == 0ull)
    atomicAdd(&h[key], (float)__popcll(m));
}

// ---------------- fused preproc: gray strip -> intensity + sobel QUADRANT hists ----------------
// Whole-image hist = sum of quadrant hists (exact integer identity) -> reconstructed in k_feat.
__global__ __launch_bounds__(256) void k_preproc(const float* __restrict__ img,
                                                 float* __restrict__ hint,
                                                 float* __restrict__ hgrd) {
  const int b = blockIdx.x, s = blockIdx.y;   // 28 strips of 16 rows
  const int r0 = s * 16;
  __shared__ float gs[18][448];
  __shared__ float lhi_w[4][128], lhs_w[4][128];   // per-wave quad*32+bin
  const int tid = threadIdx.x, wv = tid >> 6;
  for (int i = tid; i < 4 * 128; i += 256) { ((float*)lhi_w)[i] = 0.f; ((float*)lhs_w)[i] = 0.f; }
  const float* ib = img + (size_t)b * 4 * 200704;
  // stage gray: float4 per channel, 4 pixels/thread-iter
  for (int i = tid; i < 18 * 112; i += 256) {
    const int rr = i / 112, c4 = (i % 112) * 4;
    int r = r0 + rr - 1; r = r < 0 ? 0 : (r > 447 ? 447 : r);
    const size_t o = (size_t)r * 448 + c4;
    const float4 vr = *(const float4*)&ib[o];
    const float4 g1 = *(const float4*)&ib[200704 + o];
    const float4 g2 = *(const float4*)&ib[2 * 200704 + o];
    const float4 vb = *(const float4*)&ib[3 * 200704 + o];
    float4 g;
    g.x = 0.299f * vr.x + 0.587f * (0.5f * (g1.x + g2.x)) + 0.114f * vb.x;
    g.y = 0.299f * vr.y + 0.587f * (0.5f * (g1.y + g2.y)) + 0.114f * vb.y;
    g.z = 0.299f * vr.z + 0.587f * (0.5f * (g1.z + g2.z)) + 0.114f * vb.z;
    g.w = 0.299f * vr.w + 0.587f * (0.5f * (g1.w + g2.w)) + 0.114f * vb.w;
    *(float4*)&gs[rr][c4] = g;
  }
  __syncthreads();
  // process 4 pixels/thread-iter (16*112/256 = 7 full iters, no divergence)
  for (int i = tid; i < 16 * 112; i += 256) {
    const int dr = i / 112, c4 = (i % 112) * 4;
    const int r = r0 + dr;
    const unsigned quad = ((r >= 224) ? 2u : 0u) + ((c4 >= 224) ? 1u : 0u);
    const int cl = c4 > 0 ? c4 - 1 : 0;
    const int cr = c4 < 444 ? c4 + 4 : 447;
    const float4 m0 = *(const float4*)&gs[dr][c4];
    const float4 m1 = *(const float4*)&gs[dr + 1][c4];
    const float4 m2 = *(const float4*)&gs[dr + 2][c4];
    const float r0v[6] = {gs[dr][cl],     m0.x, m0.y, m0.z, m0.w, gs[dr][cr]};
    const float r1v[6] = {gs[dr + 1][cl], m1.x, m1.y, m1.z, m1.w, gs[dr + 1][cr]};
    const float r2v[6] = {gs[dr + 2][cl], m2.x, m2.y, m2.z, m2.w, gs[dr + 2][cr]};
    float* hi = lhi_w[wv];
    float* hs = lhs_w[wv];
    #pragma unroll
    for (int j = 0; j < 4; ++j) {
      const float g = r1v[j + 1];
      int bin = (int)(g * 32.f); bin = bin > 31 ? 31 : (bin < 0 ? 0 : bin);
      hist_insert(hi, quad * 32u + (unsigned)bin);
      const float gx = (-r0v[j] + r0v[j + 2] - 2.f * r1v[j] + 2.f * r1v[j + 2]
                        - r2v[j] + r2v[j + 2]) * 0.125f;
      const float gy = (-r0v[j] - 2.f * r0v[j + 1] - r0v[j + 2]
                        + r2v[j] + 2.f * r2v[j + 1] + r2v[j + 2]) * 0.125f;
      const float mag = sqrtf(gx * gx + gy * gy + 1e-6f);
      int sb = (int)(mag * 32.f); sb = sb > 31 ? 31 : (sb < 0 ? 0 : sb);
      hist_insert(hs, quad * 32u + (unsigned)sb);
    }
  }
  __syncthreads();
  for (int idx = tid; idx < 128; idx += 256) {
    atomicAdd(&hint[(size_t)b * 160 + 32 + idx],
              lhi_w[0][idx] + lhi_w[1][idx] + lhi_w[2][idx] + lhi_w[3][idx]);
    atomicAdd(&hgrd[(size_t)b * 160 + 32 + idx],
              lhs_w[0][idx] + lhs_w[1][idx] + lhs_w[2][idx] + lhs_w[3][idx]);
  }
}

// ---------------- area resize 448->112, vectorized: 1 thread = 1 output pixel, 3 channels ----------------
__global__ __launch_bounds__(256) void k_resize(const float* __restrict__ img,
                                                float* __restrict__ x0) {
  const int idx = blockIdx.x * 256 + threadIdx.x;
  if (idx >= 64 * 112 * 112) return;
  const int cc = idx % 112;
  const int rr = (idx / 112) % 112;
  const int b  = idx / (112 * 112);
  const float* ib = img + (size_t)b * 4 * 200704;
  float sr = 0.f, sg = 0.f, sb = 0.f;
  #pragma unroll
  for (int i = 0; i < 4; ++i) {
    const size_t o = (size_t)(rr * 4 + i) * 448 + cc * 4;
    const float4 vr = *(const float4*)&ib[o];
    const float4 g1 = *(const float4*)&ib[200704 + o];
    const float4 g2 = *(const float4*)&ib[2 * 200704 + o];
    const float4 vb = *(const float4*)&ib[3 * 200704 + o];
    sr += vr.x + vr.y + vr.z + vr.w;
    sg += 0.5f * (g1.x + g2.x) + 0.5f * (g1.y + g2.y) + 0.5f * (g1.z + g2.z) + 0.5f * (g1.w + g2.w);
    sb += vb.x + vb.y + vb.z + vb.w;
  }
  float* xb = x0 + (size_t)b * 3 * 112 * 112 + (size_t)rr * 112 + cc;
  xb[0]              = sr * (1.f / 16.f);
  xb[112 * 112]      = sg * (1.f / 16.f);
  xb[2 * 112 * 112]  = sb * (1.f / 16.f);
}

// ---------------- conv as MFMA GEMM (bf16 hi/lo split) ----------------
template<int CIN, int HI, int WI, int KH, int KW, int STRIDE, int IPAD, int OH, int OW, int M>
__global__ __launch_bounds__(256) void k_conv_mfma(const float* __restrict__ in,
                                                   const float* __restrict__ w,
                                                   const float* __restrict__ bias,
                                                   float* __restrict__ out) {
  constexpr int K_TOT = CIN * KH * KW;
  constexpr int KHW   = KH * KW;
  constexpr int NPB   = OH * OW;
  constexpr int KSTEPS = (K_TOT + 63) / 64;
  __shared__ unsigned short Ahi[64 * 64], Alo[64 * 64];
  __shared__ unsigned short Bhi[64 * 64], Blo[64 * 64];
  const int tid  = threadIdx.x;
  const int lane = tid & 63, wv = tid >> 6;
  const int n0 = blockIdx.x * 64, m0 = blockIdx.y * 64;
  const int row_s = tid & 63, kc2 = tid >> 6;
  const float* gA = w + (size_t)(m0 + row_s) * K_TOT;
  const int nb  = n0 + row_s;
  const int bB  = nb / NPB;
  const int rB  = nb % NPB;
  const int oyB = rB / OW, oxB = rB % OW;
  const int rowb = oyB * STRIDE - IPAD;
  const int colb = oxB * STRIDE - IPAD;
  const float* inb = in + (size_t)bB * CIN * HI * WI;
  f32x4 acc[4] = {};
  const int rA = wv * 16 + (lane & 15);
  const int kg = lane >> 4;

  for (int step = 0; step < KSTEPS; ++step) {
    const int kbase = step * 64 + kc2 * 16;
    float va[16];
    if constexpr (K_TOT % 64 == 0) {
      const float4 v0 = *(const float4*)&gA[kbase + 0];
      const float4 v1 = *(const float4*)&gA[kbase + 4];
      const float4 v2 = *(const float4*)&gA[kbase + 8];
      const float4 v3 = *(const float4*)&gA[kbase + 12];
      va[0]=v0.x; va[1]=v0.y; va[2]=v0.z; va[3]=v0.w;
      va[4]=v1.x; va[5]=v1.y; va[6]=v1.z; va[7]=v1.w;
      va[8]=v2.x; va[9]=v2.y; va[10]=v2.z; va[11]=v2.w;
      va[12]=v3.x; va[13]=v3.y; va[14]=v3.z; va[15]=v3.w;
    } else {
      #pragma unroll
      for (int j = 0; j < 16; ++j) {
        const int k = kbase + j;
        va[j] = (k < K_TOT) ? gA[k] : 0.f;
      }
    }
    u16x8 ah0, al0, ah1, al1;
    #pragma unroll
    for (int j = 0; j < 8; ++j) {
      unsigned short h, l;
      bf16split(va[j], h, l);     ah0[j] = h; al0[j] = l;
      bf16split(va[8 + j], h, l); ah1[j] = h; al1[j] = l;
    }
    {
      const int c0 = kc2 * 2, c1 = c0 + 1, r = row_s;
      *(u16x8*)&Ahi[r * 64 + ((c0 ^ (r & 7)) * 8)] = ah0;
      *(u16x8*)&Ahi[r * 64 + ((c1 ^ (r & 7)) * 8)] = ah1;
      *(u16x8*)&Alo[r * 64 + ((c0 ^ (r & 7)) * 8)] = al0;
      *(u16x8*)&Alo[r * 64 + ((c1 ^ (r & 7)) * 8)] = al1;
    }
    float vb[16];
    #pragma unroll
    for (int j = 0; j < 16; ++j) {
      const int k = kbase + j;
      float v = 0.f;
      if (k < K_TOT) {
        const int c  = k / KHW;
        const int kr = k - c * KHW;
        const int ky = kr / KW, kx = kr - (kr / KW) * KW;
        const int r  = rowb + ky, cc = colb + kx;
        if (r >= 0 && r < HI && cc >= 0 && cc < WI)
          v = inb[((size_t)c * HI + r) * WI + cc];
      }
      vb[j] = v;
    }
    u16x8 bh0, bl0, bh1, bl1;
    #pragma unroll
    for (int j = 0; j < 8; ++j) {
      unsigned short h, l;
      bf16split(vb[j], h, l);     bh0[j] = h; bl0[j] = l;
      bf16split(vb[8 + j], h, l); bh1[j] = h; bl1[j] = l;
    }
    {
      const int c0 = kc2 * 2, c1 = c0 + 1, r = row_s;
      *(u16x8*)&Bhi[r * 64 + ((c0 ^ (r & 7)) * 8)] = bh0;
      *(u16x8*)&Bhi[r * 64 + ((c1 ^ (r & 7)) * 8)] = bh1;
      *(u16x8*)&Blo[r * 64 + ((c0 ^ (r & 7)) * 8)] = bl0;
      *(u16x8*)&Blo[r * 64 + ((c1 ^ (r & 7)) * 8)] = bl1;
    }
    __syncthreads();
    #pragma unroll
    for (int s = 0; s < 2; ++s) {
      const int cA = s * 4 + kg;
      const short8 a_h = *(const short8*)&Ahi[rA * 64 + ((cA ^ (rA & 7)) * 8)];
      const short8 a_l = *(const short8*)&Alo[rA * 64 + ((cA ^ (rA & 7)) * 8)];
      #pragma unroll
      for (int t = 0; t < 4; ++t) {
        const int col = t * 16 + (lane & 15);
        const short8 b_h = *(const short8*)&Bhi[col * 64 + ((cA ^ (col & 7)) * 8)];
        const short8 b_l = *(const short8*)&Blo[col * 64 + ((cA ^ (col & 7)) * 8)];
        acc[t] = __builtin_amdgcn_mfma_f32_16x16x32_bf16(a_h, b_h, acc[t], 0, 0, 0);
        acc[t] = __builtin_amdgcn_mfma_f32_16x16x32_bf16(a_h, b_l, acc[t], 0, 0, 0);
        acc[t] = __builtin_amdgcn_mfma_f32_16x16x32_bf16(a_l, b_h, acc[t], 0, 0, 0);
      }
    }
    __syncthreads();
  }
  #pragma unroll
  for (int q = 0; q < 4; ++q) {
    const int m = m0 + wv * 16 + (lane >> 4) * 4 + q;
    const float bi = bias[m];
    #pragma unroll
    for (int t = 0; t < 4; ++t) {
      const int n = n0 + t * 16 + (lane & 15);
      const int b = n / NPB;
      const int r = n % NPB;
      out[((size_t)b * M + m) * NPB + r] = fmaxf(acc[t][q] + bi, 0.f);
    }
  }
}

// ---------------- maxpool 3x3 stride 2, unpadded ----------------
template<int C, int HI, int HO>
__global__ __launch_bounds__(256) void k_pool(const float* __restrict__ in,
                                              float* __restrict__ out) {
  const int idx = blockIdx.x * 256 + threadIdx.x;
  constexpr int TOT = 64 * C * HO * HO;
  if (idx >= TOT) return;
  const int x = idx % HO;
  const int y = (idx / HO) % HO;
  const int c = (idx / (HO * HO)) % C;
  const int b = idx / (HO * HO * C);
  const float* ib = in + (size_t)(b * C + c) * HI * HI + (size_t)(y * 2) * HI + x * 2;
  float v = -INFINITY;
  #pragma unroll
  for (int i = 0; i < 3; ++i)
    #pragma unroll
    for (int j = 0; j < 3; ++j)
      v = fmaxf(v, ib[i * HI + j]);
  out[idx] = v;
}

// ---------------- feature assembly (h0 reconstructed from quadrant sums) ----------------
__global__ __launch_bounds__(256) void k_feat(const float* __restrict__ p5,
                                              const float* __restrict__ hint,
                                              const float* __restrict__ hgrad,
                                              float* __restrict__ f) {
  const int b = blockIdx.x, tid = threadIdx.x;
  __shared__ float tmp4[4];
  __shared__ float vals[160];
  const float* ps = p5 + (size_t)b * 1024;
  float* fb = f + (size_t)b * 4096;
  float mv[4]; float ss = 0.f;
  #pragma unroll
  for (int i = 0; i < 4; ++i) { mv[i] = ps[tid + i * 256]; ss += mv[i] * mv[i]; }
  #pragma unroll
  for (int o = 32; o > 0; o >>= 1) ss += __shfl_down(ss, o, 64);
  if ((tid & 63) == 0) tmp4[tid >> 6] = ss;
  __syncthreads();
  const float inv = 1.f / (sqrtf(tmp4[0] + tmp4[1] + tmp4[2] + tmp4[3]) + 1e-7f);
  #pragma unroll
  for (int i = 0; i < 4; ++i) fb[tid + i * 256] = fmaxf(mv[i] * inv, 0.f);
  for (int ft = 0; ft < 2; ++ft) {
    const float* hb = (ft ? hgrad : hint) + (size_t)b * 160;
    __syncthreads();
    if (tid < 160) {
      float cnt;
      if (tid < 32) cnt = hb[32 + tid] + hb[64 + tid] + hb[96 + tid] + hb[128 + tid];
      else          cnt = hb[tid];
      vals[tid] = cnt * (tid < 32 ? (1.f / 200704.f) : (1.f / 50176.f));
    }
    __syncthreads();
    float s2 = 0.f;
    if (tid < 160) s2 = (tid < 32 ? 16.f : 4.f) * vals[tid] * vals[tid];
    #pragma unroll
    for (int o = 32; o > 0; o >>= 1) s2 += __shfl_down(s2, o, 64);
    __syncthreads();
    if ((tid & 63) == 0) tmp4[tid >> 6] = s2;
    __syncthreads();
    const float inv2 = 1.f / (sqrtf(tmp4[0] + tmp4[1] + tmp4[2] + tmp4[3]) + 1e-7f);
    float* fo = fb + 1024 + ft * 1536;
    for (int idx = tid; idx < 1536; idx += 256) {
      const int ch = idx >> 4, i2 = (idx >> 2) & 3, j = idx & 3;
      float v;
      if (ch < 32)      v = vals[ch];
      else if (ch < 64) v = vals[32 + (((i2 >> 1) * 2) + (j >> 1)) * 32 + (ch - 32)];
      else              v = 0.f;
      fo[idx] = fmaxf(v * inv2, 0.f);
    }
  }
}

// ---------------- fc1: one wave per (b,oc) ----------------
__global__ __launch_bounds__(256) void k_fc1(const float* __restrict__ f,
                                             const float* __restrict__ w,
                                             const float* __restrict__ bias,
                                             float* __restrict__ h1) {
  const int gid = blockIdx.x * 4 + (threadIdx.x >> 6);
  const int lane = threadIdx.x & 63;
  if (gid >= 64 * 256) return;
  const int oc = gid & 255, b = gid >> 8;
  const float* fb = f + (size_t)b * 4096;
  const float* wr = w + (size_t)oc * 4096;
  float s = 0.f;
  for (int k = lane; k < 4096; k += 64) s += fb[k] * wr[k];
  #pragma unroll
  for (int o = 32; o > 0; o >>= 1) s += __shfl_down(s, o, 64);
  if (lane == 0) h1[(size_t)b * 256 + oc] = fmaxf(s + bias[oc], 0.f);
}

// ---------------- fc2 ----------------
__global__ __launch_bounds__(256) void k_fc2_simple(const float* __restrict__ h1,
                                                    const float* __restrict__ w,
                                                    const float* __restrict__ bias,
                                                    float* __restrict__ out) {
  const int idx = blockIdx.x * 256 + threadIdx.x;
  if (idx >= 64 * 12) return;
  const int oc = idx % 12, b = idx / 12;
  const float* hb = h1 + (size_t)b * 256;
  const float* wr = w + (size_t)oc * 256;
  float s = bias[oc];
  for (int k = 0; k < 256; ++k) s += hb[k] * wr[k];
  out[b * 12 + oc] = s;
}

// ---------------- launch ----------------
extern "C" void kernel_launch(void* const* d_in, const int* in_sizes, int n_in,
                              void* d_out, int out_size, void* d_ws, size_t ws_size,
                              hipStream_t stream) {
  const float* img  = (const float*)d_in[0];
  const float* w1 = (const float*)d_in[1];  const float* b1 = (const float*)d_in[2];
  const float* w2 = (const float*)d_in[3];  const float* b2 = (const float*)d_in[4];
  const float* w3 = (const float*)d_in[5];  const float* b3 = (const float*)d_in[6];
  const float* w4 = (const float*)d_in[7];  const float* b4 = (const float*)d_in[8];
  const float* w5 = (const float*)d_in[9];  const float* b5 = (const float*)d_in[10];
  const float* fc1w = (const float*)d_in[11]; const float* fc1b = (const float*)d_in[12];
  const float* fc2w = (const float*)d_in[13]; const float* fc2b = (const float*)d_in[14];
  float* out = (float*)d_out;
  float* ws  = (float*)d_ws;

  float* hint = ws + OFF_HINT;
  float* hgrd = ws + OFF_HGRD;
  float* f    = ws + OFF_F;
  float* h1   = ws + OFF_H1;
  float* p5   = ws + OFF_P5;
  float* r2   = ws + OFF_R2;   // x0, p1, p2, a4 (time-multiplexed)
  float* r1   = ws + OFF_R1;   // a1, a2, a3, a5 (time-multiplexed)

  hipMemsetAsync(hint, 0, (size_t)2 * 64 * 160 * sizeof(float), stream);

  k_preproc<<<dim3(64, 28), 256, 0, stream>>>(img, hint, hgrd);
  k_resize <<<(64*112*112 + 255)/256, 256, 0, stream>>>(img, r2);          // x0 in r2

  // conv1: 3x112x112 (pad2, s4) -> 64x27x27
  k_conv_mfma<3,112,112,11,11,4,2,27,27,64>
      <<<dim3(729, 1), 256, 0, stream>>>(r2, w1, b1, r1);                  // a1 in r1
  k_pool<64,27,13><<<(64*64*13*13 + 255)/256, 256, 0, stream>>>(r1, r2);   // p1 in r2
  // conv2: 64x13x13 (pad2) -> 192x13x13
  k_conv_mfma<64,13,13,5,5,1,2,13,13,192>
      <<<dim3(169, 3), 256, 0, stream>>>(r2, w2, b2, r1);                  // a2 in r1
  k_pool<192,13,6><<<(64*192*6*6 + 255)/256, 256, 0, stream>>>(r1, r2);    // p2 in r2
  // conv3: 192x6x6 (pad1) -> 384x6x6
  k_conv_mfma<192,6,6,3,3,1,1,6,6,384>
      <<<dim3(36, 6), 256, 0, stream>>>(r2, w3, b3, r1);                   // a3 in r1
  // conv4: 384x6x6 (pad1) -> 256x6x6
  k_conv_mfma<384,6,6,3,3,1,1,6,6,256>
      <<<dim3(36, 4), 256, 0, stream>>>(r1, w4, b4, r2);                   // a4 in r2
  // conv5: 256x6x6 (pad1) -> 256x6x6
  k_conv_mfma<256,6,6,3,3,1,1,6,6,256>
      <<<dim3(36, 4), 256, 0, stream>>>(r2, w5, b5, r1);                   // a5 in r1
  k_pool<256,6,2><<<(64*256*2*2 + 255)/256, 256, 0, stream>>>(r1, p5);

  k_feat<<<64, 256, 0, stream>>>(p5, hint, hgrd, f);
  k_fc1<<<(64*256)/4, 256, 0, stream>>>(f, fc1w, fc1b, h1);
  k_fc2_simple<<<(64*12 + 255)/256, 256, 0, stream>>>(h1, fc2w, fc2b, out);
}

// Round 8
// 565.610 us; speedup vs baseline: 8.6324x; 1.1201x over previous
//
#include <hip/hip_runtime.h>
#include <math.h>

typedef __attribute__((ext_vector_type(8))) short short8;
typedef __attribute__((ext_vector_type(8))) unsigned short u16x8;
typedef __attribute__((ext_vector_type(4))) float f32x4;
typedef unsigned short ushort_t;

// ---------------- workspace layout (float-slots, 22.1 MB total) ----------------
constexpr size_t OFF_HINT = 0;                               // 64*160 f32
constexpr size_t OFF_HGRD = OFF_HINT + (size_t)64*160;       // 64*160 f32
constexpr size_t OFF_F    = OFF_HGRD + (size_t)64*160;       // 64*4096 f32
constexpr size_t OFF_H1   = OFF_F    + (size_t)64*4096;      // 64*256 f32
constexpr size_t OFF_P5   = OFF_H1   + (size_t)64*256;       // 64*1024 f32
constexpr size_t OFF_WP   = OFF_P5   + (size_t)64*1024;      // packed u32 weights, 2,468,544
constexpr size_t W1_OFF = 0;          constexpr size_t W1_N = 64*363;     // 23232
constexpr size_t W2_OFF = 23232;      constexpr size_t W2_N = 192*1600;   // 307200
constexpr size_t W3_OFF = 330432;     constexpr size_t W3_N = 384*1728;   // 663552
constexpr size_t W4_OFF = 993984;     constexpr size_t W4_N = 256*3456;   // 884736
constexpr size_t W5_OFF = 1878720;    constexpr size_t W5_N = 256*2304;   // 589824
constexpr size_t WP_TOT = 2468544;
constexpr size_t OFF_RA = OFF_WP + WP_TOT;                   // bf16 region A: 2,408,448 ushorts
constexpr size_t SZ_RA  = (size_t)2408448/2;                 // in float-slots
constexpr size_t OFF_RB = OFF_RA + SZ_RA;                    // bf16 region B: 2,985,984 ushorts
constexpr size_t SZ_RB  = (size_t)2985984/2;
constexpr size_t WS_FLOATS = OFF_RB + SZ_RB;                 // 5,530,304 = 22.1 MB

// bf16 hi/lo split (RNE), branchless
__device__ __forceinline__ void bf16split(float v, unsigned short& hi, unsigned short& lo) {
  union { float f; unsigned u; } a; a.f = v;
  unsigned uh = (a.u + 0x7FFFu + ((a.u >> 16) & 1u)) >> 16;
  hi = (unsigned short)uh;
  union { unsigned u; float f; } b; b.u = uh << 16;
  float rem = v - b.f;
  union { float f; unsigned u; } c; c.f = rem;
  lo = (unsigned short)((c.u + 0x7FFFu + ((c.u >> 16) & 1u)) >> 16);
}
__device__ __forceinline__ ushort_t f2bf(float f) {
  union { float f; unsigned u; } a; a.f = f;
  return (ushort_t)((a.u + 0x7FFFu + ((a.u >> 16) & 1u)) >> 16);
}
__device__ __forceinline__ float bf2f(ushort_t u) {
  union { unsigned u; float f; } a; a.u = ((unsigned)u) << 16; return a.f;
}

// ---------------- weight pre-split: fp32 -> packed (hi<<16)|lo ----------------
__global__ __launch_bounds__(256) void k_wsplit(const float* __restrict__ w,
                                                unsigned* __restrict__ out, int n) {
  const int idx = blockIdx.x * 256 + threadIdx.x;
  if (idx >= n) return;
  unsigned short h, l;
  bf16split(w[idx], h, l);
  out[idx] = ((unsigned)h << 16) | (unsigned)l;
}

// match-any histogram insert: leader lane adds popcount(equal-key mask).
__device__ __forceinline__ void hist_insert(float* __restrict__ h, unsigned key) {
  unsigned long long m = __ballot(1);
  #pragma unroll
  for (int b = 0; b < 7; ++b) {
    const unsigned long long bal = __ballot((key >> b) & 1u);
    m &= ((key >> b) & 1u) ? bal : ~bal;
  }
  const unsigned lane = __builtin_amdgcn_mbcnt_hi(~0u, __builtin_amdgcn_mbcnt_lo(~0u, 0u));
  if ((m & ((1ull << lane) - 1ull)) == 0ull)
    atomicAdd(&h[key], (float)__popcll(m));
}

// ---------------- fused preproc: gray strip -> intensity + sobel QUADRANT hists ----------------
__global__ __launch_bounds__(256) void k_preproc(const float* __restrict__ img,
                                                 float* __restrict__ hint,
                                                 float* __restrict__ hgrd) {
  const int b = blockIdx.x, s = blockIdx.y;
  const int r0 = s * 16;
  __shared__ float gs[18][448];
  __shared__ float lhi_w[4][128], lhs_w[4][128];
  const int tid = threadIdx.x, wv = tid >> 6;
  for (int i = tid; i < 4 * 128; i += 256) { ((float*)lhi_w)[i] = 0.f; ((float*)lhs_w)[i] = 0.f; }
  const float* ib = img + (size_t)b * 4 * 200704;
  for (int i = tid; i < 18 * 112; i += 256) {
    const int rr = i / 112, c4 = (i % 112) * 4;
    int r = r0 + rr - 1; r = r < 0 ? 0 : (r > 447 ? 447 : r);
    const size_t o = (size_t)r * 448 + c4;
    const float4 vr = *(const float4*)&ib[o];
    const float4 g1 = *(const float4*)&ib[200704 + o];
    const float4 g2 = *(const float4*)&ib[2 * 200704 + o];
    const float4 vb = *(const float4*)&ib[3 * 200704 + o];
    float4 g;
    g.x = 0.299f * vr.x + 0.587f * (0.5f * (g1.x + g2.x)) + 0.114f * vb.x;
    g.y = 0.299f * vr.y + 0.587f * (0.5f * (g1.y + g2.y)) + 0.114f * vb.y;
    g.z = 0.299f * vr.z + 0.587f * (0.5f * (g1.z + g2.z)) + 0.114f * vb.z;
    g.w = 0.299f * vr.w + 0.587f * (0.5f * (g1.w + g2.w)) + 0.114f * vb.w;
    *(float4*)&gs[rr][c4] = g;
  }
  __syncthreads();
  for (int i = tid; i < 16 * 112; i += 256) {
    const int dr = i / 112, c4 = (i % 112) * 4;
    const int r = r0 + dr;
    const unsigned quad = ((r >= 224) ? 2u : 0u) + ((c4 >= 224) ? 1u : 0u);
    const int cl = c4 > 0 ? c4 - 1 : 0;
    const int cr = c4 < 444 ? c4 + 4 : 447;
    const float4 m0 = *(const float4*)&gs[dr][c4];
    const float4 m1 = *(const float4*)&gs[dr + 1][c4];
    const float4 m2 = *(const float4*)&gs[dr + 2][c4];
    const float r0v[6] = {gs[dr][cl],     m0.x, m0.y, m0.z, m0.w, gs[dr][cr]};
    const float r1v[6] = {gs[dr + 1][cl], m1.x, m1.y, m1.z, m1.w, gs[dr + 1][cr]};
    const float r2v[6] = {gs[dr + 2][cl], m2.x, m2.y, m2.z, m2.w, gs[dr + 2][cr]};
    float* hi = lhi_w[wv];
    float* hs = lhs_w[wv];
    #pragma unroll
    for (int j = 0; j < 4; ++j) {
      const float g = r1v[j + 1];
      int bin = (int)(g * 32.f); bin = bin > 31 ? 31 : (bin < 0 ? 0 : bin);
      hist_insert(hi, quad * 32u + (unsigned)bin);
      const float gx = (-r0v[j] + r0v[j + 2] - 2.f * r1v[j] + 2.f * r1v[j + 2]
                        - r2v[j] + r2v[j + 2]) * 0.125f;
      const float gy = (-r0v[j] - 2.f * r0v[j + 1] - r0v[j + 2]
                        + r2v[j] + 2.f * r2v[j + 1] + r2v[j + 2]) * 0.125f;
      const float mag = sqrtf(gx * gx + gy * gy + 1e-6f);
      int sb = (int)(mag * 32.f); sb = sb > 31 ? 31 : (sb < 0 ? 0 : sb);
      hist_insert(hs, quad * 32u + (unsigned)sb);
    }
  }
  __syncthreads();
  for (int idx = tid; idx < 128; idx += 256) {
    atomicAdd(&hint[(size_t)b * 160 + 32 + idx],
              lhi_w[0][idx] + lhi_w[1][idx] + lhi_w[2][idx] + lhi_w[3][idx]);
    atomicAdd(&hgrd[(size_t)b * 160 + 32 + idx],
              lhs_w[0][idx] + lhs_w[1][idx] + lhs_w[2][idx] + lhs_w[3][idx]);
  }
}

// ---------------- area resize 448->112 -> bf16 ----------------
__global__ __launch_bounds__(256) void k_resize(const float* __restrict__ img,
                                                ushort_t* __restrict__ x0) {
  const int idx = blockIdx.x * 256 + threadIdx.x;
  if (idx >= 64 * 112 * 112) return;
  const int cc = idx % 112;
  const int rr = (idx / 112) % 112;
  const int b  = idx / (112 * 112);
  const float* ib = img + (size_t)b * 4 * 200704;
  float sr = 0.f, sg = 0.f, sb = 0.f;
  #pragma unroll
  for (int i = 0; i < 4; ++i) {
    const size_t o = (size_t)(rr * 4 + i) * 448 + cc * 4;
    const float4 vr = *(const float4*)&ib[o];
    const float4 g1 = *(const float4*)&ib[200704 + o];
    const float4 g2 = *(const float4*)&ib[2 * 200704 + o];
    const float4 vb = *(const float4*)&ib[3 * 200704 + o];
    sr += vr.x + vr.y + vr.z + vr.w;
    sg += 0.5f * (g1.x + g2.x) + 0.5f * (g1.y + g2.y) + 0.5f * (g1.z + g2.z) + 0.5f * (g1.w + g2.w);
    sb += vb.x + vb.y + vb.z + vb.w;
  }
  ushort_t* xb = x0 + (size_t)b * 3 * 112 * 112 + (size_t)rr * 112 + cc;
  xb[0]             = f2bf(sr * (1.f / 16.f));
  xb[112 * 112]     = f2bf(sg * (1.f / 16.f));
  xb[2 * 112 * 112] = f2bf(sb * (1.f / 16.f));
}

// ---------------- conv as MFMA GEMM: A = packed hi/lo weights, B = bf16 activations ----------------
template<int CIN, int HI, int WI, int KH, int KW, int STRIDE, int IPAD, int OH, int OW, int M>
__global__ __launch_bounds__(256) void k_conv_mfma(const ushort_t* __restrict__ in,
                                                   const unsigned* __restrict__ wp,
                                                   const float* __restrict__ bias,
                                                   ushort_t* __restrict__ out) {
  constexpr int K_TOT = CIN * KH * KW;
  constexpr int KHW   = KH * KW;
  constexpr int NPB   = OH * OW;
  constexpr int KSTEPS = (K_TOT + 63) / 64;
  __shared__ ushort_t Ahi[64 * 64], Alo[64 * 64], Bs[64 * 64];
  const int tid  = threadIdx.x;
  const int lane = tid & 63, wv = tid >> 6;
  const int n0 = blockIdx.x * 64, m0 = blockIdx.y * 64;
  const int row_s = tid & 63, kc2 = tid >> 6;
  const unsigned* gA = wp + (size_t)(m0 + row_s) * K_TOT;
  const int nb  = n0 + row_s;
  const int bB  = nb / NPB;
  const int rB  = nb % NPB;
  const int oyB = rB / OW, oxB = rB % OW;
  const int rowb = oyB * STRIDE - IPAD;
  const int colb = oxB * STRIDE - IPAD;
  const ushort_t* inb = in + (size_t)bB * CIN * HI * WI;
  f32x4 acc[4] = {};
  const int rA = wv * 16 + (lane & 15);
  const int kg = lane >> 4;

  for (int step = 0; step < KSTEPS; ++step) {
    const int kbase = step * 64 + kc2 * 16;
    // ---- stage A: 16 packed u32 -> hi/lo ----
    unsigned pa[16];
    if constexpr (K_TOT % 64 == 0) {
      const uint4 p0 = *(const uint4*)&gA[kbase + 0];
      const uint4 p1 = *(const uint4*)&gA[kbase + 4];
      const uint4 p2 = *(const uint4*)&gA[kbase + 8];
      const uint4 p3 = *(const uint4*)&gA[kbase + 12];
      pa[0]=p0.x; pa[1]=p0.y; pa[2]=p0.z; pa[3]=p0.w;
      pa[4]=p1.x; pa[5]=p1.y; pa[6]=p1.z; pa[7]=p1.w;
      pa[8]=p2.x; pa[9]=p2.y; pa[10]=p2.z; pa[11]=p2.w;
      pa[12]=p3.x; pa[13]=p3.y; pa[14]=p3.z; pa[15]=p3.w;
    } else {
      #pragma unroll
      for (int j = 0; j < 16; ++j) {
        const int k = kbase + j;
        pa[j] = (k < K_TOT) ? gA[k] : 0u;
      }
    }
    u16x8 h0, l0, h1, l1;
    #pragma unroll
    for (int j = 0; j < 8; ++j) {
      h0[j] = (ushort_t)(pa[j] >> 16);     l0[j] = (ushort_t)(pa[j] & 0xFFFFu);
      h1[j] = (ushort_t)(pa[8 + j] >> 16); l1[j] = (ushort_t)(pa[8 + j] & 0xFFFFu);
    }
    {
      const int c0 = kc2 * 2, c1 = c0 + 1, r = row_s;
      *(u16x8*)&Ahi[r * 64 + ((c0 ^ (r & 7)) * 8)] = h0;
      *(u16x8*)&Ahi[r * 64 + ((c1 ^ (r & 7)) * 8)] = h1;
      *(u16x8*)&Alo[r * 64 + ((c0 ^ (r & 7)) * 8)] = l0;
      *(u16x8*)&Alo[r * 64 + ((c1 ^ (r & 7)) * 8)] = l1;
    }
    // ---- stage B: implicit im2col, bf16 direct ----
    u16x8 b0, b1;
    #pragma unroll
    for (int j = 0; j < 16; ++j) {
      const int k = kbase + j;
      ushort_t v = 0;
      if (k < K_TOT) {
        const int c  = k / KHW;
        const int kr = k - c * KHW;
        const int ky = kr / KW, kx = kr - (kr / KW) * KW;
        const int r  = rowb + ky, cc = colb + kx;
        if (r >= 0 && r < HI && cc >= 0 && cc < WI)
          v = inb[((size_t)c * HI + r) * WI + cc];
      }
      if (j < 8) b0[j] = v; else b1[j - 8] = v;
    }
    {
      const int c0 = kc2 * 2, c1 = c0 + 1, r = row_s;
      *(u16x8*)&Bs[r * 64 + ((c0 ^ (r & 7)) * 8)] = b0;
      *(u16x8*)&Bs[r * 64 + ((c1 ^ (r & 7)) * 8)] = b1;
    }
    __syncthreads();
    #pragma unroll
    for (int s = 0; s < 2; ++s) {
      const int cA = s * 4 + kg;
      const short8 a_h = *(const short8*)&Ahi[rA * 64 + ((cA ^ (rA & 7)) * 8)];
      const short8 a_l = *(const short8*)&Alo[rA * 64 + ((cA ^ (rA & 7)) * 8)];
      #pragma unroll
      for (int t = 0; t < 4; ++t) {
        const int col = t * 16 + (lane & 15);
        const short8 b_v = *(const short8*)&Bs[col * 64 + ((cA ^ (col & 7)) * 8)];
        acc[t] = __builtin_amdgcn_mfma_f32_16x16x32_bf16(a_h, b_v, acc[t], 0, 0, 0);
        acc[t] = __builtin_amdgcn_mfma_f32_16x16x32_bf16(a_l, b_v, acc[t], 0, 0, 0);
      }
    }
    __syncthreads();
  }
  #pragma unroll
  for (int q = 0; q < 4; ++q) {
    const int m = m0 + wv * 16 + (lane >> 4) * 4 + q;
    const float bi = bias[m];
    #pragma unroll
    for (int t = 0; t < 4; ++t) {
      const int n = n0 + t * 16 + (lane & 15);
      const int b = n / NPB;
      const int r = n % NPB;
      out[((size_t)b * M + m) * NPB + r] = f2bf(fmaxf(acc[t][q] + bi, 0.f));
    }
  }
}

// ---------------- maxpool 3x3 s2 on bf16 bits (values >= 0 -> integer max valid) ----------------
template<int C, int HI, int HO, bool OUTF32>
__global__ __launch_bounds__(256) void k_pool(const ushort_t* __restrict__ in,
                                              void* __restrict__ out) {
  const int idx = blockIdx.x * 256 + threadIdx.x;
  constexpr int TOT = 64 * C * HO * HO;
  if (idx >= TOT) return;
  const int x = idx % HO;
  const int y = (idx / HO) % HO;
  const int c = (idx / (HO * HO)) % C;
  const int b = idx / (HO * HO * C);
  const ushort_t* ib = in + (size_t)(b * C + c) * HI * HI + (size_t)(y * 2) * HI + x * 2;
  ushort_t v = 0;
  #pragma unroll
  for (int i = 0; i < 3; ++i)
    #pragma unroll
    for (int j = 0; j < 3; ++j) {
      const ushort_t u = ib[i * HI + j];
      v = u > v ? u : v;
    }
  if constexpr (OUTF32) ((float*)out)[idx] = bf2f(v);
  else                  ((ushort_t*)out)[idx] = v;
}

// ---------------- feature assembly (h0 reconstructed from quadrant sums) ----------------
__global__ __launch_bounds__(256) void k_feat(const float* __restrict__ p5,
                                              const float* __restrict__ hint,
                                              const float* __restrict__ hgrad,
                                              float* __restrict__ f) {
  const int b = blockIdx.x, tid = threadIdx.x;
  __shared__ float tmp4[4];
  __shared__ float vals[160];
  const float* ps = p5 + (size_t)b * 1024;
  float* fb = f + (size_t)b * 4096;
  float mv[4]; float ss = 0.f;
  #pragma unroll
  for (int i = 0; i < 4; ++i) { mv[i] = ps[tid + i * 256]; ss += mv[i] * mv[i]; }
  #pragma unroll
  for (int o = 32; o > 0; o >>= 1) ss += __shfl_down(ss, o, 64);
  if ((tid & 63) == 0) tmp4[tid >> 6] = ss;
  __syncthreads();
  const float inv = 1.f / (sqrtf(tmp4[0] + tmp4[1] + tmp4[2] + tmp4[3]) + 1e-7f);
  #pragma unroll
  for (int i = 0; i < 4; ++i) fb[tid + i * 256] = fmaxf(mv[i] * inv, 0.f);
  for (int ft = 0; ft < 2; ++ft) {
    const float* hb = (ft ? hgrad : hint) + (size_t)b * 160;
    __syncthreads();
    if (tid < 160) {
      float cnt;
      if (tid < 32) cnt = hb[32 + tid] + hb[64 + tid] + hb[96 + tid] + hb[128 + tid];
      else          cnt = hb[tid];
      vals[tid] = cnt * (tid < 32 ? (1.f / 200704.f) : (1.f / 50176.f));
    }
    __syncthreads();
    float s2 = 0.f;
    if (tid < 160) s2 = (tid < 32 ? 16.f : 4.f) * vals[tid] * vals[tid];
    #pragma unroll
    for (int o = 32; o > 0; o >>= 1) s2 += __shfl_down(s2, o, 64);
    __syncthreads();
    if ((tid & 63) == 0) tmp4[tid >> 6] = s2;
    __syncthreads();
    const float inv2 = 1.f / (sqrtf(tmp4[0] + tmp4[1] + tmp4[2] + tmp4[3]) + 1e-7f);
    float* fo = fb + 1024 + ft * 1536;
    for (int idx = tid; idx < 1536; idx += 256) {
      const int ch = idx >> 4, i2 = (idx >> 2) & 3, j = idx & 3;
      float v;
      if (ch < 32)      v = vals[ch];
      else if (ch < 64) v = vals[32 + (((i2 >> 1) * 2) + (j >> 1)) * 32 + (ch - 32)];
      else              v = 0.f;
      fo[idx] = fmaxf(v * inv2, 0.f);
    }
  }
}

// ---------------- fc1: one wave per (b,oc) ----------------
__global__ __launch_bounds__(256) void k_fc1(const float* __restrict__ f,
                                             const float* __restrict__ w,
                                             const float* __restrict__ bias,
                                             float* __restrict__ h1) {
  const int gid = blockIdx.x * 4 + (threadIdx.x >> 6);
  const int lane = threadIdx.x & 63;
  if (gid >= 64 * 256) return;
  const int oc = gid & 255, b = gid >> 8;
  const float* fb = f + (size_t)b * 4096;
  const float* wr = w + (size_t)oc * 4096;
  float s = 0.f;
  for (int k = lane; k < 4096; k += 64) s += fb[k] * wr[k];
  #pragma unroll
  for (int o = 32; o > 0; o >>= 1) s += __shfl_down(s, o, 64);
  if (lane == 0) h1[(size_t)b * 256 + oc] = fmaxf(s + bias[oc], 0.f);
}

// ---------------- fc2 ----------------
__global__ __launch_bounds__(256) void k_fc2_simple(const float* __restrict__ h1,
                                                    const float* __restrict__ w,
                                                    const float* __restrict__ bias,
                                                    float* __restrict__ out) {
  const int idx = blockIdx.x * 256 + threadIdx.x;
  if (idx >= 64 * 12) return;
  const int oc = idx % 12, b = idx / 12;
  const float* hb = h1 + (size_t)b * 256;
  const float* wr = w + (size_t)oc * 256;
  float s = bias[oc];
  for (int k = 0; k < 256; ++k) s += hb[k] * wr[k];
  out[b * 12 + oc] = s;
}

// ---------------- launch ----------------
extern "C" void kernel_launch(void* const* d_in, const int* in_sizes, int n_in,
                              void* d_out, int out_size, void* d_ws, size_t ws_size,
                              hipStream_t stream) {
  const float* img  = (const float*)d_in[0];
  const float* w1 = (const float*)d_in[1];  const float* b1 = (const float*)d_in[2];
  const float* w2 = (const float*)d_in[3];  const float* b2 = (const float*)d_in[4];
  const float* w3 = (const float*)d_in[5];  const float* b3 = (const float*)d_in[6];
  const float* w4 = (const float*)d_in[7];  const float* b4 = (const float*)d_in[8];
  const float* w5 = (const float*)d_in[9];  const float* b5 = (const float*)d_in[10];
  const float* fc1w = (const float*)d_in[11]; const float* fc1b = (const float*)d_in[12];
  const float* fc2w = (const float*)d_in[13]; const float* fc2b = (const float*)d_in[14];
  float* out = (float*)d_out;
  float* ws  = (float*)d_ws;

  float* hint = ws + OFF_HINT;
  float* hgrd = ws + OFF_HGRD;
  float* f    = ws + OFF_F;
  float* h1   = ws + OFF_H1;
  float* p5   = ws + OFF_P5;
  unsigned* wpack = (unsigned*)(ws + OFF_WP);
  ushort_t* ra = (ushort_t*)(ws + OFF_RA);  // x0, p1, p2, a4
  ushort_t* rb = (ushort_t*)(ws + OFF_RB);  // a1, a2, a3, a5

  hipMemsetAsync(hint, 0, (size_t)2 * 64 * 160 * sizeof(float), stream);

  // weight pre-split (packed hi/lo u32)
  k_wsplit<<<(W1_N + 255)/256, 256, 0, stream>>>(w1, wpack + W1_OFF, W1_N);
  k_wsplit<<<(W2_N + 255)/256, 256, 0, stream>>>(w2, wpack + W2_OFF, W2_N);
  k_wsplit<<<(W3_N + 255)/256, 256, 0, stream>>>(w3, wpack + W3_OFF, W3_N);
  k_wsplit<<<(W4_N + 255)/256, 256, 0, stream>>>(w4, wpack + W4_OFF, W4_N);
  k_wsplit<<<(W5_N + 255)/256, 256, 0, stream>>>(w5, wpack + W5_OFF, W5_N);

  k_preproc<<<dim3(64, 28), 256, 0, stream>>>(img, hint, hgrd);
  k_resize <<<(64*112*112 + 255)/256, 256, 0, stream>>>(img, ra);          // x0 in RA

  // conv1: 3x112x112 (pad2, s4) -> 64x27x27
  k_conv_mfma<3,112,112,11,11,4,2,27,27,64>
      <<<dim3(729, 1), 256, 0, stream>>>(ra, wpack + W1_OFF, b1, rb);      // a1 in RB
  k_pool<64,27,13,false><<<(64*64*13*13 + 255)/256, 256, 0, stream>>>(rb, ra);   // p1 in RA
  // conv2: 64x13x13 (pad2) -> 192x13x13
  k_conv_mfma<64,13,13,5,5,1,2,13,13,192>
      <<<dim3(169, 3), 256, 0, stream>>>(ra, wpack + W2_OFF, b2, rb);      // a2 in RB
  k_pool<192,13,6,false><<<(64*192*6*6 + 255)/256, 256, 0, stream>>>(rb, ra);    // p2 in RA
  // conv3: 192x6x6 (pad1) -> 384x6x6
  k_conv_mfma<192,6,6,3,3,1,1,6,6,384>
      <<<dim3(36, 6), 256, 0, stream>>>(ra, wpack + W3_OFF, b3, rb);       // a3 in RB
  // conv4: 384x6x6 (pad1) -> 256x6x6
  k_conv_mfma<384,6,6,3,3,1,1,6,6,256>
      <<<dim3(36, 4), 256, 0, stream>>>(rb, wpack + W4_OFF, b4, ra);       // a4 in RA
  // conv5: 256x6x6 (pad1) -> 256x6x6
  k_conv_mfma<256,6,6,3,3,1,1,6,6,256>
      <<<dim3(36, 4), 256, 0, stream>>>(ra, wpack + W5_OFF, b5, rb);       // a5 in RB
  k_pool<256,6,2,true><<<(64*256*2*2 + 255)/256, 256, 0, stream>>>(rb, p5);

  k_feat<<<64, 256, 0, stream>>>(p5, hint, hgrd, f);
  k_fc1<<<(64*256)/4, 256, 0, stream>>>(f, fc1w, fc1b, h1);
  k_fc2_simple<<<(64*12 + 255)/256, 256, 0, stream>>>(h1, fc2w, fc2b, out);
}

// Round 9
// 499.541 us; speedup vs baseline: 9.7741x; 1.1323x over previous
//
#include <hip/hip_runtime.h>
#include <math.h>

typedef __attribute__((ext_vector_type(8))) short short8;
typedef __attribute__((ext_vector_type(8))) unsigned short u16x8;
typedef __attribute__((ext_vector_type(4))) float f32x4;
typedef unsigned short ushort_t;

// ---------------- workspace layout (float-slots, ~21.6 MB) ----------------
constexpr size_t OFF_HINT = 0;                                // 64*160
constexpr size_t OFF_HGRD = OFF_HINT + (size_t)64*160;        // 64*160
constexpr size_t OFF_F    = OFF_HGRD + (size_t)64*160;        // 64*4096
constexpr size_t OFF_H1   = OFF_F    + (size_t)64*4096;       // 64*256
constexpr size_t OFF_P5   = OFF_H1   + (size_t)64*256;        // 64*1024
constexpr size_t OFF_WHI  = OFF_P5   + (size_t)64*1024;       // 2,506,752 u16 = 1,253,376 slots
// per-layer weight offsets in u16 units, rows padded to K_ROUND = roundup(K,128)
constexpr size_t W1_OFF = 0;         constexpr int K1T = 363,  K1R = 384;   // 64  x 384
constexpr size_t W2_OFF = 24576;     constexpr int K2T = 1600, K2R = 1664;  // 192 x 1664
constexpr size_t W3_OFF = 344064;    constexpr int K3T = 1728, K3R = 1792;  // 384 x 1792
constexpr size_t W4_OFF = 1032192;   constexpr int K4T = 3456, K4R = 3456;  // 256 x 3456
constexpr size_t W5_OFF = 1916928;   constexpr int K5T = 2304, K5R = 2304;  // 256 x 2304
constexpr size_t WP_U16 = 2506752;
constexpr size_t OFF_WLO  = OFF_WHI + WP_U16/2;
constexpr size_t OFF_RA   = OFF_WLO + WP_U16/2;               // 2,583,552 u16 (x0p / p1p / p2p+a4p)
constexpr size_t SZ_RA    = (size_t)2583552/2;
constexpr size_t A4P_U16  = 786432;                           // a4p offset within RA (u16 units)
constexpr size_t OFF_RB   = OFF_RA + SZ_RA;                   // 2,985,984 u16 (a1 / a2 / a3p / a5)
constexpr size_t SZ_RB    = (size_t)2985984/2;
constexpr size_t WS_FLOATS = OFF_RB + SZ_RB;                  // 5,656,064 slots

__device__ __forceinline__ void bf16split(float v, unsigned short& hi, unsigned short& lo) {
  union { float f; unsigned u; } a; a.f = v;
  unsigned uh = (a.u + 0x7FFFu + ((a.u >> 16) & 1u)) >> 16;
  hi = (unsigned short)uh;
  union { unsigned u; float f; } b; b.u = uh << 16;
  float rem = v - b.f;
  union { float f; unsigned u; } c; c.f = rem;
  lo = (unsigned short)((c.u + 0x7FFFu + ((c.u >> 16) & 1u)) >> 16);
}
__device__ __forceinline__ ushort_t f2bf(float f) {
  union { float f; unsigned u; } a; a.f = f;
  return (ushort_t)((a.u + 0x7FFFu + ((a.u >> 16) & 1u)) >> 16);
}
__device__ __forceinline__ float bf2f(ushort_t u) {
  union { unsigned u; float f; } a; a.u = ((unsigned)u) << 16; return a.f;
}

// ---------------- weight pre-split: fp32 -> separate hi/lo bf16, rows padded to kround ----------------
__global__ __launch_bounds__(256) void k_wsplit(const float* __restrict__ w,
                                                ushort_t* __restrict__ whi,
                                                ushort_t* __restrict__ wlo,
                                                int ktot, int kround, int total) {
  const int idx = blockIdx.x * 256 + threadIdx.x;
  if (idx >= total) return;
  const int m = idx / kround, k = idx - m * kround;
  const float v = (k < ktot) ? w[(size_t)m * ktot + k] : 0.f;
  unsigned short h, l;
  bf16split(v, h, l);
  whi[idx] = h; wlo[idx] = l;
}

// match-any histogram insert
__device__ __forceinline__ void hist_insert(float* __restrict__ h, unsigned key) {
  unsigned long long m = __ballot(1);
  #pragma unroll
  for (int b = 0; b < 7; ++b) {
    const unsigned long long bal = __ballot((key >> b) & 1u);
    m &= ((key >> b) & 1u) ? bal : ~bal;
  }
  const unsigned lane = __builtin_amdgcn_mbcnt_hi(~0u, __builtin_amdgcn_mbcnt_lo(~0u, 0u));
  if ((m & ((1ull << lane) - 1ull)) == 0ull)
    atomicAdd(&h[key], (float)__popcll(m));
}

// ---------------- fused preproc: gray strip -> intensity + sobel QUADRANT hists ----------------
__global__ __launch_bounds__(256) void k_preproc(const float* __restrict__ img,
                                                 float* __restrict__ hint,
                                                 float* __restrict__ hgrd) {
  const int b = blockIdx.x, s = blockIdx.y;
  const int r0 = s * 16;
  __shared__ float gs[18][448];
  __shared__ float lhi_w[4][128], lhs_w[4][128];
  const int tid = threadIdx.x, wv = tid >> 6;
  for (int i = tid; i < 4 * 128; i += 256) { ((float*)lhi_w)[i] = 0.f; ((float*)lhs_w)[i] = 0.f; }
  const float* ib = img + (size_t)b * 4 * 200704;
  for (int i = tid; i < 18 * 112; i += 256) {
    const int rr = i / 112, c4 = (i % 112) * 4;
    int r = r0 + rr - 1; r = r < 0 ? 0 : (r > 447 ? 447 : r);
    const size_t o = (size_t)r * 448 + c4;
    const float4 vr = *(const float4*)&ib[o];
    const float4 g1 = *(const float4*)&ib[200704 + o];
    const float4 g2 = *(const float4*)&ib[2 * 200704 + o];
    const float4 vb = *(const float4*)&ib[3 * 200704 + o];
    float4 g;
    g.x = 0.299f * vr.x + 0.587f * (0.5f * (g1.x + g2.x)) + 0.114f * vb.x;
    g.y = 0.299f * vr.y + 0.587f * (0.5f * (g1.y + g2.y)) + 0.114f * vb.y;
    g.z = 0.299f * vr.z + 0.587f * (0.5f * (g1.z + g2.z)) + 0.114f * vb.z;
    g.w = 0.299f * vr.w + 0.587f * (0.5f * (g1.w + g2.w)) + 0.114f * vb.w;
    *(float4*)&gs[rr][c4] = g;
  }
  __syncthreads();
  for (int i = tid; i < 16 * 112; i += 256) {
    const int dr = i / 112, c4 = (i % 112) * 4;
    const int r = r0 + dr;
    const unsigned quad = ((r >= 224) ? 2u : 0u) + ((c4 >= 224) ? 1u : 0u);
    const int cl = c4 > 0 ? c4 - 1 : 0;
    const int cr = c4 < 444 ? c4 + 4 : 447;
    const float4 m0 = *(const float4*)&gs[dr][c4];
    const float4 m1 = *(const float4*)&gs[dr + 1][c4];
    const float4 m2 = *(const float4*)&gs[dr + 2][c4];
    const float r0v[6] = {gs[dr][cl],     m0.x, m0.y, m0.z, m0.w, gs[dr][cr]};
    const float r1v[6] = {gs[dr + 1][cl], m1.x, m1.y, m1.z, m1.w, gs[dr + 1][cr]};
    const float r2v[6] = {gs[dr + 2][cl], m2.x, m2.y, m2.z, m2.w, gs[dr + 2][cr]};
    float* hi = lhi_w[wv];
    float* hs = lhs_w[wv];
    #pragma unroll
    for (int j = 0; j < 4; ++j) {
      const float g = r1v[j + 1];
      int bin = (int)(g * 32.f); bin = bin > 31 ? 31 : (bin < 0 ? 0 : bin);
      hist_insert(hi, quad * 32u + (unsigned)bin);
      const float gx = (-r0v[j] + r0v[j + 2] - 2.f * r1v[j] + 2.f * r1v[j + 2]
                        - r2v[j] + r2v[j + 2]) * 0.125f;
      const float gy = (-r0v[j] - 2.f * r0v[j + 1] - r0v[j + 2]
                        + r2v[j] + 2.f * r2v[j + 1] + r2v[j + 2]) * 0.125f;
      const float mag = sqrtf(gx * gx + gy * gy + 1e-6f);
      int sb = (int)(mag * 32.f); sb = sb > 31 ? 31 : (sb < 0 ? 0 : sb);
      hist_insert(hs, quad * 32u + (unsigned)sb);
    }
  }
  __syncthreads();
  for (int idx = tid; idx < 128; idx += 256) {
    atomicAdd(&hint[(size_t)b * 160 + 32 + idx],
              lhi_w[0][idx] + lhi_w[1][idx] + lhi_w[2][idx] + lhi_w[3][idx]);
    atomicAdd(&hgrd[(size_t)b * 160 + 32 + idx],
              lhs_w[0][idx] + lhs_w[1][idx] + lhs_w[2][idx] + lhs_w[3][idx]);
  }
}

// ---------------- area resize 448->112 -> bf16 padded [b][3][116][116], pads zeroed ----------------
__global__ __launch_bounds__(256) void k_resize(const float* __restrict__ img,
                                                ushort_t* __restrict__ x0) {
  const int idx = blockIdx.x * 256 + threadIdx.x;
  if (idx >= 64 * 116 * 116) return;
  const int c = idx % 116;
  const int r = (idx / 116) % 116;
  const int b = idx / (116 * 116);
  ushort_t* xb = x0 + ((size_t)b * 3 * 116 + r) * 116 + c;
  if (r < 2 || r >= 114 || c < 2 || c >= 114) {
    xb[0] = 0; xb[116 * 116] = 0; xb[2 * 116 * 116] = 0;
    return;
  }
  const int rr = r - 2, cc = c - 2;
  const float* ib = img + (size_t)b * 4 * 200704;
  float sr = 0.f, sg = 0.f, sb = 0.f;
  #pragma unroll
  for (int i = 0; i < 4; ++i) {
    const size_t o = (size_t)(rr * 4 + i) * 448 + cc * 4;
    const float4 vr = *(const float4*)&ib[o];
    const float4 g1 = *(const float4*)&ib[200704 + o];
    const float4 g2 = *(const float4*)&ib[2 * 200704 + o];
    const float4 vb = *(const float4*)&ib[3 * 200704 + o];
    sr += vr.x + vr.y + vr.z + vr.w;
    sg += 0.5f * (g1.x + g2.x) + 0.5f * (g1.y + g2.y) + 0.5f * (g1.z + g2.z) + 0.5f * (g1.w + g2.w);
    sb += vb.x + vb.y + vb.z + vb.w;
  }
  xb[0]             = f2bf(sr * (1.f / 16.f));
  xb[116 * 116]     = f2bf(sg * (1.f / 16.f));
  xb[2 * 116 * 116] = f2bf(sb * (1.f / 16.f));
}

// ---------------- conv MFMA: padded bf16 input, direct-global hi/lo A, K-split x2, 512 thr ----------------
// out written at OPAD ring offset into [OHP][OWP] planes
template<int CIN, int HP, int WP, int KH, int KW, int STRIDE, int OH, int OW,
         int OHP, int OWP, int OPAD, int M, int MT>
__global__ __launch_bounds__(512) void k_conv_mfma(const ushort_t* __restrict__ in,
                                                   const ushort_t* __restrict__ whi_,
                                                   const ushort_t* __restrict__ wlo_,
                                                   const float* __restrict__ bias,
                                                   ushort_t* __restrict__ out) {
  constexpr int K_TOT  = CIN * KH * KW;
  constexpr int K_ROUND = ((K_TOT + 127) / 128) * 128;
  constexpr int GSTEPS = K_ROUND / 128;
  constexpr int KHW = KH * KW;
  constexpr int NPB = OH * OW;
  constexpr int WROWS = MT / 16;     // waves along m per K-group (4 or 2)
  constexpr int TGRP  = 4 / WROWS;   // n-groups of waves (1 or 2)
  constexpr int TFRAG = 4 / TGRP;    // 16-col frags per wave (4 or 2)
  __shared__ ushort_t Bs[2][64 * 64];
  __shared__ ushort_t ftab[K_ROUND];
  const int tid = threadIdx.x;
  const int lane = tid & 63, wv = tid >> 6;
  const int g = wv >> 2, wg = wv & 3;
  const int sub = tid & 255;
  const int n0 = blockIdx.x * 64, m0 = blockIdx.y * MT;
  // build ftab (byte offsets into the padded image; 0 for padded-K tail)
  for (int k = tid; k < K_ROUND; k += 512) {
    const int c = k / KHW, kr = k - c * KHW;
    const int ky = kr / KW, kx = kr - (kr / KW) * KW;
    ftab[k] = (k < K_TOT) ? (ushort_t)(2 * ((c * HP + ky) * WP + kx)) : (ushort_t)0;
  }
  // B staging coords: thread owns column `col`, ks [kc2*16, +16)
  const int col = sub & 63, kc2 = sub >> 6;
  const int nb = n0 + col;
  const int bB = nb / NPB, rB = nb % NPB;
  const int oyB = rB / OW, oxB = rB % OW;
  const char* baseB = (const char*)(in + (size_t)bB * CIN * HP * WP)
                      + 2 * (oyB * STRIDE * WP + oxB * STRIDE);
  // compute coords
  const int wm = wg % WROWS, tg = wg / WROWS;
  const int mrow = m0 + wm * 16 + (lane & 15);
  const ushort_t* wh = whi_ + (size_t)mrow * K_ROUND;
  const ushort_t* wl = wlo_ + (size_t)mrow * K_ROUND;
  const int kA = (lane >> 4) * 8;
  f32x4 acc[TFRAG] = {};
  __syncthreads();   // ftab ready
  const int kb0 = g * GSTEPS * 64;
  for (int step = 0; step < GSTEPS; ++step) {
    const int kb = kb0 + step * 64;
    const u16x8 f0 = *(const u16x8*)&ftab[kb + kc2 * 16];
    const u16x8 f1 = *(const u16x8*)&ftab[kb + kc2 * 16 + 8];
    u16x8 b0, b1;
    #pragma unroll
    for (int j = 0; j < 8; ++j) b0[j] = *(const ushort_t*)(baseB + f0[j]);
    #pragma unroll
    for (int j = 0; j < 8; ++j) b1[j] = *(const ushort_t*)(baseB + f1[j]);
    const int c0 = kc2 * 2, c1 = c0 + 1;
    *(u16x8*)&Bs[g][col * 64 + ((c0 ^ (col & 7)) * 8)] = b0;
    *(u16x8*)&Bs[g][col * 64 + ((c1 ^ (col & 7)) * 8)] = b1;
    __syncthreads();
    #pragma unroll
    for (int s = 0; s < 2; ++s) {
      const int kk = kb + s * 32 + kA;
      const short8 a_h = *(const short8*)&wh[kk];
      const short8 a_l = *(const short8*)&wl[kk];
      const int cA = s * 4 + (lane >> 4);
      #pragma unroll
      for (int tt = 0; tt < TFRAG; ++tt) {
        const int t = tg * TFRAG + tt;
        const int coln = t * 16 + (lane & 15);
        const short8 b_v = *(const short8*)&Bs[g][coln * 64 + ((cA ^ (coln & 7)) * 8)];
        acc[tt] = __builtin_amdgcn_mfma_f32_16x16x32_bf16(a_h, b_v, acc[tt], 0, 0, 0);
        acc[tt] = __builtin_amdgcn_mfma_f32_16x16x32_bf16(a_l, b_v, acc[tt], 0, 0, 0);
      }
    }
    __syncthreads();
  }
  // cross-group reduce through LDS (scratch overlays Bs)
  float* scratch = (float*)&Bs[0][0];   // MT*64 f32 <= 16KB
  if (g == 1) {
    #pragma unroll
    for (int tt = 0; tt < TFRAG; ++tt) {
      const int t = tg * TFRAG + tt;
      #pragma unroll
      for (int q = 0; q < 4; ++q)
        scratch[(wm * 16 + (lane >> 4) * 4 + q) * 64 + t * 16 + (lane & 15)] = acc[tt][q];
    }
  }
  __syncthreads();
  if (g == 0) {
    #pragma unroll
    for (int q = 0; q < 4; ++q) {
      const int m = m0 + wm * 16 + (lane >> 4) * 4 + q;
      const float bi = bias[m];
      #pragma unroll
      for (int tt = 0; tt < TFRAG; ++tt) {
        const int t = tg * TFRAG + tt;
        const int n = n0 + t * 16 + (lane & 15);
        const float v = acc[tt][q]
                      + scratch[(wm * 16 + (lane >> 4) * 4 + q) * 64 + t * 16 + (lane & 15)]
                      + bi;
        const int b = n / NPB, r = n % NPB;
        const int oy = r / OW, ox = r - (r / OW) * OW;
        out[(((size_t)b * M + m) * OHP + OPAD + oy) * OWP + OPAD + ox] = f2bf(fmaxf(v, 0.f));
      }
    }
  }
}

// ---------------- maxpool 3x3 s2 on bf16 bits -> padded output with zero ring ----------------
template<int C, int HI, int HO, int HOP, int PAD, bool OUTF32>
__global__ __launch_bounds__(256) void k_pool(const ushort_t* __restrict__ in,
                                              void* __restrict__ out) {
  const int idx = blockIdx.x * 256 + threadIdx.x;
  constexpr int TOT = 64 * C * HOP * HOP;
  if (idx >= TOT) return;
  const int x = idx % HOP;
  const int y = (idx / HOP) % HOP;
  const int c = (idx / (HOP * HOP)) % C;
  const int b = idx / (HOP * HOP * C);
  ushort_t v = 0;
  const int oy = y - PAD, ox = x - PAD;
  if (oy >= 0 && oy < HO && ox >= 0 && ox < HO) {
    const ushort_t* ib = in + (size_t)(b * C + c) * HI * HI + (size_t)(oy * 2) * HI + ox * 2;
    #pragma unroll
    for (int i = 0; i < 3; ++i)
      #pragma unroll
      for (int j = 0; j < 3; ++j) {
        const ushort_t u = ib[i * HI + j];
        v = u > v ? u : v;
      }
  }
  if constexpr (OUTF32) ((float*)out)[idx] = bf2f(v);
  else                  ((ushort_t*)out)[idx] = v;
}

// ---------------- feature assembly (h0 reconstructed from quadrant sums) ----------------
__global__ __launch_bounds__(256) void k_feat(const float* __restrict__ p5,
                                              const float* __restrict__ hint,
                                              const float* __restrict__ hgrad,
                                              float* __restrict__ f) {
  const int b = blockIdx.x, tid = threadIdx.x;
  __shared__ float tmp4[4];
  __shared__ float vals[160];
  const float* ps = p5 + (size_t)b * 1024;
  float* fb = f + (size_t)b * 4096;
  float mv[4]; float ss = 0.f;
  #pragma unroll
  for (int i = 0; i < 4; ++i) { mv[i] = ps[tid + i * 256]; ss += mv[i] * mv[i]; }
  #pragma unroll
  for (int o = 32; o > 0; o >>= 1) ss += __shfl_down(ss, o, 64);
  if ((tid & 63) == 0) tmp4[tid >> 6] = ss;
  __syncthreads();
  const float inv = 1.f / (sqrtf(tmp4[0] + tmp4[1] + tmp4[2] + tmp4[3]) + 1e-7f);
  #pragma unroll
  for (int i = 0; i < 4; ++i) fb[tid + i * 256] = fmaxf(mv[i] * inv, 0.f);
  for (int ft = 0; ft < 2; ++ft) {
    const float* hb = (ft ? hgrad : hint) + (size_t)b * 160;
    __syncthreads();
    if (tid < 160) {
      float cnt;
      if (tid < 32) cnt = hb[32 + tid] + hb[64 + tid] + hb[96 + tid] + hb[128 + tid];
      else          cnt = hb[tid];
      vals[tid] = cnt * (tid < 32 ? (1.f / 200704.f) : (1.f / 50176.f));
    }
    __syncthreads();
    float s2 = 0.f;
    if (tid < 160) s2 = (tid < 32 ? 16.f : 4.f) * vals[tid] * vals[tid];
    #pragma unroll
    for (int o = 32; o > 0; o >>= 1) s2 += __shfl_down(s2, o, 64);
    __syncthreads();
    if ((tid & 63) == 0) tmp4[tid >> 6] = s2;
    __syncthreads();
    const float inv2 = 1.f / (sqrtf(tmp4[0] + tmp4[1] + tmp4[2] + tmp4[3]) + 1e-7f);
    float* fo = fb + 1024 + ft * 1536;
    for (int idx = tid; idx < 1536; idx += 256) {
      const int ch = idx >> 4, i2 = (idx >> 2) & 3, j = idx & 3;
      float v;
      if (ch < 32)      v = vals[ch];
      else if (ch < 64) v = vals[32 + (((i2 >> 1) * 2) + (j >> 1)) * 32 + (ch - 32)];
      else              v = 0.f;
      fo[idx] = fmaxf(v * inv2, 0.f);
    }
  }
}

// ---------------- fc1: one wave per (b,oc) ----------------
__global__ __launch_bounds__(256) void k_fc1(const float* __restrict__ f,
                                             const float* __restrict__ w,
                                             const float* __restrict__ bias,
                                             float* __restrict__ h1) {
  const int gid = blockIdx.x * 4 + (threadIdx.x >> 6);
  const int lane = threadIdx.x & 63;
  if (gid >= 64 * 256) return;
  const int oc = gid & 255, b = gid >> 8;
  const float* fb = f + (size_t)b * 4096;
  const float* wr = w + (size_t)oc * 4096;
  float s = 0.f;
  for (int k = lane; k < 4096; k += 64) s += fb[k] * wr[k];
  #pragma unroll
  for (int o = 32; o > 0; o >>= 1) s += __shfl_down(s, o, 64);
  if (lane == 0) h1[(size_t)b * 256 + oc] = fmaxf(s + bias[oc], 0.f);
}

// ---------------- fc2 ----------------
__global__ __launch_bounds__(256) void k_fc2_simple(const float* __restrict__ h1,
                                                    const float* __restrict__ w,
                                                    const float* __restrict__ bias,
                                                    float* __restrict__ out) {
  const int idx = blockIdx.x * 256 + threadIdx.x;
  if (idx >= 64 * 12) return;
  const int oc = idx % 12, b = idx / 12;
  const float* hb = h1 + (size_t)b * 256;
  const float* wr = w + (size_t)oc * 256;
  float s = bias[oc];
  for (int k = 0; k < 256; ++k) s += hb[k] * wr[k];
  out[b * 12 + oc] = s;
}

// ---------------- launch ----------------
extern "C" void kernel_launch(void* const* d_in, const int* in_sizes, int n_in,
                              void* d_out, int out_size, void* d_ws, size_t ws_size,
                              hipStream_t stream) {
  const float* img  = (const float*)d_in[0];
  const float* w1 = (const float*)d_in[1];  const float* b1 = (const float*)d_in[2];
  const float* w2 = (const float*)d_in[3];  const float* b2 = (const float*)d_in[4];
  const float* w3 = (const float*)d_in[5];  const float* b3 = (const float*)d_in[6];
  const float* w4 = (const float*)d_in[7];  const float* b4 = (const float*)d_in[8];
  const float* w5 = (const float*)d_in[9];  const float* b5 = (const float*)d_in[10];
  const float* fc1w = (const float*)d_in[11]; const float* fc1b = (const float*)d_in[12];
  const float* fc2w = (const float*)d_in[13]; const float* fc2b = (const float*)d_in[14];
  float* out = (float*)d_out;
  float* ws  = (float*)d_ws;

  float* hint = ws + OFF_HINT;
  float* hgrd = ws + OFF_HGRD;
  float* f    = ws + OFF_F;
  float* h1   = ws + OFF_H1;
  float* p5   = ws + OFF_P5;
  ushort_t* whi = (ushort_t*)(ws + OFF_WHI);
  ushort_t* wlo = (ushort_t*)(ws + OFF_WLO);
  ushort_t* ra  = (ushort_t*)(ws + OFF_RA);   // x0p / p1p / p2p ; a4p at +A4P_U16
  ushort_t* rb  = (ushort_t*)(ws + OFF_RB);   // a1 / a2 / a3p / a5

  hipMemsetAsync(hint, 0, (size_t)2 * 64 * 160 * sizeof(float), stream);

  // weight pre-split to padded hi/lo rows
  k_wsplit<<<(64*K1R  + 255)/256, 256, 0, stream>>>(w1, whi + W1_OFF, wlo + W1_OFF, K1T, K1R, 64*K1R);
  k_wsplit<<<(192*K2R + 255)/256, 256, 0, stream>>>(w2, whi + W2_OFF, wlo + W2_OFF, K2T, K2R, 192*K2R);
  k_wsplit<<<(384*K3R + 255)/256, 256, 0, stream>>>(w3, whi + W3_OFF, wlo + W3_OFF, K3T, K3R, 384*K3R);
  k_wsplit<<<(256*K4R + 255)/256, 256, 0, stream>>>(w4, whi + W4_OFF, wlo + W4_OFF, K4T, K4R, 256*K4R);
  k_wsplit<<<(256*K5R + 255)/256, 256, 0, stream>>>(w5, whi + W5_OFF, wlo + W5_OFF, K5T, K5R, 256*K5R);

  k_preproc<<<dim3(64, 28), 256, 0, stream>>>(img, hint, hgrd);
  k_resize <<<(64*116*116 + 255)/256, 256, 0, stream>>>(img, ra);          // x0p (pads zeroed)

  // conv1: [b][3][116][116] -> a1 [b][64][27][27] (RB)
  k_conv_mfma<3,116,116,11,11,4,27,27,27,27,0,64,64>
      <<<dim3(729, 1), 512, 0, stream>>>(ra, whi + W1_OFF, wlo + W1_OFF, b1, rb);
  // pool1 -> p1p [b][64][17][17] pad2 (RA)
  k_pool<64,27,13,17,2,false><<<(64*64*17*17 + 255)/256, 256, 0, stream>>>(rb, ra);
  // conv2: -> a2 [b][192][13][13] (RB)
  k_conv_mfma<64,17,17,5,5,1,13,13,13,13,0,192,64>
      <<<dim3(169, 3), 512, 0, stream>>>(ra, whi + W2_OFF, wlo + W2_OFF, b2, rb);
  // pool2 -> p2p [b][192][8][8] pad1 (RA)
  k_pool<192,13,6,8,1,false><<<(64*192*8*8 + 255)/256, 256, 0, stream>>>(rb, ra);
  // zero pad rings for conv3/conv4 padded outputs (regions now dead)
  hipMemsetAsync(rb, 0, (size_t)64*384*8*8*2, stream);                      // a3p
  hipMemsetAsync(ra + A4P_U16, 0, (size_t)64*256*8*8*2, stream);            // a4p
  // conv3: p2p -> a3p [b][384][8][8] pad1 interior (RB)
  k_conv_mfma<192,8,8,3,3,1,6,6,8,8,1,384,32>
      <<<dim3(36, 12), 512, 0, stream>>>(ra, whi + W3_OFF, wlo + W3_OFF, b3, rb);
  // conv4: a3p -> a4p [b][256][8][8] pad1 interior (RA + A4P_U16)
  k_conv_mfma<384,8,8,3,3,1,6,6,8,8,1,256,32>
      <<<dim3(36, 8), 512, 0, stream>>>(rb, whi + W4_OFF, wlo + W4_OFF, b4, ra + A4P_U16);
  // conv5: a4p -> a5 [b][256][6][6] (RB)
  k_conv_mfma<256,8,8,3,3,1,6,6,6,6,0,256,32>
      <<<dim3(36, 8), 512, 0, stream>>>(ra + A4P_U16, whi + W5_OFF, wlo + W5_OFF, b5, rb);
  // pool5 -> p5 f32 [b][256][2][2]
  k_pool<256,6,2,2,0,true><<<(64*256*2*2 + 255)/256, 256, 0, stream>>>(rb, p5);

  k_feat<<<64, 256, 0, stream>>>(p5, hint, hgrd, f);
  k_fc1<<<(64*256)/4, 256, 0, stream>>>(f, fc1w, fc1b, h1);
  k_fc2_simple<<<(64*12 + 255)/256, 256, 0, stream>>>(h1, fc2w, fc2b, out);
}

// Round 10
// 475.077 us; speedup vs baseline: 10.2775x; 1.0515x over previous
//
#include <hip/hip_runtime.h>
#include <math.h>

typedef __attribute__((ext_vector_type(8))) short short8;
typedef __attribute__((ext_vector_type(8))) unsigned short u16x8;
typedef __attribute__((ext_vector_type(4))) float f32x4;
typedef unsigned short ushort_t;

// ---------------- workspace layout (float-slots, ~21.6 MB) ----------------
constexpr size_t OFF_HINT = 0;                                // 64*160
constexpr size_t OFF_HGRD = OFF_HINT + (size_t)64*160;        // 64*160
constexpr size_t OFF_F    = OFF_HGRD + (size_t)64*160;        // 64*4096
constexpr size_t OFF_H1   = OFF_F    + (size_t)64*4096;       // 64*256
constexpr size_t OFF_P5   = OFF_H1   + (size_t)64*256;        // 64*1024
constexpr size_t OFF_WHI  = OFF_P5   + (size_t)64*1024;       // 2,506,752 u16 = 1,253,376 slots
constexpr size_t W1_OFF = 0;         constexpr int K1T = 363,  K1R = 384;   // 64  x 384
constexpr size_t W2_OFF = 24576;     constexpr int K2T = 1600, K2R = 1664;  // 192 x 1664
constexpr size_t W3_OFF = 344064;    constexpr int K3T = 1728, K3R = 1792;  // 384 x 1792
constexpr size_t W4_OFF = 1032192;   constexpr int K4T = 3456, K4R = 3456;  // 256 x 3456
constexpr size_t W5_OFF = 1916928;   constexpr int K5T = 2304, K5R = 2304;  // 256 x 2304
constexpr size_t WP_U16 = 2506752;
constexpr size_t OFF_WLO  = OFF_WHI + WP_U16/2;
constexpr size_t OFF_RA   = OFF_WLO + WP_U16/2;               // 2,583,552 u16 (x0p / p1p / p2p+a4p)
constexpr size_t SZ_RA    = (size_t)2583552/2;
constexpr size_t A4P_U16  = 786432;                           // a4p offset within RA (u16 units)
constexpr size_t OFF_RB   = OFF_RA + SZ_RA;                   // 2,985,984 u16 (a1 / a2 / a3p / a5)
constexpr size_t SZ_RB    = (size_t)2985984/2;
constexpr size_t WS_FLOATS = OFF_RB + SZ_RB;                  // 5,656,064 slots

__device__ __forceinline__ void bf16split(float v, unsigned short& hi, unsigned short& lo) {
  union { float f; unsigned u; } a; a.f = v;
  unsigned uh = (a.u + 0x7FFFu + ((a.u >> 16) & 1u)) >> 16;
  hi = (unsigned short)uh;
  union { unsigned u; float f; } b; b.u = uh << 16;
  float rem = v - b.f;
  union { float f; unsigned u; } c; c.f = rem;
  lo = (unsigned short)((c.u + 0x7FFFu + ((c.u >> 16) & 1u)) >> 16);
}
__device__ __forceinline__ ushort_t f2bf(float f) {
  union { float f; unsigned u; } a; a.f = f;
  return (ushort_t)((a.u + 0x7FFFu + ((a.u >> 16) & 1u)) >> 16);
}
__device__ __forceinline__ float bf2f(ushort_t u) {
  union { unsigned u; float f; } a; a.u = ((unsigned)u) << 16; return a.f;
}

// ---------------- weight pre-split: fp32 -> separate hi/lo bf16, rows padded to kround ----------------
__global__ __launch_bounds__(256) void k_wsplit(const float* __restrict__ w,
                                                ushort_t* __restrict__ whi,
                                                ushort_t* __restrict__ wlo,
                                                int ktot, int kround, int total) {
  const int idx = blockIdx.x * 256 + threadIdx.x;
  if (idx >= total) return;
  const int m = idx / kround, k = idx - m * kround;
  const float v = (k < ktot) ? w[(size_t)m * ktot + k] : 0.f;
  unsigned short h, l;
  bf16split(v, h, l);
  whi[idx] = h; wlo[idx] = l;
}

// ---------------- fused preproc: per-thread u8 LDS histogram columns, no atomics/ballots ----------------
// Table: [128 keys][260 u8]; key = type*64 + colbit*32 + bin. Row-quad bit is block-uniform
// (strips of 16 rows never straddle r=224) and is folded into the final global index.
__global__ __launch_bounds__(256) void k_preproc(const float* __restrict__ img,
                                                 float* __restrict__ hint,
                                                 float* __restrict__ hgrd) {
  const int b = blockIdx.x, s = blockIdx.y;   // 28 strips of 16 rows
  const int r0 = s * 16;
  __shared__ float gs[18][448];                 // 32256 B
  __shared__ unsigned char lh[128 * 260];       // 33280 B
  const int tid = threadIdx.x;
  for (int i = tid; i < (128 * 260) / 4; i += 256) ((unsigned*)lh)[i] = 0u;
  const float* ib = img + (size_t)b * 4 * 200704;
  for (int i = tid; i < 18 * 112; i += 256) {
    const int rr = i / 112, c4 = (i % 112) * 4;
    int r = r0 + rr - 1; r = r < 0 ? 0 : (r > 447 ? 447 : r);
    const size_t o = (size_t)r * 448 + c4;
    const float4 vr = *(const float4*)&ib[o];
    const float4 g1 = *(const float4*)&ib[200704 + o];
    const float4 g2 = *(const float4*)&ib[2 * 200704 + o];
    const float4 vb = *(const float4*)&ib[3 * 200704 + o];
    float4 g;
    g.x = 0.299f * vr.x + 0.587f * (0.5f * (g1.x + g2.x)) + 0.114f * vb.x;
    g.y = 0.299f * vr.y + 0.587f * (0.5f * (g1.y + g2.y)) + 0.114f * vb.y;
    g.z = 0.299f * vr.z + 0.587f * (0.5f * (g1.z + g2.z)) + 0.114f * vb.z;
    g.w = 0.299f * vr.w + 0.587f * (0.5f * (g1.w + g2.w)) + 0.114f * vb.w;
    *(float4*)&gs[rr][c4] = g;
  }
  __syncthreads();
  for (int i = tid; i < 16 * 112; i += 256) {   // 7 full iterations
    const int dr = i / 112, c4 = (i % 112) * 4;
    const unsigned colbit = (c4 >= 224) ? 1u : 0u;   // 4-px block never straddles 224
    const int cl = c4 > 0 ? c4 - 1 : 0;
    const int cr = c4 < 444 ? c4 + 4 : 447;
    const float4 m0 = *(const float4*)&gs[dr][c4];
    const float4 m1 = *(const float4*)&gs[dr + 1][c4];
    const float4 m2 = *(const float4*)&gs[dr + 2][c4];
    const float r0v[6] = {gs[dr][cl],     m0.x, m0.y, m0.z, m0.w, gs[dr][cr]};
    const float r1v[6] = {gs[dr + 1][cl], m1.x, m1.y, m1.z, m1.w, gs[dr + 1][cr]};
    const float r2v[6] = {gs[dr + 2][cl], m2.x, m2.y, m2.z, m2.w, gs[dr + 2][cr]};
    #pragma unroll
    for (int j = 0; j < 4; ++j) {
      const float g = r1v[j + 1];
      int bin = (int)(g * 32.f); bin = bin > 31 ? 31 : (bin < 0 ? 0 : bin);
      lh[(colbit * 32u + (unsigned)bin) * 260u + (unsigned)tid]++;
      const float gx = (-r0v[j] + r0v[j + 2] - 2.f * r1v[j] + 2.f * r1v[j + 2]
                        - r2v[j] + r2v[j + 2]) * 0.125f;
      const float gy = (-r0v[j] - 2.f * r0v[j + 1] - r0v[j + 2]
                        + r2v[j] + 2.f * r2v[j + 1] + r2v[j + 2]) * 0.125f;
      const float mag = sqrtf(gx * gx + gy * gy + 1e-6f);
      int sb = (int)(mag * 32.f); sb = sb > 31 ? 31 : (sb < 0 ? 0 : sb);
      lh[(64u + colbit * 32u + (unsigned)sb) * 260u + (unsigned)tid]++;
    }
  }
  __syncthreads();
  // reduction: 2 threads per key sum 256 u8 counts (64 dwords), combine, one atomic
  const unsigned rowbit = (s >= 14) ? 1u : 0u;
  const int key = tid >> 1, half = tid & 1;
  const unsigned* row = (const unsigned*)&lh[(unsigned)key * 260u];  // 260 = 65 dwords, 4B aligned
  unsigned sum = 0;
  #pragma unroll
  for (int d = 0; d < 32; ++d) {
    const unsigned v = row[half * 32 + d];
    sum += (v & 0xFFu) + ((v >> 8) & 0xFFu) + ((v >> 16) & 0xFFu) + (v >> 24);
  }
  sum += __shfl_down(sum, 1, 64);
  if (half == 0) {
    const int type = key >> 6;
    const int rest = key & 63;
    const int colbit2 = rest >> 5, bin = rest & 31;
    float* dst = (type ? hgrd : hint) + (size_t)b * 160 + 32 + (rowbit * 2 + colbit2) * 32 + bin;
    atomicAdd(dst, (float)sum);
  }
}

// ---------------- area resize 448->112 -> bf16 padded [b][3][116][116], pads zeroed ----------------
__global__ __launch_bounds__(256) void k_resize(const float* __restrict__ img,
                                                ushort_t* __restrict__ x0) {
  const int idx = blockIdx.x * 256 + threadIdx.x;
  if (idx >= 64 * 116 * 116) return;
  const int c = idx % 116;
  const int r = (idx / 116) % 116;
  const int b = idx / (116 * 116);
  ushort_t* xb = x0 + ((size_t)b * 3 * 116 + r) * 116 + c;
  if (r < 2 || r >= 114 || c < 2 || c >= 114) {
    xb[0] = 0; xb[116 * 116] = 0; xb[2 * 116 * 116] = 0;
    return;
  }
  const int rr = r - 2, cc = c - 2;
  const float* ib = img + (size_t)b * 4 * 200704;
  float sr = 0.f, sg = 0.f, sb = 0.f;
  #pragma unroll
  for (int i = 0; i < 4; ++i) {
    const size_t o = (size_t)(rr * 4 + i) * 448 + cc * 4;
    const float4 vr = *(const float4*)&ib[o];
    const float4 g1 = *(const float4*)&ib[200704 + o];
    const float4 g2 = *(const float4*)&ib[2 * 200704 + o];
    const float4 vb = *(const float4*)&ib[3 * 200704 + o];
    sr += vr.x + vr.y + vr.z + vr.w;
    sg += 0.5f * (g1.x + g2.x) + 0.5f * (g1.y + g2.y) + 0.5f * (g1.z + g2.z) + 0.5f * (g1.w + g2.w);
    sb += vb.x + vb.y + vb.z + vb.w;
  }
  xb[0]             = f2bf(sr * (1.f / 16.f));
  xb[116 * 116]     = f2bf(sg * (1.f / 16.f));
  xb[2 * 116 * 116] = f2bf(sb * (1.f / 16.f));
}

// ---------------- conv MFMA: padded bf16 input, direct-global hi/lo A, K-split x2, 512 thr ----------------
template<int CIN, int HP, int WP, int KH, int KW, int STRIDE, int OH, int OW,
         int OHP, int OWP, int OPAD, int M, int MT>
__global__ __launch_bounds__(512) void k_conv_mfma(const ushort_t* __restrict__ in,
                                                   const ushort_t* __restrict__ whi_,
                                                   const ushort_t* __restrict__ wlo_,
                                                   const float* __restrict__ bias,
                                                   ushort_t* __restrict__ out) {
  constexpr int K_TOT  = CIN * KH * KW;
  constexpr int K_ROUND = ((K_TOT + 127) / 128) * 128;
  constexpr int GSTEPS = K_ROUND / 128;
  constexpr int KHW = KH * KW;
  constexpr int NPB = OH * OW;
  constexpr int WROWS = MT / 16;
  constexpr int TGRP  = 4 / WROWS;
  constexpr int TFRAG = 4 / TGRP;
  __shared__ ushort_t Bs[2][64 * 64];
  __shared__ ushort_t ftab[K_ROUND];
  const int tid = threadIdx.x;
  const int lane = tid & 63, wv = tid >> 6;
  const int g = wv >> 2, wg = wv & 3;
  const int sub = tid & 255;
  const int n0 = blockIdx.x * 64, m0 = blockIdx.y * MT;
  for (int k = tid; k < K_ROUND; k += 512) {
    const int c = k / KHW, kr = k - c * KHW;
    const int ky = kr / KW, kx = kr - (kr / KW) * KW;
    ftab[k] = (k < K_TOT) ? (ushort_t)(2 * ((c * HP + ky) * WP + kx)) : (ushort_t)0;
  }
  const int col = sub & 63, kc2 = sub >> 6;
  const int nb = n0 + col;
  const int bB = nb / NPB, rB = nb % NPB;
  const int oyB = rB / OW, oxB = rB % OW;
  const char* baseB = (const char*)(in + (size_t)bB * CIN * HP * WP)
                      + 2 * (oyB * STRIDE * WP + oxB * STRIDE);
  const int wm = wg % WROWS, tg = wg / WROWS;
  const int mrow = m0 + wm * 16 + (lane & 15);
  const ushort_t* wh = whi_ + (size_t)mrow * K_ROUND;
  const ushort_t* wl = wlo_ + (size_t)mrow * K_ROUND;
  const int kA = (lane >> 4) * 8;
  f32x4 acc[TFRAG] = {};
  __syncthreads();
  const int kb0 = g * GSTEPS * 64;
  for (int step = 0; step < GSTEPS; ++step) {
    const int kb = kb0 + step * 64;
    const u16x8 f0 = *(const u16x8*)&ftab[kb + kc2 * 16];
    const u16x8 f1 = *(const u16x8*)&ftab[kb + kc2 * 16 + 8];
    u16x8 b0, b1;
    #pragma unroll
    for (int j = 0; j < 8; ++j) b0[j] = *(const ushort_t*)(baseB + f0[j]);
    #pragma unroll
    for (int j = 0; j < 8; ++j) b1[j] = *(const ushort_t*)(baseB + f1[j]);
    const int c0 = kc2 * 2, c1 = c0 + 1;
    *(u16x8*)&Bs[g][col * 64 + ((c0 ^ (col & 7)) * 8)] = b0;
    *(u16x8*)&Bs[g][col * 64 + ((c1 ^ (col & 7)) * 8)] = b1;
    __syncthreads();
    #pragma unroll
    for (int s = 0; s < 2; ++s) {
      const int kk = kb + s * 32 + kA;
      const short8 a_h = *(const short8*)&wh[kk];
      const short8 a_l = *(const short8*)&wl[kk];
      const int cA = s * 4 + (lane >> 4);
      #pragma unroll
      for (int tt = 0; tt < TFRAG; ++tt) {
        const int t = tg * TFRAG + tt;
        const int coln = t * 16 + (lane & 15);
        const short8 b_v = *(const short8*)&Bs[g][coln * 64 + ((cA ^ (coln & 7)) * 8)];
        acc[tt] = __builtin_amdgcn_mfma_f32_16x16x32_bf16(a_h, b_v, acc[tt], 0, 0, 0);
        acc[tt] = __builtin_amdgcn_mfma_f32_16x16x32_bf16(a_l, b_v, acc[tt], 0, 0, 0);
      }
    }
    __syncthreads();
  }
  float* scratch = (float*)&Bs[0][0];
  if (g == 1) {
    #pragma unroll
    for (int tt = 0; tt < TFRAG; ++tt) {
      const int t = tg * TFRAG + tt;
      #pragma unroll
      for (int q = 0; q < 4; ++q)
        scratch[(wm * 16 + (lane >> 4) * 4 + q) * 64 + t * 16 + (lane & 15)] = acc[tt][q];
    }
  }
  __syncthreads();
  if (g == 0) {
    #pragma unroll
    for (int q = 0; q < 4; ++q) {
      const int m = m0 + wm * 16 + (lane >> 4) * 4 + q;
      const float bi = bias[m];
      #pragma unroll
      for (int tt = 0; tt < TFRAG; ++tt) {
        const int t = tg * TFRAG + tt;
        const int n = n0 + t * 16 + (lane & 15);
        const float v = acc[tt][q]
                      + scratch[(wm * 16 + (lane >> 4) * 4 + q) * 64 + t * 16 + (lane & 15)]
                      + bi;
        const int b = n / NPB, r = n % NPB;
        const int oy = r / OW, ox = r - (r / OW) * OW;
        out[(((size_t)b * M + m) * OHP + OPAD + oy) * OWP + OPAD + ox] = f2bf(fmaxf(v, 0.f));
      }
    }
  }
}

// ---------------- maxpool 3x3 s2 on bf16 bits -> padded output with zero ring ----------------
template<int C, int HI, int HO, int HOP, int PAD, bool OUTF32>
__global__ __launch_bounds__(256) void k_pool(const ushort_t* __restrict__ in,
                                              void* __restrict__ out) {
  const int idx = blockIdx.x * 256 + threadIdx.x;
  constexpr int TOT = 64 * C * HOP * HOP;
  if (idx >= TOT) return;
  const int x = idx % HOP;
  const int y = (idx / HOP) % HOP;
  const int c = (idx / (HOP * HOP)) % C;
  const int b = idx / (HOP * HOP * C);
  ushort_t v = 0;
  const int oy = y - PAD, ox = x - PAD;
  if (oy >= 0 && oy < HO && ox >= 0 && ox < HO) {
    const ushort_t* ib = in + (size_t)(b * C + c) * HI * HI + (size_t)(oy * 2) * HI + ox * 2;
    #pragma unroll
    for (int i = 0; i < 3; ++i)
      #pragma unroll
      for (int j = 0; j < 3; ++j) {
        const ushort_t u = ib[i * HI + j];
        v = u > v ? u : v;
      }
  }
  if constexpr (OUTF32) ((float*)out)[idx] = bf2f(v);
  else                  ((ushort_t*)out)[idx] = v;
}

// ---------------- feature assembly (h0 reconstructed from quadrant sums) ----------------
__global__ __launch_bounds__(256) void k_feat(const float* __restrict__ p5,
                                              const float* __restrict__ hint,
                                              const float* __restrict__ hgrad,
                                              float* __restrict__ f) {
  const int b = blockIdx.x, tid = threadIdx.x;
  __shared__ float tmp4[4];
  __shared__ float vals[160];
  const float* ps = p5 + (size_t)b * 1024;
  float* fb = f + (size_t)b * 4096;
  float mv[4]; float ss = 0.f;
  #pragma unroll
  for (int i = 0; i < 4; ++i) { mv[i] = ps[tid + i * 256]; ss += mv[i] * mv[i]; }
  #pragma unroll
  for (int o = 32; o > 0; o >>= 1) ss += __shfl_down(ss, o, 64);
  if ((tid & 63) == 0) tmp4[tid >> 6] = ss;
  __syncthreads();
  const float inv = 1.f / (sqrtf(tmp4[0] + tmp4[1] + tmp4[2] + tmp4[3]) + 1e-7f);
  #pragma unroll
  for (int i = 0; i < 4; ++i) fb[tid + i * 256] = fmaxf(mv[i] * inv, 0.f);
  for (int ft = 0; ft < 2; ++ft) {
    const float* hb = (ft ? hgrad : hint) + (size_t)b * 160;
    __syncthreads();
    if (tid < 160) {
      float cnt;
      if (tid < 32) cnt = hb[32 + tid] + hb[64 + tid] + hb[96 + tid] + hb[128 + tid];
      else          cnt = hb[tid];
      vals[tid] = cnt * (tid < 32 ? (1.f / 200704.f) : (1.f / 50176.f));
    }
    __syncthreads();
    float s2 = 0.f;
    if (tid < 160) s2 = (tid < 32 ? 16.f : 4.f) * vals[tid] * vals[tid];
    #pragma unroll
    for (int o = 32; o > 0; o >>= 1) s2 += __shfl_down(s2, o, 64);
    __syncthreads();
    if ((tid & 63) == 0) tmp4[tid >> 6] = s2;
    __syncthreads();
    const float inv2 = 1.f / (sqrtf(tmp4[0] + tmp4[1] + tmp4[2] + tmp4[3]) + 1e-7f);
    float* fo = fb + 1024 + ft * 1536;
    for (int idx = tid; idx < 1536; idx += 256) {
      const int ch = idx >> 4, i2 = (idx >> 2) & 3, j = idx & 3;
      float v;
      if (ch < 32)      v = vals[ch];
      else if (ch < 64) v = vals[32 + (((i2 >> 1) * 2) + (j >> 1)) * 32 + (ch - 32)];
      else              v = 0.f;
      fo[idx] = fmaxf(v * inv2, 0.f);
    }
  }
}

// ---------------- fc1: one wave per (b,oc) ----------------
__global__ __launch_bounds__(256) void k_fc1(const float* __restrict__ f,
                                             const float* __restrict__ w,
                                             const float* __restrict__ bias,
                                             float* __restrict__ h1) {
  const int gid = blockIdx.x * 4 + (threadIdx.x >> 6);
  const int lane = threadIdx.x & 63;
  if (gid >= 64 * 256) return;
  const int oc = gid & 255, b = gid >> 8;
  const float* fb = f + (size_t)b * 4096;
  const float* wr = w + (size_t)oc * 4096;
  float s = 0.f;
  for (int k = lane; k < 4096; k += 64) s += fb[k] * wr[k];
  #pragma unroll
  for (int o = 32; o > 0; o >>= 1) s += __shfl_down(s, o, 64);
  if (lane == 0) h1[(size_t)b * 256 + oc] = fmaxf(s + bias[oc], 0.f);
}

// ---------------- fc2 ----------------
__global__ __launch_bounds__(256) void k_fc2_simple(const float* __restrict__ h1,
                                                    const float* __restrict__ w,
                                                    const float* __restrict__ bias,
                                                    float* __restrict__ out) {
  const int idx = blockIdx.x * 256 + threadIdx.x;
  if (idx >= 64 * 12) return;
  const int oc = idx % 12, b = idx / 12;
  const float* hb = h1 + (size_t)b * 256;
  const float* wr = w + (size_t)oc * 256;
  float s = bias[oc];
  for (int k = 0; k < 256; ++k) s += hb[k] * wr[k];
  out[b * 12 + oc] = s;
}

// ---------------- launch ----------------
extern "C" void kernel_launch(void* const* d_in, const int* in_sizes, int n_in,
                              void* d_out, int out_size, void* d_ws, size_t ws_size,
                              hipStream_t stream) {
  const float* img  = (const float*)d_in[0];
  const float* w1 = (const float*)d_in[1];  const float* b1 = (const float*)d_in[2];
  const float* w2 = (const float*)d_in[3];  const float* b2 = (const float*)d_in[4];
  const float* w3 = (const float*)d_in[5];  const float* b3 = (const float*)d_in[6];
  const float* w4 = (const float*)d_in[7];  const float* b4 = (const float*)d_in[8];
  const float* w5 = (const float*)d_in[9];  const float* b5 = (const float*)d_in[10];
  const float* fc1w = (const float*)d_in[11]; const float* fc1b = (const float*)d_in[12];
  const float* fc2w = (const float*)d_in[13]; const float* fc2b = (const float*)d_in[14];
  float* out = (float*)d_out;
  float* ws  = (float*)d_ws;

  float* hint = ws + OFF_HINT;
  float* hgrd = ws + OFF_HGRD;
  float* f    = ws + OFF_F;
  float* h1   = ws + OFF_H1;
  float* p5   = ws + OFF_P5;
  ushort_t* whi = (ushort_t*)(ws + OFF_WHI);
  ushort_t* wlo = (ushort_t*)(ws + OFF_WLO);
  ushort_t* ra  = (ushort_t*)(ws + OFF_RA);   // x0p / p1p / p2p ; a4p at +A4P_U16
  ushort_t* rb  = (ushort_t*)(ws + OFF_RB);   // a1 / a2 / a3p / a5

  hipMemsetAsync(hint, 0, (size_t)2 * 64 * 160 * sizeof(float), stream);

  // weight pre-split to padded hi/lo rows
  k_wsplit<<<(64*K1R  + 255)/256, 256, 0, stream>>>(w1, whi + W1_OFF, wlo + W1_OFF, K1T, K1R, 64*K1R);
  k_wsplit<<<(192*K2R + 255)/256, 256, 0, stream>>>(w2, whi + W2_OFF, wlo + W2_OFF, K2T, K2R, 192*K2R);
  k_wsplit<<<(384*K3R + 255)/256, 256, 0, stream>>>(w3, whi + W3_OFF, wlo + W3_OFF, K3T, K3R, 384*K3R);
  k_wsplit<<<(256*K4R + 255)/256, 256, 0, stream>>>(w4, whi + W4_OFF, wlo + W4_OFF, K4T, K4R, 256*K4R);
  k_wsplit<<<(256*K5R + 255)/256, 256, 0, stream>>>(w5, whi + W5_OFF, wlo + W5_OFF, K5T, K5R, 256*K5R);

  k_preproc<<<dim3(64, 28), 256, 0, stream>>>(img, hint, hgrd);
  k_resize <<<(64*116*116 + 255)/256, 256, 0, stream>>>(img, ra);          // x0p (pads zeroed)

  // conv1: [b][3][116][116] -> a1 [b][64][27][27] (RB)
  k_conv_mfma<3,116,116,11,11,4,27,27,27,27,0,64,64>
      <<<dim3(729, 1), 512, 0, stream>>>(ra, whi + W1_OFF, wlo + W1_OFF, b1, rb);
  // pool1 -> p1p [b][64][17][17] pad2 (RA)
  k_pool<64,27,13,17,2,false><<<(64*64*17*17 + 255)/256, 256, 0, stream>>>(rb, ra);
  // conv2: -> a2 [b][192][13][13] (RB)
  k_conv_mfma<64,17,17,5,5,1,13,13,13,13,0,192,64>
      <<<dim3(169, 3), 512, 0, stream>>>(ra, whi + W2_OFF, wlo + W2_OFF, b2, rb);
  // pool2 -> p2p [b][192][8][8] pad1 (RA)
  k_pool<192,13,6,8,1,false><<<(64*192*8*8 + 255)/256, 256, 0, stream>>>(rb, ra);
  // zero pad rings for conv3/conv4 padded outputs
  hipMemsetAsync(rb, 0, (size_t)64*384*8*8*2, stream);                      // a3p
  hipMemsetAsync(ra + A4P_U16, 0, (size_t)64*256*8*8*2, stream);            // a4p
  // conv3: p2p -> a3p [b][384][8][8] pad1 interior (RB)
  k_conv_mfma<192,8,8,3,3,1,6,6,8,8,1,384,32>
      <<<dim3(36, 12), 512, 0, stream>>>(ra, whi + W3_OFF, wlo + W3_OFF, b3, rb);
  // conv4: a3p -> a4p [b][256][8][8] pad1 interior (RA + A4P_U16)
  k_conv_mfma<384,8,8,3,3,1,6,6,8,8,1,256,32>
      <<<dim3(36, 8), 512, 0, stream>>>(rb, whi + W4_OFF, wlo + W4_OFF, b4, ra + A4P_U16);
  // conv5: a4p -> a5 [b][256][6][6] (RB)
  k_conv_mfma<256,8,8,3,3,1,6,6,6,6,0,256,32>
      <<<dim3(36, 8), 512, 0, stream>>>(ra + A4P_U16, whi + W5_OFF, wlo + W5_OFF, b5, rb);
  // pool5 -> p5 f32 [b][256][2][2]
  k_pool<256,6,2,2,0,true><<<(64*256*2*2 + 255)/256, 256, 0, stream>>>(rb, p5);

  k_feat<<<64, 256, 0, stream>>>(p5, hint, hgrd, f);
  k_fc1<<<(64*256)/4, 256, 0, stream>>>(f, fc1w, fc1b, h1);
  k_fc2_simple<<<(64*12 + 255)/256, 256, 0, stream>>>(h1, fc2w, fc2b, out);
}

// Round 11
// 445.476 us; speedup vs baseline: 10.9604x; 1.0664x over previous
//
#include <hip/hip_runtime.h>
#include <math.h>

typedef __attribute__((ext_vector_type(8))) short short8;
typedef __attribute__((ext_vector_type(8))) unsigned short u16x8;
typedef __attribute__((ext_vector_type(4))) float f32x4;
typedef unsigned short ushort_t;

// ---------------- workspace layout (float-slots, ~21.6 MB) ----------------
constexpr size_t OFF_HINT = 0;                                // 64*160
constexpr size_t OFF_HGRD = OFF_HINT + (size_t)64*160;        // 64*160
constexpr size_t OFF_F    = OFF_HGRD + (size_t)64*160;        // 64*4096
constexpr size_t OFF_H1   = OFF_F    + (size_t)64*4096;       // 64*256
constexpr size_t OFF_P5   = OFF_H1   + (size_t)64*256;        // 64*1024
constexpr size_t OFF_WHI  = OFF_P5   + (size_t)64*1024;       // 2,506,752 u16 = 1,253,376 slots
constexpr size_t W1_OFF = 0;         constexpr int K1T = 363,  K1R = 384;   // 64  x 384
constexpr size_t W2_OFF = 24576;     constexpr int K2T = 1600, K2R = 1664;  // 192 x 1664
constexpr size_t W3_OFF = 344064;    constexpr int K3T = 1728, K3R = 1792;  // 384 x 1792
constexpr size_t W4_OFF = 1032192;   constexpr int K4T = 3456, K4R = 3456;  // 256 x 3456
constexpr size_t W5_OFF = 1916928;   constexpr int K5T = 2304, K5R = 2304;  // 256 x 2304
constexpr size_t WP_U16 = 2506752;
constexpr size_t OFF_WLO  = OFF_WHI + WP_U16/2;
constexpr size_t OFF_RA   = OFF_WLO + WP_U16/2;               // 2,583,552 u16 (x0p / p1p / p2p+a4p)
constexpr size_t SZ_RA    = (size_t)2583552/2;
constexpr size_t A4P_U16  = 786432;                           // a4p offset within RA (u16 units)
constexpr size_t OFF_RB   = OFF_RA + SZ_RA;                   // 2,985,984 u16 (a1 / a2 / a3p / a5)
constexpr size_t SZ_RB    = (size_t)2985984/2;
constexpr size_t WS_FLOATS = OFF_RB + SZ_RB;                  // 5,656,064 slots

__device__ __forceinline__ void bf16split(float v, unsigned short& hi, unsigned short& lo) {
  union { float f; unsigned u; } a; a.f = v;
  unsigned uh = (a.u + 0x7FFFu + ((a.u >> 16) & 1u)) >> 16;
  hi = (unsigned short)uh;
  union { unsigned u; float f; } b; b.u = uh << 16;
  float rem = v - b.f;
  union { float f; unsigned u; } c; c.f = rem;
  lo = (unsigned short)((c.u + 0x7FFFu + ((c.u >> 16) & 1u)) >> 16);
}
__device__ __forceinline__ ushort_t f2bf(float f) {
  union { float f; unsigned u; } a; a.f = f;
  return (ushort_t)((a.u + 0x7FFFu + ((a.u >> 16) & 1u)) >> 16);
}
__device__ __forceinline__ float bf2f(ushort_t u) {
  union { unsigned u; float f; } a; a.u = ((unsigned)u) << 16; return a.f;
}

// ---------------- single-launch weight pre-split for all 5 layers ----------------
__global__ __launch_bounds__(256) void k_wsplit_all(const float* __restrict__ w1,
                                                    const float* __restrict__ w2,
                                                    const float* __restrict__ w3,
                                                    const float* __restrict__ w4,
                                                    const float* __restrict__ w5,
                                                    ushort_t* __restrict__ whi,
                                                    ushort_t* __restrict__ wlo) {
  const size_t idx = (size_t)blockIdx.x * 256 + threadIdx.x;
  if (idx >= WP_U16) return;
  const float* w; int kt, kr; size_t base;
  if (idx < W2_OFF)                { w = w1; kt = K1T; kr = K1R; base = W1_OFF; }
  else if (idx < W3_OFF)           { w = w2; kt = K2T; kr = K2R; base = W2_OFF; }
  else if (idx < W4_OFF)           { w = w3; kt = K3T; kr = K3R; base = W3_OFF; }
  else if (idx < W5_OFF)           { w = w4; kt = K4T; kr = K4R; base = W4_OFF; }
  else                             { w = w5; kt = K5T; kr = K5R; base = W5_OFF; }
  const size_t rel = idx - base;
  const int m = (int)(rel / kr), k = (int)(rel - (size_t)m * kr);
  const float v = (k < kt) ? w[(size_t)m * kt + k] : 0.f;
  unsigned short h, l;
  bf16split(v, h, l);
  whi[idx] = h; wlo[idx] = l;
}

// ---------------- fused preproc: hists (per-thread u8 columns) + area-resize, ONE image read ----------------
// 8-row strips (56 per image). Hist key = type*64 + colbit*32 + bin; row-quad bit is
// block-uniform (8-row strips never straddle r=224) and folded into the global index.
// Resize: per-row horizontal channel sums -> part[8][112][3] (unique slot/thread, no atomics),
// then 4-row vertical reduce -> bf16 x0p interior (ring zeroed by memset beforehand).
__global__ __launch_bounds__(256) void k_preproc(const float* __restrict__ img,
                                                 float* __restrict__ hint,
                                                 float* __restrict__ hgrd,
                                                 ushort_t* __restrict__ x0) {
  const int b = blockIdx.x, s = blockIdx.y;   // 56 strips of 8 rows
  const int r0 = s * 8;
  __shared__ float gs[10][448];                 // 17920 B
  __shared__ unsigned char lh[128 * 260];       // 33280 B
  __shared__ float part[8 * 112 * 3];           // 10752 B   (total 61952 B)
  const int tid = threadIdx.x;
  for (int i = tid; i < (128 * 260) / 4; i += 256) ((unsigned*)lh)[i] = 0u;
  const float* ib = img + (size_t)b * 4 * 200704;
  // stage gray rows r0-1..r0+8 (clamped); interior rows also emit resize h-sums
  for (int i = tid; i < 10 * 112; i += 256) {
    const int rr = i / 112, cc = i % 112, c4 = cc * 4;
    int r = r0 + rr - 1; r = r < 0 ? 0 : (r > 447 ? 447 : r);
    const size_t o = (size_t)r * 448 + c4;
    const float4 vr = *(const float4*)&ib[o];
    const float4 g1 = *(const float4*)&ib[200704 + o];
    const float4 g2 = *(const float4*)&ib[2 * 200704 + o];
    const float4 vb = *(const float4*)&ib[3 * 200704 + o];
    float4 g;
    g.x = 0.299f * vr.x + 0.587f * (0.5f * (g1.x + g2.x)) + 0.114f * vb.x;
    g.y = 0.299f * vr.y + 0.587f * (0.5f * (g1.y + g2.y)) + 0.114f * vb.y;
    g.z = 0.299f * vr.z + 0.587f * (0.5f * (g1.z + g2.z)) + 0.114f * vb.z;
    g.w = 0.299f * vr.w + 0.587f * (0.5f * (g1.w + g2.w)) + 0.114f * vb.w;
    *(float4*)&gs[rr][c4] = g;
    if (rr >= 1 && rr <= 8) {
      const float sr = vr.x + vr.y + vr.z + vr.w;
      const float sg = 0.5f * (g1.x + g2.x) + 0.5f * (g1.y + g2.y)
                     + 0.5f * (g1.z + g2.z) + 0.5f * (g1.w + g2.w);
      const float sb = vb.x + vb.y + vb.z + vb.w;
      float* pp = &part[((rr - 1) * 112 + cc) * 3];
      pp[0] = sr; pp[1] = sg; pp[2] = sb;
    }
  }
  __syncthreads();
  // histogram pass (8 interior rows)
  for (int i = tid; i < 8 * 112; i += 256) {
    const int dr = i / 112, c4 = (i % 112) * 4;
    const unsigned colbit = (c4 >= 224) ? 1u : 0u;
    const int cl = c4 > 0 ? c4 - 1 : 0;
    const int cr = c4 < 444 ? c4 + 4 : 447;
    const float4 m0 = *(const float4*)&gs[dr][c4];
    const float4 m1 = *(const float4*)&gs[dr + 1][c4];
    const float4 m2 = *(const float4*)&gs[dr + 2][c4];
    const float r0v[6] = {gs[dr][cl],     m0.x, m0.y, m0.z, m0.w, gs[dr][cr]};
    const float r1v[6] = {gs[dr + 1][cl], m1.x, m1.y, m1.z, m1.w, gs[dr + 1][cr]};
    const float r2v[6] = {gs[dr + 2][cl], m2.x, m2.y, m2.z, m2.w, gs[dr + 2][cr]};
    #pragma unroll
    for (int j = 0; j < 4; ++j) {
      const float g = r1v[j + 1];
      int bin = (int)(g * 32.f); bin = bin > 31 ? 31 : (bin < 0 ? 0 : bin);
      lh[(colbit * 32u + (unsigned)bin) * 260u + (unsigned)tid]++;
      const float gx = (-r0v[j] + r0v[j + 2] - 2.f * r1v[j] + 2.f * r1v[j + 2]
                        - r2v[j] + r2v[j + 2]) * 0.125f;
      const float gy = (-r0v[j] - 2.f * r0v[j + 1] - r0v[j + 2]
                        + r2v[j] + 2.f * r2v[j + 1] + r2v[j + 2]) * 0.125f;
      const float mag = sqrtf(gx * gx + gy * gy + 1e-6f);
      int sb = (int)(mag * 32.f); sb = sb > 31 ? 31 : (sb < 0 ? 0 : sb);
      lh[(64u + colbit * 32u + (unsigned)sb) * 260u + (unsigned)tid]++;
    }
  }
  __syncthreads();
  // hist reduction: 2 threads per key sum 256 u8 counts, combine, one atomic
  {
    const unsigned rowbit = (s >= 28) ? 1u : 0u;
    const int key = tid >> 1, half = tid & 1;
    const unsigned* row = (const unsigned*)&lh[(unsigned)key * 260u];
    unsigned sum = 0;
    #pragma unroll
    for (int d = 0; d < 32; ++d) {
      const unsigned v = row[half * 32 + d];
      sum += (v & 0xFFu) + ((v >> 8) & 0xFFu) + ((v >> 16) & 0xFFu) + (v >> 24);
    }
    sum += __shfl_down(sum, 1, 64);
    if (half == 0) {
      const int type = key >> 6;
      const int rest = key & 63;
      const int colbit2 = rest >> 5, bin = rest & 31;
      float* dst = (type ? hgrd : hint) + (size_t)b * 160 + 32 + (rowbit * 2 + colbit2) * 32 + bin;
      atomicAdd(dst, (float)sum);
    }
  }
  // resize output: 2 output rows x 112 cols x 3 channels
  for (int i = tid; i < 672; i += 256) {
    const int cc = i % 112;
    const int t  = i / 112;
    const int or2 = t & 1, ch = t >> 1;
    float sum = 0.f;
    #pragma unroll
    for (int rw = 0; rw < 4; ++rw)
      sum += part[((or2 * 4 + rw) * 112 + cc) * 3 + ch];
    x0[(((size_t)b * 3 + ch) * 116 + 2 + 2 * s + or2) * 116 + 2 + cc] = f2bf(sum * (1.f / 16.f));
  }
}

// ---------------- conv MFMA: padded bf16 input, direct-global hi/lo A, K-split x2, 512 thr ----------------
template<int CIN, int HP, int WP, int KH, int KW, int STRIDE, int OH, int OW,
         int OHP, int OWP, int OPAD, int M, int MT>
__global__ __launch_bounds__(512) void k_conv_mfma(const ushort_t* __restrict__ in,
                                                   const ushort_t* __restrict__ whi_,
                                                   const ushort_t* __restrict__ wlo_,
                                                   const float* __restrict__ bias,
                                                   ushort_t* __restrict__ out) {
  constexpr int K_TOT  = CIN * KH * KW;
  constexpr int K_ROUND = ((K_TOT + 127) / 128) * 128;
  constexpr int GSTEPS = K_ROUND / 128;
  constexpr int KHW = KH * KW;
  constexpr int NPB = OH * OW;
  constexpr int WROWS = MT / 16;
  constexpr int TGRP  = 4 / WROWS;
  constexpr int TFRAG = 4 / TGRP;
  __shared__ ushort_t Bs[2][64 * 64];
  __shared__ ushort_t ftab[K_ROUND];
  const int tid = threadIdx.x;
  const int lane = tid & 63, wv = tid >> 6;
  const int g = wv >> 2, wg = wv & 3;
  const int sub = tid & 255;
  const int n0 = blockIdx.x * 64, m0 = blockIdx.y * MT;
  for (int k = tid; k < K_ROUND; k += 512) {
    const int c = k / KHW, kr = k - c * KHW;
    const int ky = kr / KW, kx = kr - (kr / KW) * KW;
    ftab[k] = (k < K_TOT) ? (ushort_t)(2 * ((c * HP + ky) * WP + kx)) : (ushort_t)0;
  }
  const int col = sub & 63, kc2 = sub >> 6;
  const int nb = n0 + col;
  const int bB = nb / NPB, rB = nb % NPB;
  const int oyB = rB / OW, oxB = rB % OW;
  const char* baseB = (const char*)(in + (size_t)bB * CIN * HP * WP)
                      + 2 * (oyB * STRIDE * WP + oxB * STRIDE);
  const int wm = wg % WROWS, tg = wg / WROWS;
  const int mrow = m0 + wm * 16 + (lane & 15);
  const ushort_t* wh = whi_ + (size_t)mrow * K_ROUND;
  const ushort_t* wl = wlo_ + (size_t)mrow * K_ROUND;
  const int kA = (lane >> 4) * 8;
  f32x4 acc[TFRAG] = {};
  __syncthreads();
  const int kb0 = g * GSTEPS * 64;
  for (int step = 0; step < GSTEPS; ++step) {
    const int kb = kb0 + step * 64;
    const u16x8 f0 = *(const u16x8*)&ftab[kb + kc2 * 16];
    const u16x8 f1 = *(const u16x8*)&ftab[kb + kc2 * 16 + 8];
    u16x8 b0, b1;
    #pragma unroll
    for (int j = 0; j < 8; ++j) b0[j] = *(const ushort_t*)(baseB + f0[j]);
    #pragma unroll
    for (int j = 0; j < 8; ++j) b1[j] = *(const ushort_t*)(baseB + f1[j]);
    const int c0 = kc2 * 2, c1 = c0 + 1;
    *(u16x8*)&Bs[g][col * 64 + ((c0 ^ (col & 7)) * 8)] = b0;
    *(u16x8*)&Bs[g][col * 64 + ((c1 ^ (col & 7)) * 8)] = b1;
    __syncthreads();
    #pragma unroll
    for (int s = 0; s < 2; ++s) {
      const int kk = kb + s * 32 + kA;
      const short8 a_h = *(const short8*)&wh[kk];
      const short8 a_l = *(const short8*)&wl[kk];
      const int cA = s * 4 + (lane >> 4);
      #pragma unroll
      for (int tt = 0; tt < TFRAG; ++tt) {
        const int t = tg * TFRAG + tt;
        const int coln = t * 16 + (lane & 15);
        const short8 b_v = *(const short8*)&Bs[g][coln * 64 + ((cA ^ (coln & 7)) * 8)];
        acc[tt] = __builtin_amdgcn_mfma_f32_16x16x32_bf16(a_h, b_v, acc[tt], 0, 0, 0);
        acc[tt] = __builtin_amdgcn_mfma_f32_16x16x32_bf16(a_l, b_v, acc[tt], 0, 0, 0);
      }
    }
    __syncthreads();
  }
  float* scratch = (float*)&Bs[0][0];
  if (g == 1) {
    #pragma unroll
    for (int tt = 0; tt < TFRAG; ++tt) {
      const int t = tg * TFRAG + tt;
      #pragma unroll
      for (int q = 0; q < 4; ++q)
        scratch[(wm * 16 + (lane >> 4) * 4 + q) * 64 + t * 16 + (lane & 15)] = acc[tt][q];
    }
  }
  __syncthreads();
  if (g == 0) {
    #pragma unroll
    for (int q = 0; q < 4; ++q) {
      const int m = m0 + wm * 16 + (lane >> 4) * 4 + q;
      const float bi = bias[m];
      #pragma unroll
      for (int tt = 0; tt < TFRAG; ++tt) {
        const int t = tg * TFRAG + tt;
        const int n = n0 + t * 16 + (lane & 15);
        const float v = acc[tt][q]
                      + scratch[(wm * 16 + (lane >> 4) * 4 + q) * 64 + t * 16 + (lane & 15)]
                      + bi;
        const int b = n / NPB, r = n % NPB;
        const int oy = r / OW, ox = r - (r / OW) * OW;
        out[(((size_t)b * M + m) * OHP + OPAD + oy) * OWP + OPAD + ox] = f2bf(fmaxf(v, 0.f));
      }
    }
  }
}

// ---------------- maxpool 3x3 s2 on bf16 bits -> padded output with zero ring ----------------
template<int C, int HI, int HO, int HOP, int PAD, bool OUTF32>
__global__ __launch_bounds__(256) void k_pool(const ushort_t* __restrict__ in,
                                              void* __restrict__ out) {
  const int idx = blockIdx.x * 256 + threadIdx.x;
  constexpr int TOT = 64 * C * HOP * HOP;
  if (idx >= TOT) return;
  const int x = idx % HOP;
  const int y = (idx / HOP) % HOP;
  const int c = (idx / (HOP * HOP)) % C;
  const int b = idx / (HOP * HOP * C);
  ushort_t v = 0;
  const int oy = y - PAD, ox = x - PAD;
  if (oy >= 0 && oy < HO && ox >= 0 && ox < HO) {
    const ushort_t* ib = in + (size_t)(b * C + c) * HI * HI + (size_t)(oy * 2) * HI + ox * 2;
    #pragma unroll
    for (int i = 0; i < 3; ++i)
      #pragma unroll
      for (int j = 0; j < 3; ++j) {
        const ushort_t u = ib[i * HI + j];
        v = u > v ? u : v;
      }
  }
  if constexpr (OUTF32) ((float*)out)[idx] = bf2f(v);
  else                  ((ushort_t*)out)[idx] = v;
}

// ---------------- feature assembly (h0 reconstructed from quadrant sums) ----------------
__global__ __launch_bounds__(256) void k_feat(const float* __restrict__ p5,
                                              const float* __restrict__ hint,
                                              const float* __restrict__ hgrad,
                                              float* __restrict__ f) {
  const int b = blockIdx.x, tid = threadIdx.x;
  __shared__ float tmp4[4];
  __shared__ float vals[160];
  const float* ps = p5 + (size_t)b * 1024;
  float* fb = f + (size_t)b * 4096;
  float mv[4]; float ss = 0.f;
  #pragma unroll
  for (int i = 0; i < 4; ++i) { mv[i] = ps[tid + i * 256]; ss += mv[i] * mv[i]; }
  #pragma unroll
  for (int o = 32; o > 0; o >>= 1) ss += __shfl_down(ss, o, 64);
  if ((tid & 63) == 0) tmp4[tid >> 6] = ss;
  __syncthreads();
  const float inv = 1.f / (sqrtf(tmp4[0] + tmp4[1] + tmp4[2] + tmp4[3]) + 1e-7f);
  #pragma unroll
  for (int i = 0; i < 4; ++i) fb[tid + i * 256] = fmaxf(mv[i] * inv, 0.f);
  for (int ft = 0; ft < 2; ++ft) {
    const float* hb = (ft ? hgrad : hint) + (size_t)b * 160;
    __syncthreads();
    if (tid < 160) {
      float cnt;
      if (tid < 32) cnt = hb[32 + tid] + hb[64 + tid] + hb[96 + tid] + hb[128 + tid];
      else          cnt = hb[tid];
      vals[tid] = cnt * (tid < 32 ? (1.f / 200704.f) : (1.f / 50176.f));
    }
    __syncthreads();
    float s2 = 0.f;
    if (tid < 160) s2 = (tid < 32 ? 16.f : 4.f) * vals[tid] * vals[tid];
    #pragma unroll
    for (int o = 32; o > 0; o >>= 1) s2 += __shfl_down(s2, o, 64);
    __syncthreads();
    if ((tid & 63) == 0) tmp4[tid >> 6] = s2;
    __syncthreads();
    const float inv2 = 1.f / (sqrtf(tmp4[0] + tmp4[1] + tmp4[2] + tmp4[3]) + 1e-7f);
    float* fo = fb + 1024 + ft * 1536;
    for (int idx = tid; idx < 1536; idx += 256) {
      const int ch = idx >> 4, i2 = (idx >> 2) & 3, j = idx & 3;
      float v;
      if (ch < 32)      v = vals[ch];
      else if (ch < 64) v = vals[32 + (((i2 >> 1) * 2) + (j >> 1)) * 32 + (ch - 32)];
      else              v = 0.f;
      fo[idx] = fmaxf(v * inv2, 0.f);
    }
  }
}

// ---------------- fc1: one wave per (b,oc) ----------------
__global__ __launch_bounds__(256) void k_fc1(const float* __restrict__ f,
                                             const float* __restrict__ w,
                                             const float* __restrict__ bias,
                                             float* __restrict__ h1) {
  const int gid = blockIdx.x * 4 + (threadIdx.x >> 6);
  const int lane = threadIdx.x & 63;
  if (gid >= 64 * 256) return;
  const int oc = gid & 255, b = gid >> 8;
  const float* fb = f + (size_t)b * 4096;
  const float* wr = w + (size_t)oc * 4096;
  float s = 0.f;
  for (int k = lane; k < 4096; k += 64) s += fb[k] * wr[k];
  #pragma unroll
  for (int o = 32; o > 0; o >>= 1) s += __shfl_down(s, o, 64);
  if (lane == 0) h1[(size_t)b * 256 + oc] = fmaxf(s + bias[oc], 0.f);
}

// ---------------- fc2 ----------------
__global__ __launch_bounds__(256) void k_fc2_simple(const float* __restrict__ h1,
                                                    const float* __restrict__ w,
                                                    const float* __restrict__ bias,
                                                    float* __restrict__ out) {
  const int idx = blockIdx.x * 256 + threadIdx.x;
  if (idx >= 64 * 12) return;
  const int oc = idx % 12, b = idx / 12;
  const float* hb = h1 + (size_t)b * 256;
  const float* wr = w + (size_t)oc * 256;
  float s = bias[oc];
  for (int k = 0; k < 256; ++k) s += hb[k] * wr[k];
  out[b * 12 + oc] = s;
}

// ---------------- launch ----------------
extern "C" void kernel_launch(void* const* d_in, const int* in_sizes, int n_in,
                              void* d_out, int out_size, void* d_ws, size_t ws_size,
                              hipStream_t stream) {
  const float* img  = (const float*)d_in[0];
  const float* w1 = (const float*)d_in[1];  const float* b1 = (const float*)d_in[2];
  const float* w2 = (const float*)d_in[3];  const float* b2 = (const float*)d_in[4];
  const float* w3 = (const float*)d_in[5];  const float* b3 = (const float*)d_in[6];
  const float* w4 = (const float*)d_in[7];  const float* b4 = (const float*)d_in[8];
  const float* w5 = (const float*)d_in[9];  const float* b5 = (const float*)d_in[10];
  const float* fc1w = (const float*)d_in[11]; const float* fc1b = (const float*)d_in[12];
  const float* fc2w = (const float*)d_in[13]; const float* fc2b = (const float*)d_in[14];
  float* out = (float*)d_out;
  float* ws  = (float*)d_ws;

  float* hint = ws + OFF_HINT;
  float* hgrd = ws + OFF_HGRD;
  float* f    = ws + OFF_F;
  float* h1   = ws + OFF_H1;
  float* p5   = ws + OFF_P5;
  ushort_t* whi = (ushort_t*)(ws + OFF_WHI);
  ushort_t* wlo = (ushort_t*)(ws + OFF_WLO);
  ushort_t* ra  = (ushort_t*)(ws + OFF_RA);   // x0p / p1p / p2p ; a4p at +A4P_U16
  ushort_t* rb  = (ushort_t*)(ws + OFF_RB);   // a1 / a2 / a3p / a5

  hipMemsetAsync(hint, 0, (size_t)2 * 64 * 160 * sizeof(float), stream);
  hipMemsetAsync(ra, 0, (size_t)64 * 3 * 116 * 116 * 2, stream);   // x0p incl. zero ring

  k_wsplit_all<<<(int)((WP_U16 + 255) / 256), 256, 0, stream>>>(w1, w2, w3, w4, w5, whi, wlo);

  // fused hist + resize (single pass over the 205 MB image)
  k_preproc<<<dim3(64, 56), 256, 0, stream>>>(img, hint, hgrd, ra);

  // conv1: [b][3][116][116] -> a1 [b][64][27][27] (RB)
  k_conv_mfma<3,116,116,11,11,4,27,27,27,27,0,64,64>
      <<<dim3(729, 1), 512, 0, stream>>>(ra, whi + W1_OFF, wlo + W1_OFF, b1, rb);
  // pool1 -> p1p [b][64][17][17] pad2 (RA)
  k_pool<64,27,13,17,2,false><<<(64*64*17*17 + 255)/256, 256, 0, stream>>>(rb, ra);
  // conv2: -> a2 [b][192][13][13] (RB)
  k_conv_mfma<64,17,17,5,5,1,13,13,13,13,0,192,64>
      <<<dim3(169, 3), 512, 0, stream>>>(ra, whi + W2_OFF, wlo + W2_OFF, b2, rb);
  // pool2 -> p2p [b][192][8][8] pad1 (RA)
  k_pool<192,13,6,8,1,false><<<(64*192*8*8 + 255)/256, 256, 0, stream>>>(rb, ra);
  // zero pad rings for conv3/conv4 padded outputs
  hipMemsetAsync(rb, 0, (size_t)64*384*8*8*2, stream);                      // a3p
  hipMemsetAsync(ra + A4P_U16, 0, (size_t)64*256*8*8*2, stream);            // a4p
  // conv3: p2p -> a3p [b][384][8][8] pad1 interior (RB)
  k_conv_mfma<192,8,8,3,3,1,6,6,8,8,1,384,32>
      <<<dim3(36, 12), 512, 0, stream>>>(ra, whi + W3_OFF, wlo + W3_OFF, b3, rb);
  // conv4: a3p -> a4p [b][256][8][8] pad1 interior (RA + A4P_U16)
  k_conv_mfma<384,8,8,3,3,1,6,6,8,8,1,256,32>
      <<<dim3(36, 8), 512, 0, stream>>>(rb, whi + W4_OFF, wlo + W4_OFF, b4, ra + A4P_U16);
  // conv5: a4p -> a5 [b][256][6][6] (RB)
  k_conv_mfma<256,8,8,3,3,1,6,6,6,6,0,256,32>
      <<<dim3(36, 8), 512, 0, stream>>>(ra + A4P_U16, whi + W5_OFF, wlo + W5_OFF, b5, rb);
  // pool5 -> p5 f32 [b][256][2][2]
  k_pool<256,6,2,2,0,true><<<(64*256*2*2 + 255)/256, 256, 0, stream>>>(rb, p5);

  k_feat<<<64, 256, 0, stream>>>(p5, hint, hgrd, f);
  k_fc1<<<(64*256)/4, 256, 0, stream>>>(f, fc1w, fc1b, h1);
  k_fc2_simple<<<(64*12 + 255)/256, 256, 0, stream>>>(h1, fc2w, fc2b, out);
}